// Round 5
// baseline (627.532 us; speedup 1.0000x reference)
//
#include <hip/hip_runtime.h>
#include <hip/hip_bf16.h>

#define N_NODES 50000
#define NUM_E   800000
#define EPS_BN  1e-5f
#define NUM_GRAPHS 64

typedef __attribute__((ext_vector_type(8))) short bf16x8;
typedef __attribute__((ext_vector_type(4))) float f32x4;
typedef unsigned short ushort_t;
typedef unsigned int uint_t;

static __device__ __forceinline__ unsigned short f2bf(float f) {
    unsigned int u = __float_as_uint(f);
    u += 0x7fffu + ((u >> 16) & 1u);   // RNE
    return (unsigned short)(u >> 16);
}
static __device__ __forceinline__ uint_t pkbf(float lo, float hi) {
    __hip_bfloat162 t = __float22bfloat162_rn(make_float2(lo, hi));
    return *(uint_t*)&t;
}
static __device__ __forceinline__ float bflo(uint_t u) { return __uint_as_float(u << 16); }
static __device__ __forceinline__ float bfhi(uint_t u) { return __uint_as_float(u & 0xffff0000u); }

// ---------------- hist + prep merged (independent work, block-range split): saves a launch ----------------
__global__ void hist_prep_kernel(const int* __restrict__ ei, int* __restrict__ deg,
                                 const float* __restrict__ W1, const float* __restrict__ W2,
                                 const float* __restrict__ W3, const float* __restrict__ x,
                                 ushort_t* __restrict__ w1t, ushort_t* __restrict__ w2t,
                                 ushort_t* __restrict__ w3t, ushort_t* __restrict__ xbf) {
    const int HB = (NUM_E + 255) / 256;          // 3125 hist blocks
    const int S1 = 128 * 256, S2 = 256 * 256, S3 = 256 * 64;
    const int SW = S1 + S2 + S3;                 // 81920
    const int SX = N_NODES * 128 / 4;            // 1.6M float4 units
    int b = blockIdx.x;
    if (b < HB) {
        int e = b * 256 + threadIdx.x;
        if (e < NUM_E) atomicAdd(&deg[ei[NUM_E + e]], 1);
        return;
    }
    int i = (b - HB) * 256 + threadIdx.x;
    if (i < SX) {
        float4 v = ((const float4*)x)[i];
        ((uint2*)xbf)[i] = make_uint2(pkbf(v.x, v.y), pkbf(v.z, v.w));
    } else if (i < SX + SW) {
        int j = i - SX;
        if (j < S1) {
            int k = j / 256, n = j % 256;
            w1t[n * 128 + k] = f2bf(W1[j]);
        } else if (j < S1 + S2) {
            int jj = j - S1; int k = jj / 256, n = jj % 256;
            w2t[n * 256 + k] = f2bf(W2[jj]);
        } else {
            int jj = j - S1 - S2; int k = jj / 64, n = jj % 64;
            w3t[n * 256 + k] = f2bf(W3[jj]);
        }
    }
}

__global__ void scan_local_kernel(const int* __restrict__ deg, int* __restrict__ rowptr,
                                  int* __restrict__ bsum) {
    __shared__ int ws[4];
    int b = blockIdx.x, t = threadIdx.x;
    int i = b * 256 + t;
    int lane = t & 63, wv = t >> 6;
    int v = (i < N_NODES) ? deg[i] : 0;
    int incl = v;
#pragma unroll
    for (int off = 1; off < 64; off <<= 1) {
        int u = __shfl_up(incl, off, 64);
        if (lane >= off) incl += u;
    }
    if (lane == 63) ws[wv] = incl;
    __syncthreads();
    if (t == 0) {
        int s = 0;
#pragma unroll
        for (int k = 0; k < 4; ++k) { int x = ws[k]; ws[k] = s; s += x; }
        bsum[b] = s;
    }
    __syncthreads();
    if (i < N_NODES) rowptr[i + 1] = ws[wv] + incl;
}

// merged scan_sums + scan_add: each block redundantly sums its bsum prefix (196 entries, trivial)
__global__ __launch_bounds__(256) void scan_fixup_kernel(int* __restrict__ rowptr,
                                                         const int* __restrict__ bsum) {
    __shared__ int ws[4];
    int b = blockIdx.x, t = threadIdx.x;
    int lane = t & 63, wv = t >> 6;
    int v = (t < b) ? bsum[t] : 0;   // b <= 195 < 256, t < b => valid index
#pragma unroll
    for (int off = 1; off < 64; off <<= 1) v += __shfl_xor(v, off, 64);
    if (lane == 0) ws[wv] = v;
    __syncthreads();
    int pre = ws[0] + ws[1] + ws[2] + ws[3];
    int i = b * 256 + t;
    if (i < N_NODES) rowptr[i + 1] += pre;
    if (b == 0 && t == 0) rowptr[0] = 0;
}

__global__ void scatter_kernel(const int* __restrict__ ei, const int* __restrict__ rowptr,
                               int* __restrict__ fill, int* __restrict__ srcs) {
    int e = blockIdx.x * blockDim.x + threadIdx.x;
    if (e >= NUM_E) return;
    int dst = ei[NUM_E + e];
    int pos = rowptr[dst] + atomicAdd(&fill[dst], 1);
    srcs[pos] = ei[e];
}

// ---------------- BN fold into W: Wts[n][k] = a[k]*Wt[n][k];  cvec[n] = sum_k b[k]*Wt[n][k] ----------------
__global__ __launch_bounds__(256) void scale_w_kernel(const float* __restrict__ stats,
                                                      const float* __restrict__ g,
                                                      const float* __restrict__ be,
                                                      const ushort_t* __restrict__ wt,
                                                      ushort_t* __restrict__ wts,
                                                      float* __restrict__ cvec) {
    int n = blockIdx.x, k = threadIdx.x;
    float m = stats[k] * (1.f / N_NODES);
    float var = fmaxf(stats[256 + k] * (1.f / N_NODES) - m * m, 0.f);
    float rs = rsqrtf(var + EPS_BN) * g[k];
    float b = be[k] - m * rs;
    float wv = bflo((uint_t)wt[n * 256 + k]);
    wts[n * 256 + k] = f2bf(rs * wv);
    float p = b * wv;
    __shared__ float ws[4];
    int lane = k & 63, wid = k >> 6;
#pragma unroll
    for (int off = 1; off < 64; off <<= 1) p += __shfl_xor(p, off, 64);
    if (lane == 0) ws[wid] = p;
    __syncthreads();
    if (k == 0) cvec[n] = ws[0] + ws[1] + ws[2] + ws[3];
}

// ---------------- GEMM: A(bf16) @ Bt^T + cvec -> h(bf16) + per-head logits ----------------
template<int K, int NFULL, int BN>
__global__ __launch_bounds__(256) void gemm_fused_kernel(const ushort_t* __restrict__ A,
                                                         const ushort_t* __restrict__ Bt,
                                                         ushort_t* __restrict__ C,
                                                         const float* __restrict__ cvec,
                                                         const float* __restrict__ a_src,
                                                         const float* __restrict__ a_dst,
                                                         float* __restrict__ as_,
                                                         float* __restrict__ ad_) {
    const int NT = BN / 16;
    const int NG = BN / 64;
    constexpr int LOOP_BYTES = (128 * 40 + BN * 40) * 2;
    constexpr int EPI_BYTES  = 4 * 32 * 64 * 2;
    constexpr int SMEM_BYTES = LOOP_BYTES > EPI_BYTES ? LOOP_BYTES : EPI_BYTES;
    __shared__ __align__(16) unsigned char smem[SMEM_BYTES];
    ushort_t (*As)[40]     = (ushort_t (*)[40])smem;                       // [128][40]
    ushort_t (*Bs)[40]     = (ushort_t (*)[40])(smem + 128 * 40 * 2);      // [BN][40]
    ushort_t (*Cs)[32][64] = (ushort_t (*)[32][64])smem;                   // [4][32][64] (aliases As/Bs)
    __shared__ float cvec_s[BN];
    __shared__ float asrc_s[BN], adst_s[BN];
    int tid = threadIdx.x;
    int lane = tid & 63, w = tid >> 6;
    int row0 = blockIdx.x * 128, col0 = blockIdx.y * BN;
    int m_l = lane & 15, q = lane >> 4;

    if (tid < BN) {
        cvec_s[tid] = cvec[col0 + tid];
        asrc_s[tid] = a_src[col0 + tid];
        adst_s[tid] = a_dst[col0 + tid];
    }
    __syncthreads();

    f32x4 acc[2][NT];
#pragma unroll
    for (int r = 0; r < 2; ++r)
#pragma unroll
        for (int c = 0; c < NT; ++c) acc[r][c] = (f32x4){0.f, 0.f, 0.f, 0.f};

    int ar = tid >> 1, ako = (tid & 1) * 16;

    for (int k0 = 0; k0 < K; k0 += 32) {
        int gr = row0 + ar;
        uint4 u0 = make_uint4(0, 0, 0, 0), u1 = make_uint4(0, 0, 0, 0);
        if (gr < N_NODES) {
            const ushort_t* ap = A + (long)gr * K + k0 + ako;
            u0 = *(const uint4*)ap;
            u1 = *(const uint4*)(ap + 8);
        }
        if constexpr (BN == 128) {
            int br = tid >> 1, bko = (tid & 1) * 16;
            const ushort_t* bp = Bt + (long)(col0 + br) * K + k0 + bko;
            uint4 b0 = *(const uint4*)bp;
            uint4 b1 = *(const uint4*)(bp + 8);
            *(uint4*)&As[ar][ako] = u0;
            *(uint4*)&As[ar][ako + 8] = u1;
            *(uint4*)&Bs[br][bko] = b0;
            *(uint4*)&Bs[br][bko + 8] = b1;
        } else {
            int br = tid >> 2, bko = (tid & 3) * 8;
            uint4 bv = *(const uint4*)(Bt + (long)(col0 + br) * K + k0 + bko);
            *(uint4*)&As[ar][ako] = u0;
            *(uint4*)&As[ar][ako + 8] = u1;
            *(uint4*)&Bs[br][bko] = bv;
        }
        __syncthreads();

        bf16x8 af[2];
#pragma unroll
        for (int r = 0; r < 2; ++r)
            af[r] = *(const bf16x8*)&As[w * 32 + r * 16 + m_l][q * 8];
#pragma unroll
        for (int c = 0; c < NT; ++c) {
            bf16x8 bf = *(const bf16x8*)&Bs[c * 16 + m_l][q * 8];
#pragma unroll
            for (int r = 0; r < 2; ++r)
                acc[r][c] = __builtin_amdgcn_mfma_f32_16x16x32_bf16(af[r], bf, acc[r][c], 0, 0, 0);
        }
        __syncthreads();   // after this barrier As/Bs are dead -> Cs may alias
    }

    const int H = NFULL / 64;
#pragma unroll
    for (int gblk = 0; gblk < NG; ++gblk) {
        int hidx = blockIdx.y * NG + gblk;
        int colg = col0 + gblk * 64;
#pragma unroll
        for (int r = 0; r < 2; ++r)
#pragma unroll
            for (int cc = 0; cc < 4; ++cc)
#pragma unroll
                for (int i = 0; i < 4; ++i)
                    Cs[w][r * 16 + q * 4 + i][cc * 16 + m_l] =
                        f2bf(acc[r][gblk * 4 + cc][i] + cvec_s[gblk * 64 + cc * 16 + m_l]);
        // same-wave LDS RAW: in-order DS pipe, no barrier needed
#pragma unroll
        for (int j = 0; j < 4; ++j) {
            int flat = j * 64 + lane;
            int lr = flat >> 3, chg = flat & 7;
            int gr = row0 + w * 32 + lr;
            uint4 u = *(uint4*)&Cs[w][lr][chg * 8];
            float f0 = bflo(u.x), f1 = bfhi(u.x), f2 = bflo(u.y), f3 = bfhi(u.y);
            float f4 = bflo(u.z), f5 = bfhi(u.z), f6 = bflo(u.w), f7 = bfhi(u.w);
            int cb = gblk * 64 + chg * 8;
            float s1 = f0 * asrc_s[cb] + f1 * asrc_s[cb + 1] + f2 * asrc_s[cb + 2] + f3 * asrc_s[cb + 3]
                     + f4 * asrc_s[cb + 4] + f5 * asrc_s[cb + 5] + f6 * asrc_s[cb + 6] + f7 * asrc_s[cb + 7];
            float s2 = f0 * adst_s[cb] + f1 * adst_s[cb + 1] + f2 * adst_s[cb + 2] + f3 * adst_s[cb + 3]
                     + f4 * adst_s[cb + 4] + f5 * adst_s[cb + 5] + f6 * adst_s[cb + 6] + f7 * adst_s[cb + 7];
#pragma unroll
            for (int o = 1; o < 8; o <<= 1) {
                s1 += __shfl_xor(s1, o, 64);
                s2 += __shfl_xor(s2, o, 64);
            }
            if (gr < N_NODES) {
                *(uint4*)(C + (long)gr * NFULL + colg + chg * 8) = u;
                if ((lane & 7) == 0) {
                    as_[gr * H + hidx] = s1;
                    ad_[gr * H + hidx] = s2;
                }
            }
        }
    }
}

// ---------------- GAT aggregation H=4 (R3 gather structure, at ~3.3 TB/s ceiling) + fused BN stats ----------------
// Stats fusion deletes the bn_stats dispatch + its 25.6MB re-read. Register-careful: acc[] reused
// in place (bias+relu applied into acc), per-t immediate shfl reduce (no s1/s2 arrays).
// Grid exact (N%16==0): no early returns -> __syncthreads safe.
__global__ __launch_bounds__(256) void agg4_kernel(const ushort_t* __restrict__ h,
                                                   const float* __restrict__ as_,
                                                   const float* __restrict__ ad_,
                                                   const int* __restrict__ rowptr,
                                                   const int* __restrict__ srcs,
                                                   const float* __restrict__ bias,
                                                   ushort_t* __restrict__ out,
                                                   float* __restrict__ stats) {
    __shared__ float4 alf[4][4][17];   // [wave][quarter][edge] 4 head alphas (pad 17)
    __shared__ int    sed[4][4][17];   // [wave][quarter][edge] src id
    __shared__ float  ssum[256], ssq[256];
    int tid = threadIdx.x;
    int lane = tid & 63, w = tid >> 6;
    int q = lane >> 4, cl = lane & 15;
    int n = blockIdx.x * 16 + w * 4 + q;   // grid exact: n < N_NODES always
    ssum[tid] = 0.f; ssq[tid] = 0.f;
    __syncthreads();

    int start = rowptr[n];
    int deg = rowptr[n + 1] - start;

    float4 adv = *(const float4*)(ad_ + n * 4);
    float ad4[4] = {adv.x, adv.y, adv.z, adv.w};

    float mx[4] = {-1e30f, -1e30f, -1e30f, -1e30f};
    float dn[4] = {0.f, 0.f, 0.f, 0.f};
    {
        float vst[4] = {-1e30f, -1e30f, -1e30f, -1e30f};
        int s0 = 0;
        if (deg > 0) s0 = srcs[start + min(cl, deg - 1)];
        sed[w][q][cl] = s0;
        if (cl < deg) {
            float4 av = *(const float4*)(as_ + s0 * 4);
            float vv[4] = {av.x + ad4[0], av.y + ad4[1], av.z + ad4[2], av.w + ad4[3]};
#pragma unroll
            for (int hh = 0; hh < 4; ++hh) {
                float v = vv[hh] > 0.f ? vv[hh] : 0.2f * vv[hh];
                vst[hh] = v; mx[hh] = v; dn[hh] = 1.f;
            }
        }
        alf[w][q][cl] = make_float4(vst[0], vst[1], vst[2], vst[3]);
        for (int j = cl + 16; j < deg; j += 16) {
            int s = srcs[start + j];
            float4 av = *(const float4*)(as_ + s * 4);
            float vv[4] = {av.x + ad4[0], av.y + ad4[1], av.z + ad4[2], av.w + ad4[3]};
#pragma unroll
            for (int hh = 0; hh < 4; ++hh) {
                float v = vv[hh] > 0.f ? vv[hh] : 0.2f * vv[hh];
                float mn = fmaxf(mx[hh], v);
                dn[hh] = dn[hh] * __expf(mx[hh] - mn) + __expf(v - mn);
                mx[hh] = mn;
            }
        }
    }
    float mloc[4] = {mx[0], mx[1], mx[2], mx[3]};
#pragma unroll
    for (int off = 1; off < 16; off <<= 1)
#pragma unroll
        for (int hh = 0; hh < 4; ++hh) mx[hh] = fmaxf(mx[hh], __shfl_xor(mx[hh], off, 64));
#pragma unroll
    for (int hh = 0; hh < 4; ++hh) dn[hh] *= __expf(mloc[hh] - mx[hh]);
#pragma unroll
    for (int off = 1; off < 16; off <<= 1)
#pragma unroll
        for (int hh = 0; hh < 4; ++hh) dn[hh] += __shfl_xor(dn[hh], off, 64);
    float inv[4];
#pragma unroll
    for (int hh = 0; hh < 4; ++hh) inv[hh] = dn[hh] > 0.f ? 1.f / dn[hh] : 0.f;
    {
        float4 vv = alf[w][q][cl];   // logits -> alphas (OOB lanes: exp(-1e30-mx)=0)
        alf[w][q][cl] = make_float4(__expf(vv.x - mx[0]) * inv[0], __expf(vv.y - mx[1]) * inv[1],
                                    __expf(vv.z - mx[2]) * inv[2], __expf(vv.w - mx[3]) * inv[3]);
    }

    int hd = cl >> 2, cbase = cl * 16;
    float acc[16];
#pragma unroll
    for (int k = 0; k < 16; ++k) acc[k] = 0.f;

    for (int chunk = 0; chunk < deg || chunk == 0; chunk += 16) {
        if (chunk > 0) {
            int j = chunk + cl;
            int s = srcs[start + min(j, deg - 1)];
            sed[w][q][cl] = s;
            float a4[4] = {0.f, 0.f, 0.f, 0.f};
            if (j < deg) {
                float4 av = *(const float4*)(as_ + s * 4);
                float vv[4] = {av.x + ad4[0], av.y + ad4[1], av.z + ad4[2], av.w + ad4[3]};
#pragma unroll
                for (int hh = 0; hh < 4; ++hh) {
                    float v = vv[hh] > 0.f ? vv[hh] : 0.2f * vv[hh];
                    a4[hh] = __expf(v - mx[hh]) * inv[hh];
                }
            }
            alf[w][q][cl] = make_float4(a4[0], a4[1], a4[2], a4[3]);
        }
        int cnt = min(16, deg - chunk);
        if (cnt < 0) cnt = 0;
        int e = 0;
        // 4-edge groups, half-row batches: 4 uint4 in flight, 2 batches per group
        for (; e + 4 <= cnt; e += 4) {
            float av[4]; int sv[4];
#pragma unroll
            for (int t = 0; t < 4; ++t) {
                av[t] = ((const float*)&alf[w][q][e + t])[hd];
                sv[t] = sed[w][q][e + t];
            }
            uint4 ua[4];
#pragma unroll
            for (int t = 0; t < 4; ++t)
                ua[t] = *(const uint4*)(h + (long)sv[t] * 256 + cbase);
#pragma unroll
            for (int t = 0; t < 4; ++t) {
                float al = av[t];
                acc[0] += al * bflo(ua[t].x); acc[1] += al * bfhi(ua[t].x);
                acc[2] += al * bflo(ua[t].y); acc[3] += al * bfhi(ua[t].y);
                acc[4] += al * bflo(ua[t].z); acc[5] += al * bfhi(ua[t].z);
                acc[6] += al * bflo(ua[t].w); acc[7] += al * bfhi(ua[t].w);
            }
#pragma unroll
            for (int t = 0; t < 4; ++t)
                ua[t] = *(const uint4*)(h + (long)sv[t] * 256 + cbase + 8);
#pragma unroll
            for (int t = 0; t < 4; ++t) {
                float al = av[t];
                acc[8]  += al * bflo(ua[t].x); acc[9]  += al * bfhi(ua[t].x);
                acc[10] += al * bflo(ua[t].y); acc[11] += al * bfhi(ua[t].y);
                acc[12] += al * bflo(ua[t].z); acc[13] += al * bfhi(ua[t].z);
                acc[14] += al * bflo(ua[t].w); acc[15] += al * bfhi(ua[t].w);
            }
        }
        for (; e < cnt; ++e) {   // exact tail, 1 edge
            float al = ((const float*)&alf[w][q][e])[hd];
            const ushort_t* hr = h + (long)sed[w][q][e] * 256 + cbase;
            uint4 u0 = *(const uint4*)hr;
            uint4 u1 = *(const uint4*)(hr + 8);
            acc[0]  += al * bflo(u0.x); acc[1]  += al * bfhi(u0.x);
            acc[2]  += al * bflo(u0.y); acc[3]  += al * bfhi(u0.y);
            acc[4]  += al * bflo(u0.z); acc[5]  += al * bfhi(u0.z);
            acc[6]  += al * bflo(u0.w); acc[7]  += al * bfhi(u0.w);
            acc[8]  += al * bflo(u1.x); acc[9]  += al * bfhi(u1.x);
            acc[10] += al * bflo(u1.y); acc[11] += al * bfhi(u1.y);
            acc[12] += al * bflo(u1.z); acc[13] += al * bfhi(u1.z);
            acc[14] += al * bflo(u1.w); acc[15] += al * bfhi(u1.w);
        }
        if (deg <= 16) break;
    }

    // epilogue: bias + relu into acc (in place), bf16 store, fused BN-stat partials
#pragma unroll
    for (int t = 0; t < 16; ++t) acc[t] = fmaxf(acc[t] + bias[cbase + t], 0.f);
    uint_t ow[8];
#pragma unroll
    for (int t = 0; t < 8; ++t) ow[t] = pkbf(acc[2 * t], acc[2 * t + 1]);
    ushort_t* op = out + (long)n * 256 + cbase;
    *(uint4*)op = make_uint4(ow[0], ow[1], ow[2], ow[3]);
    *(uint4*)(op + 8) = make_uint4(ow[4], ow[5], ow[6], ow[7]);

#pragma unroll
    for (int t = 0; t < 16; ++t) {   // reduce 4 quarters (same cl -> same channels), no extra arrays
        float a = acc[t], sq = a * a;
        a  += __shfl_xor(a, 16, 64);  a  += __shfl_xor(a, 32, 64);
        sq += __shfl_xor(sq, 16, 64); sq += __shfl_xor(sq, 32, 64);
        if (lane < 16) {
            atomicAdd(&ssum[cbase + t], a);
            atomicAdd(&ssq[cbase + t], sq);
        }
    }
    __syncthreads();
    atomicAdd(&stats[tid], ssum[tid]);
    atomicAdd(&stats[256 + tid], ssq[tid]);
}

// ---------------- GAT aggregation H=1: octant (8 lanes) per dst, 4-edge groups, fused BN stats ----------------
__global__ __launch_bounds__(256) void agg1_kernel(const ushort_t* __restrict__ h,
                                                   const float* __restrict__ as_,
                                                   const float* __restrict__ ad_,
                                                   const int* __restrict__ rowptr,
                                                   const int* __restrict__ srcs,
                                                   const float* __restrict__ bias,
                                                   ushort_t* __restrict__ out,
                                                   float* __restrict__ stats) {
    __shared__ float alf1[4][8][9];
    __shared__ int   sed1[4][8][9];
    __shared__ float ssum[64], ssq[64];
    int tid = threadIdx.x;
    int lane = tid & 63, w = tid >> 6;
    int o = lane >> 3, cl = lane & 7;
    int n = blockIdx.x * 32 + w * 8 + o;
    bool valid = n < N_NODES;
    int nc = valid ? n : N_NODES - 1;
    if (tid < 64) { ssum[tid] = 0.f; ssq[tid] = 0.f; }
    __syncthreads();

    int start = rowptr[nc];
    int deg = valid ? rowptr[nc + 1] - start : 0;
    float adn = ad_[nc];

    float mx = -1e30f, dn = 0.f;
    {
        float vst = -1e30f;
        int s0 = 0;
        if (deg > 0) s0 = srcs[start + min(cl, deg - 1)];
        sed1[w][o][cl] = s0;
        if (cl < deg) {
            float v = as_[s0] + adn;
            v = v > 0.f ? v : 0.2f * v;
            vst = v; mx = v; dn = 1.f;
        }
        alf1[w][o][cl] = vst;
        for (int j = cl + 8; j < deg; j += 8) {
            int s = srcs[start + j];
            float v = as_[s] + adn;
            v = v > 0.f ? v : 0.2f * v;
            float mn = fmaxf(mx, v);
            dn = dn * __expf(mx - mn) + __expf(v - mn);
            mx = mn;
        }
    }
    float mloc = mx;
#pragma unroll
    for (int off = 1; off < 8; off <<= 1) mx = fmaxf(mx, __shfl_xor(mx, off, 64));
    dn *= __expf(mloc - mx);
#pragma unroll
    for (int off = 1; off < 8; off <<= 1) dn += __shfl_xor(dn, off, 64);
    float inv = dn > 0.f ? 1.f / dn : 0.f;

    alf1[w][o][cl] = __expf(alf1[w][o][cl] - mx) * inv;

    int c0 = cl * 8;
    float acc[8] = {0.f, 0.f, 0.f, 0.f, 0.f, 0.f, 0.f, 0.f};

    for (int chunk = 0; chunk < deg || chunk == 0; chunk += 8) {
        if (chunk > 0) {
            int j = chunk + cl;
            int s = srcs[start + min(j, deg - 1)];
            sed1[w][o][cl] = s;
            float al = 0.f;
            if (j < deg) {
                float v = as_[s] + adn;
                v = v > 0.f ? v : 0.2f * v;
                al = __expf(v - mx) * inv;
            }
            alf1[w][o][cl] = al;
        }
        int cnt = min(8, deg - chunk);
        if (cnt < 0) cnt = 0;
        int e = 0;
        for (; e + 4 <= cnt; e += 4) {
            float av[4]; int sv[4];
#pragma unroll
            for (int t = 0; t < 4; ++t) {
                av[t] = alf1[w][o][e + t];
                sv[t] = sed1[w][o][e + t];
            }
            uint4 ua[4];
#pragma unroll
            for (int t = 0; t < 4; ++t)
                ua[t] = *(const uint4*)(h + (long)sv[t] * 64 + c0);
#pragma unroll
            for (int t = 0; t < 4; ++t) {
                float al = av[t];
                acc[0] += al * bflo(ua[t].x); acc[1] += al * bfhi(ua[t].x);
                acc[2] += al * bflo(ua[t].y); acc[3] += al * bfhi(ua[t].y);
                acc[4] += al * bflo(ua[t].z); acc[5] += al * bfhi(ua[t].z);
                acc[6] += al * bflo(ua[t].w); acc[7] += al * bfhi(ua[t].w);
            }
        }
        for (; e < cnt; ++e) {
            float al = alf1[w][o][e];
            uint4 u = *(const uint4*)(h + (long)sed1[w][o][e] * 64 + c0);
            acc[0] += al * bflo(u.x); acc[1] += al * bfhi(u.x);
            acc[2] += al * bflo(u.y); acc[3] += al * bfhi(u.y);
            acc[4] += al * bflo(u.z); acc[5] += al * bfhi(u.z);
            acc[6] += al * bflo(u.w); acc[7] += al * bfhi(u.w);
        }
        if (deg <= 8) break;
    }

    float v[8];
#pragma unroll
    for (int t = 0; t < 8; ++t) v[t] = fmaxf(acc[t] + bias[c0 + t], 0.f);
    if (valid) {
        uint_t ow[4];
#pragma unroll
        for (int t = 0; t < 4; ++t) ow[t] = pkbf(v[2 * t], v[2 * t + 1]);
        *(uint4*)(out + (long)n * 64 + c0) = make_uint4(ow[0], ow[1], ow[2], ow[3]);
    }
    float s1[8], s2[8];
#pragma unroll
    for (int t = 0; t < 8; ++t) {
        s1[t] = valid ? v[t] : 0.f;
        s2[t] = valid ? v[t] * v[t] : 0.f;
    }
#pragma unroll
    for (int off = 8; off < 64; off <<= 1)    // reduce 8 octants (same cl -> same channels)
#pragma unroll
        for (int t = 0; t < 8; ++t) {
            s1[t] += __shfl_xor(s1[t], off, 64);
            s2[t] += __shfl_xor(s2[t], off, 64);
        }
    if (lane < 8) {
#pragma unroll
        for (int t = 0; t < 8; ++t) {
            atomicAdd(&ssum[c0 + t], s1[t]);
            atomicAdd(&ssq[c0 + t], s2[t]);
        }
    }
    __syncthreads();
    if (tid < 64) {
        atomicAdd(&stats[tid], ssum[tid]);
        atomicAdd(&stats[256 + tid], ssq[tid]);
    }
}

// ---------------- pool (BN affine fused) + FC, one block per graph; goff inlined (binary search) ----------------
__global__ __launch_bounds__(256) void pool_fc_kernel(const ushort_t* __restrict__ h,
                                                      const int* __restrict__ batch,
                                                      const float* __restrict__ stats,
                                                      const float* __restrict__ g3,
                                                      const float* __restrict__ be3,
                                                      const float* __restrict__ fcW,
                                                      const float* __restrict__ fcb,
                                                      float* __restrict__ out) {
    int g = blockIdx.x;
    __shared__ int se[2];
    if (threadIdx.x < 2) {
        int gg = g + threadIdx.x;
        int lo = 0, hi = N_NODES;
        while (lo < hi) {
            int mid = (lo + hi) >> 1;
            if (batch[mid] < gg) lo = mid + 1; else hi = mid;
        }
        se[threadIdx.x] = lo;
    }
    __syncthreads();
    int s = se[0], e = se[1];
    int c = threadIdx.x & 63;
    int ty = threadIdx.x >> 6;
    float sum = 0.f;
    for (int n = s + ty; n < e; n += 4) sum += bflo((uint_t)h[(long)n * 64 + c]);
    __shared__ float red[4][64];
    __shared__ float pv[64];
    red[ty][c] = sum;
    __syncthreads();
    if (ty == 0) {
        float tot = red[0][c] + red[1][c] + red[2][c] + red[3][c];
        float v = tot / fmaxf((float)(e - s), 1.f);
        float m = stats[c] * (1.f / N_NODES);
        float var = fmaxf(stats[256 + c] * (1.f / N_NODES) - m * m, 0.f);
        pv[c] = (v - m) * rsqrtf(var + EPS_BN) * g3[c] + be3[c];
    }
    __syncthreads();
    if (threadIdx.x < 10) {
        int j = threadIdx.x;
        float acc = fcb[j];
#pragma unroll
        for (int k = 0; k < 64; ++k) acc += pv[k] * fcW[k * 10 + j];
        out[g * 10 + j] = acc;
    }
}

extern "C" void kernel_launch(void* const* d_in, const int* in_sizes, int n_in,
                              void* d_out, int out_size, void* d_ws, size_t ws_size,
                              hipStream_t stream) {
    const float* x      = (const float*)d_in[0];
    const int*   ei     = (const int*)d_in[1];
    const int*   batch  = (const int*)d_in[2];
    const float* W1     = (const float*)d_in[3];
    const float* a_src1 = (const float*)d_in[4];
    const float* a_dst1 = (const float*)d_in[5];
    const float* b1     = (const float*)d_in[6];
    const float* g1     = (const float*)d_in[7];
    const float* be1    = (const float*)d_in[8];
    const float* W2     = (const float*)d_in[9];
    const float* a_src2 = (const float*)d_in[10];
    const float* a_dst2 = (const float*)d_in[11];
    const float* b2     = (const float*)d_in[12];
    const float* g2     = (const float*)d_in[13];
    const float* be2    = (const float*)d_in[14];
    const float* W3     = (const float*)d_in[15];
    const float* a_src3 = (const float*)d_in[16];
    const float* a_dst3 = (const float*)d_in[17];
    const float* b3     = (const float*)d_in[18];
    const float* g3     = (const float*)d_in[19];
    const float* be3    = (const float*)d_in[20];
    const float* fcW    = (const float*)d_in[21];
    const float* fcb    = (const float*)d_in[22];
    float* out = (float*)d_out;

    const size_t N = N_NODES, E = NUM_E;
    ushort_t* hbf    = (ushort_t*)d_ws;                 // [N,256] bf16 GEMM output
    ushort_t* hagg   = hbf + N * 256;                   // [N,256] bf16 agg output (pre-BN)
    ushort_t* xbf    = hagg + N * 256;                  // [N,128] bf16 x
    ushort_t* w1t    = xbf + N * 128;                   // [256][128]
    ushort_t* w2t    = w1t + 256 * 128;                 // [256][256]
    ushort_t* w3t    = w2t + 256 * 256;                 // [64][256]
    ushort_t* w2ts   = w3t + 64 * 256;                  // [256][256] BN-scaled
    ushort_t* w3ts   = w2ts + 256 * 256;                // [64][256]  BN-scaled
    float*    as_    = (float*)(w3ts + 64 * 256 + 128); // [N,4]
    float*    ad_    = as_ + N * 4;                     // [N,4]
    int*      deg    = (int*)(ad_ + N * 4);             // [N]   (zero region start)
    int*      fill   = deg + N;                         // [N]
    float*    statsA = (float*)(fill + N);              // [512]
    float*    statsB = statsA + 512;                    // [512]
    float*    statsC = statsB + 512;                    // [512]
    float*    cvec0  = statsC + 512;                    // [256] zeros (layer-1 cvec)
    int*      rowptr = (int*)(cvec0 + 256);             // [N+1]
    int*      srcs   = rowptr + (N + 1);                // [E]
    int*      bsum   = srcs + E;                        // [256]
    float*    cvec2  = (float*)(bsum + 256);            // [256]
    float*    cvec3  = cvec2 + 256;                     // [64]

    const int NB = (N_NODES + 255) / 256;  // 196
    const int HB = (NUM_E + 255) / 256;    // 3125
    const int SX = N_NODES * 128 / 4;
    const int SW = 128 * 256 + 256 * 256 + 256 * 64;
    const int PB = (SX + SW + 255) / 256;  // 6570

    // ---- setup (merged where independent; R9: grid.sync cooperative fusion = 5-10x slower) ----
    hipMemsetAsync(deg, 0, sizeof(int) * (2 * N + 3 * 512 + 256), stream);
    hist_prep_kernel<<<HB + PB, 256, 0, stream>>>(ei, deg, W1, W2, W3, x, w1t, w2t, w3t, xbf);
    scan_local_kernel<<<NB, 256, 0, stream>>>(deg, rowptr, bsum);
    scan_fixup_kernel<<<NB, 256, 0, stream>>>(rowptr, bsum);
    scatter_kernel<<<HB, 256, 0, stream>>>(ei, rowptr, fill, srcs);

    const int GB = (N_NODES + 127) / 128;  // 391
    const int AB = N_NODES / 16;           // 3125 (exact: 50000 % 16 == 0)

    // ---- layer 1: identity BN (cvec0 = zeros, W1 unscaled); stats fused into agg4 ----
    gemm_fused_kernel<128, 256, 128><<<dim3(GB, 2), 256, 0, stream>>>(
        xbf, w1t, hbf, cvec0, a_src1, a_dst1, as_, ad_);
    agg4_kernel<<<AB, 256, 0, stream>>>(hbf, as_, ad_, rowptr, srcs, b1, hagg, statsA);

    // ---- layer 2: fold BN1 into W2 ----
    scale_w_kernel<<<256, 256, 0, stream>>>(statsA, g1, be1, w2t, w2ts, cvec2);
    gemm_fused_kernel<256, 256, 128><<<dim3(GB, 2), 256, 0, stream>>>(
        hagg, w2ts, hbf, cvec2, a_src2, a_dst2, as_, ad_);
    agg4_kernel<<<AB, 256, 0, stream>>>(hbf, as_, ad_, rowptr, srcs, b2, hagg, statsB);

    // ---- layer 3: fold BN2 into W3 ----
    scale_w_kernel<<<64, 256, 0, stream>>>(statsB, g2, be2, w3t, w3ts, cvec3);
    gemm_fused_kernel<256, 64, 64><<<dim3(GB, 1), 256, 0, stream>>>(
        hagg, w3ts, hbf, cvec3, a_src3, a_dst3, as_, ad_);
    agg1_kernel<<<(N_NODES + 31) / 32, 256, 0, stream>>>(hbf, as_, ad_, rowptr, srcs, b3, hagg, statsC);

    // ---- pool + BN3 affine + FC in one (goff inlined) ----
    pool_fc_kernel<<<NUM_GRAPHS, 256, 0, stream>>>(hagg, batch, statsC, g3, be3, fcW, fcb, out);
}

// Round 6
// 526.476 us; speedup vs baseline: 1.1919x; 1.1919x over previous
//
#include <hip/hip_runtime.h>
#include <hip/hip_bf16.h>

#define N_NODES 50000
#define NUM_E   800000
#define EPS_BN  1e-5f
#define NUM_GRAPHS 64
#define NCOPY 64   // striped stats copies (kills global-atomic serialization, R5 post-mortem)

typedef __attribute__((ext_vector_type(8))) short bf16x8;
typedef __attribute__((ext_vector_type(4))) float f32x4;
typedef unsigned short ushort_t;
typedef unsigned int uint_t;

static __device__ __forceinline__ unsigned short f2bf(float f) {
    unsigned int u = __float_as_uint(f);
    u += 0x7fffu + ((u >> 16) & 1u);   // RNE
    return (unsigned short)(u >> 16);
}
static __device__ __forceinline__ uint_t pkbf(float lo, float hi) {
    __hip_bfloat162 t = __float22bfloat162_rn(make_float2(lo, hi));
    return *(uint_t*)&t;
}
static __device__ __forceinline__ float bflo(uint_t u) { return __uint_as_float(u << 16); }
static __device__ __forceinline__ float bfhi(uint_t u) { return __uint_as_float(u & 0xffff0000u); }

// ---------------- hist + prep merged (independent work, block-range split) ----------------
__global__ void hist_prep_kernel(const int* __restrict__ ei, int* __restrict__ deg,
                                 const float* __restrict__ W1, const float* __restrict__ W2,
                                 const float* __restrict__ W3, const float* __restrict__ x,
                                 ushort_t* __restrict__ w1t, ushort_t* __restrict__ w2t,
                                 ushort_t* __restrict__ w3t, ushort_t* __restrict__ xbf) {
    const int HB = (NUM_E + 255) / 256;          // 3125 hist blocks
    const int S1 = 128 * 256, S2 = 256 * 256, S3 = 256 * 64;
    const int SW = S1 + S2 + S3;                 // 81920
    const int SX = N_NODES * 128 / 4;            // 1.6M float4 units
    int b = blockIdx.x;
    if (b < HB) {
        int e = b * 256 + threadIdx.x;
        if (e < NUM_E) atomicAdd(&deg[ei[NUM_E + e]], 1);
        return;
    }
    int i = (b - HB) * 256 + threadIdx.x;
    if (i < SX) {
        float4 v = ((const float4*)x)[i];
        ((uint2*)xbf)[i] = make_uint2(pkbf(v.x, v.y), pkbf(v.z, v.w));
    } else if (i < SX + SW) {
        int j = i - SX;
        if (j < S1) {
            int k = j / 256, n = j % 256;
            w1t[n * 128 + k] = f2bf(W1[j]);
        } else if (j < S1 + S2) {
            int jj = j - S1; int k = jj / 256, n = jj % 256;
            w2t[n * 256 + k] = f2bf(W2[jj]);
        } else {
            int jj = j - S1 - S2; int k = jj / 64, n = jj % 64;
            w3t[n * 256 + k] = f2bf(W3[jj]);
        }
    }
}

__global__ void scan_local_kernel(const int* __restrict__ deg, int* __restrict__ rowptr,
                                  int* __restrict__ bsum) {
    __shared__ int ws[4];
    int b = blockIdx.x, t = threadIdx.x;
    int i = b * 256 + t;
    int lane = t & 63, wv = t >> 6;
    int v = (i < N_NODES) ? deg[i] : 0;
    int incl = v;
#pragma unroll
    for (int off = 1; off < 64; off <<= 1) {
        int u = __shfl_up(incl, off, 64);
        if (lane >= off) incl += u;
    }
    if (lane == 63) ws[wv] = incl;
    __syncthreads();
    if (t == 0) {
        int s = 0;
#pragma unroll
        for (int k = 0; k < 4; ++k) { int x = ws[k]; ws[k] = s; s += x; }
        bsum[b] = s;
    }
    __syncthreads();
    if (i < N_NODES) rowptr[i + 1] = ws[wv] + incl;
}

// merged scan_sums + scan_add: each block redundantly sums its bsum prefix (196 entries, trivial)
__global__ __launch_bounds__(256) void scan_fixup_kernel(int* __restrict__ rowptr,
                                                         const int* __restrict__ bsum) {
    __shared__ int ws[4];
    int b = blockIdx.x, t = threadIdx.x;
    int lane = t & 63, wv = t >> 6;
    int v = (t < b) ? bsum[t] : 0;   // b <= 195 < 256, t < b => valid index
#pragma unroll
    for (int off = 1; off < 64; off <<= 1) v += __shfl_xor(v, off, 64);
    if (lane == 0) ws[wv] = v;
    __syncthreads();
    int pre = ws[0] + ws[1] + ws[2] + ws[3];
    int i = b * 256 + t;
    if (i < N_NODES) rowptr[i + 1] += pre;
    if (b == 0 && t == 0) rowptr[0] = 0;
}

__global__ void scatter_kernel(const int* __restrict__ ei, const int* __restrict__ rowptr,
                               int* __restrict__ fill, int* __restrict__ srcs) {
    int e = blockIdx.x * blockDim.x + threadIdx.x;
    if (e >= NUM_E) return;
    int dst = ei[NUM_E + e];
    int pos = rowptr[dst] + atomicAdd(&fill[dst], 1);
    srcs[pos] = ei[e];
}

// ---------------- BN fold into W (reduces NCOPY striped stats copies first) ----------------
__global__ __launch_bounds__(256) void scale_w_kernel(const float* __restrict__ stats,
                                                      const float* __restrict__ g,
                                                      const float* __restrict__ be,
                                                      const ushort_t* __restrict__ wt,
                                                      ushort_t* __restrict__ wts,
                                                      float* __restrict__ cvec) {
    int n = blockIdx.x, k = threadIdx.x;
    float s0 = 0.f, s1 = 0.f;
#pragma unroll 8
    for (int j = 0; j < NCOPY; ++j) {          // 128KB, L2-resident across blocks
        s0 += stats[j * 512 + k];
        s1 += stats[j * 512 + 256 + k];
    }
    float m = s0 * (1.f / N_NODES);
    float var = fmaxf(s1 * (1.f / N_NODES) - m * m, 0.f);
    float rs = rsqrtf(var + EPS_BN) * g[k];
    float b = be[k] - m * rs;
    float wv = bflo((uint_t)wt[n * 256 + k]);
    wts[n * 256 + k] = f2bf(rs * wv);
    float p = b * wv;
    __shared__ float ws[4];
    int lane = k & 63, wid = k >> 6;
#pragma unroll
    for (int off = 1; off < 64; off <<= 1) p += __shfl_xor(p, off, 64);
    if (lane == 0) ws[wid] = p;
    __syncthreads();
    if (k == 0) cvec[n] = ws[0] + ws[1] + ws[2] + ws[3];
}

// ---------------- GEMM: A(bf16) @ Bt^T + cvec -> h(bf16) + per-head logits ----------------
template<int K, int NFULL, int BN>
__global__ __launch_bounds__(256) void gemm_fused_kernel(const ushort_t* __restrict__ A,
                                                         const ushort_t* __restrict__ Bt,
                                                         ushort_t* __restrict__ C,
                                                         const float* __restrict__ cvec,
                                                         const float* __restrict__ a_src,
                                                         const float* __restrict__ a_dst,
                                                         float* __restrict__ as_,
                                                         float* __restrict__ ad_) {
    const int NT = BN / 16;
    const int NG = BN / 64;
    constexpr int LOOP_BYTES = (128 * 40 + BN * 40) * 2;
    constexpr int EPI_BYTES  = 4 * 32 * 64 * 2;
    constexpr int SMEM_BYTES = LOOP_BYTES > EPI_BYTES ? LOOP_BYTES : EPI_BYTES;
    __shared__ __align__(16) unsigned char smem[SMEM_BYTES];
    ushort_t (*As)[40]     = (ushort_t (*)[40])smem;                       // [128][40]
    ushort_t (*Bs)[40]     = (ushort_t (*)[40])(smem + 128 * 40 * 2);      // [BN][40]
    ushort_t (*Cs)[32][64] = (ushort_t (*)[32][64])smem;                   // [4][32][64] (aliases As/Bs)
    __shared__ float cvec_s[BN];
    __shared__ float asrc_s[BN], adst_s[BN];
    int tid = threadIdx.x;
    int lane = tid & 63, w = tid >> 6;
    int row0 = blockIdx.x * 128, col0 = blockIdx.y * BN;
    int m_l = lane & 15, q = lane >> 4;

    if (tid < BN) {
        cvec_s[tid] = cvec[col0 + tid];
        asrc_s[tid] = a_src[col0 + tid];
        adst_s[tid] = a_dst[col0 + tid];
    }
    __syncthreads();

    f32x4 acc[2][NT];
#pragma unroll
    for (int r = 0; r < 2; ++r)
#pragma unroll
        for (int c = 0; c < NT; ++c) acc[r][c] = (f32x4){0.f, 0.f, 0.f, 0.f};

    int ar = tid >> 1, ako = (tid & 1) * 16;

    for (int k0 = 0; k0 < K; k0 += 32) {
        int gr = row0 + ar;
        uint4 u0 = make_uint4(0, 0, 0, 0), u1 = make_uint4(0, 0, 0, 0);
        if (gr < N_NODES) {
            const ushort_t* ap = A + (long)gr * K + k0 + ako;
            u0 = *(const uint4*)ap;
            u1 = *(const uint4*)(ap + 8);
        }
        if constexpr (BN == 128) {
            int br = tid >> 1, bko = (tid & 1) * 16;
            const ushort_t* bp = Bt + (long)(col0 + br) * K + k0 + bko;
            uint4 b0 = *(const uint4*)bp;
            uint4 b1 = *(const uint4*)(bp + 8);
            *(uint4*)&As[ar][ako] = u0;
            *(uint4*)&As[ar][ako + 8] = u1;
            *(uint4*)&Bs[br][bko] = b0;
            *(uint4*)&Bs[br][bko + 8] = b1;
        } else {
            int br = tid >> 2, bko = (tid & 3) * 8;
            uint4 bv = *(const uint4*)(Bt + (long)(col0 + br) * K + k0 + bko);
            *(uint4*)&As[ar][ako] = u0;
            *(uint4*)&As[ar][ako + 8] = u1;
            *(uint4*)&Bs[br][bko] = bv;
        }
        __syncthreads();

        bf16x8 af[2];
#pragma unroll
        for (int r = 0; r < 2; ++r)
            af[r] = *(const bf16x8*)&As[w * 32 + r * 16 + m_l][q * 8];
#pragma unroll
        for (int c = 0; c < NT; ++c) {
            bf16x8 bf = *(const bf16x8*)&Bs[c * 16 + m_l][q * 8];
#pragma unroll
            for (int r = 0; r < 2; ++r)
                acc[r][c] = __builtin_amdgcn_mfma_f32_16x16x32_bf16(af[r], bf, acc[r][c], 0, 0, 0);
        }
        __syncthreads();   // after this barrier As/Bs are dead -> Cs may alias
    }

    const int H = NFULL / 64;
#pragma unroll
    for (int gblk = 0; gblk < NG; ++gblk) {
        int hidx = blockIdx.y * NG + gblk;
        int colg = col0 + gblk * 64;
#pragma unroll
        for (int r = 0; r < 2; ++r)
#pragma unroll
            for (int cc = 0; cc < 4; ++cc)
#pragma unroll
                for (int i = 0; i < 4; ++i)
                    Cs[w][r * 16 + q * 4 + i][cc * 16 + m_l] =
                        f2bf(acc[r][gblk * 4 + cc][i] + cvec_s[gblk * 64 + cc * 16 + m_l]);
        // same-wave LDS RAW: in-order DS pipe, no barrier needed
#pragma unroll
        for (int j = 0; j < 4; ++j) {
            int flat = j * 64 + lane;
            int lr = flat >> 3, chg = flat & 7;
            int gr = row0 + w * 32 + lr;
            uint4 u = *(uint4*)&Cs[w][lr][chg * 8];
            float f0 = bflo(u.x), f1 = bfhi(u.x), f2 = bflo(u.y), f3 = bfhi(u.y);
            float f4 = bflo(u.z), f5 = bfhi(u.z), f6 = bflo(u.w), f7 = bfhi(u.w);
            int cb = gblk * 64 + chg * 8;
            float s1 = f0 * asrc_s[cb] + f1 * asrc_s[cb + 1] + f2 * asrc_s[cb + 2] + f3 * asrc_s[cb + 3]
                     + f4 * asrc_s[cb + 4] + f5 * asrc_s[cb + 5] + f6 * asrc_s[cb + 6] + f7 * asrc_s[cb + 7];
            float s2 = f0 * adst_s[cb] + f1 * adst_s[cb + 1] + f2 * adst_s[cb + 2] + f3 * adst_s[cb + 3]
                     + f4 * adst_s[cb + 4] + f5 * adst_s[cb + 5] + f6 * adst_s[cb + 6] + f7 * adst_s[cb + 7];
#pragma unroll
            for (int o = 1; o < 8; o <<= 1) {
                s1 += __shfl_xor(s1, o, 64);
                s2 += __shfl_xor(s2, o, 64);
            }
            if (gr < N_NODES) {
                *(uint4*)(C + (long)gr * NFULL + colg + chg * 8) = u;
                if ((lane & 7) == 0) {
                    as_[gr * H + hidx] = s1;
                    ad_[gr * H + hidx] = s2;
                }
            }
        }
    }
}

// ---------------- GAT aggregation H=4 + fused BN stats (NCOPY-striped: ~49 atomics/address) ----------------
__global__ __launch_bounds__(256) void agg4_kernel(const ushort_t* __restrict__ h,
                                                   const float* __restrict__ as_,
                                                   const float* __restrict__ ad_,
                                                   const int* __restrict__ rowptr,
                                                   const int* __restrict__ srcs,
                                                   const float* __restrict__ bias,
                                                   ushort_t* __restrict__ out,
                                                   float* __restrict__ stats) {
    __shared__ float4 alf[4][4][17];   // [wave][quarter][edge] 4 head alphas (pad 17)
    __shared__ int    sed[4][4][17];   // [wave][quarter][edge] src id
    __shared__ float  ssum[256], ssq[256];
    int tid = threadIdx.x;
    int lane = tid & 63, w = tid >> 6;
    int q = lane >> 4, cl = lane & 15;
    int n = blockIdx.x * 16 + w * 4 + q;   // grid exact: n < N_NODES always
    ssum[tid] = 0.f; ssq[tid] = 0.f;
    __syncthreads();

    int start = rowptr[n];
    int deg = rowptr[n + 1] - start;

    float4 adv = *(const float4*)(ad_ + n * 4);
    float ad4[4] = {adv.x, adv.y, adv.z, adv.w};

    float mx[4] = {-1e30f, -1e30f, -1e30f, -1e30f};
    float dn[4] = {0.f, 0.f, 0.f, 0.f};
    {
        float vst[4] = {-1e30f, -1e30f, -1e30f, -1e30f};
        int s0 = 0;
        if (deg > 0) s0 = srcs[start + min(cl, deg - 1)];
        sed[w][q][cl] = s0;
        if (cl < deg) {
            float4 av = *(const float4*)(as_ + s0 * 4);
            float vv[4] = {av.x + ad4[0], av.y + ad4[1], av.z + ad4[2], av.w + ad4[3]};
#pragma unroll
            for (int hh = 0; hh < 4; ++hh) {
                float v = vv[hh] > 0.f ? vv[hh] : 0.2f * vv[hh];
                vst[hh] = v; mx[hh] = v; dn[hh] = 1.f;
            }
        }
        alf[w][q][cl] = make_float4(vst[0], vst[1], vst[2], vst[3]);
        for (int j = cl + 16; j < deg; j += 16) {
            int s = srcs[start + j];
            float4 av = *(const float4*)(as_ + s * 4);
            float vv[4] = {av.x + ad4[0], av.y + ad4[1], av.z + ad4[2], av.w + ad4[3]};
#pragma unroll
            for (int hh = 0; hh < 4; ++hh) {
                float v = vv[hh] > 0.f ? vv[hh] : 0.2f * vv[hh];
                float mn = fmaxf(mx[hh], v);
                dn[hh] = dn[hh] * __expf(mx[hh] - mn) + __expf(v - mn);
                mx[hh] = mn;
            }
        }
    }
    float mloc[4] = {mx[0], mx[1], mx[2], mx[3]};
#pragma unroll
    for (int off = 1; off < 16; off <<= 1)
#pragma unroll
        for (int hh = 0; hh < 4; ++hh) mx[hh] = fmaxf(mx[hh], __shfl_xor(mx[hh], off, 64));
#pragma unroll
    for (int hh = 0; hh < 4; ++hh) dn[hh] *= __expf(mloc[hh] - mx[hh]);
#pragma unroll
    for (int off = 1; off < 16; off <<= 1)
#pragma unroll
        for (int hh = 0; hh < 4; ++hh) dn[hh] += __shfl_xor(dn[hh], off, 64);
    float inv[4];
#pragma unroll
    for (int hh = 0; hh < 4; ++hh) inv[hh] = dn[hh] > 0.f ? 1.f / dn[hh] : 0.f;
    {
        float4 vv = alf[w][q][cl];   // logits -> alphas (OOB lanes: exp(-1e30-mx)=0)
        alf[w][q][cl] = make_float4(__expf(vv.x - mx[0]) * inv[0], __expf(vv.y - mx[1]) * inv[1],
                                    __expf(vv.z - mx[2]) * inv[2], __expf(vv.w - mx[3]) * inv[3]);
    }

    int hd = cl >> 2, cbase = cl * 16;
    float acc[16];
#pragma unroll
    for (int k = 0; k < 16; ++k) acc[k] = 0.f;

    for (int chunk = 0; chunk < deg || chunk == 0; chunk += 16) {
        if (chunk > 0) {
            int j = chunk + cl;
            int s = srcs[start + min(j, deg - 1)];
            sed[w][q][cl] = s;
            float a4[4] = {0.f, 0.f, 0.f, 0.f};
            if (j < deg) {
                float4 av = *(const float4*)(as_ + s * 4);
                float vv[4] = {av.x + ad4[0], av.y + ad4[1], av.z + ad4[2], av.w + ad4[3]};
#pragma unroll
                for (int hh = 0; hh < 4; ++hh) {
                    float v = vv[hh] > 0.f ? vv[hh] : 0.2f * vv[hh];
                    a4[hh] = __expf(v - mx[hh]) * inv[hh];
                }
            }
            alf[w][q][cl] = make_float4(a4[0], a4[1], a4[2], a4[3]);
        }
        int cnt = min(16, deg - chunk);
        if (cnt < 0) cnt = 0;
        int e = 0;
        // 4-edge groups, half-row batches: 4 uint4 in flight, 2 batches per group
        for (; e + 4 <= cnt; e += 4) {
            float av[4]; int sv[4];
#pragma unroll
            for (int t = 0; t < 4; ++t) {
                av[t] = ((const float*)&alf[w][q][e + t])[hd];
                sv[t] = sed[w][q][e + t];
            }
            uint4 ua[4];
#pragma unroll
            for (int t = 0; t < 4; ++t)
                ua[t] = *(const uint4*)(h + (long)sv[t] * 256 + cbase);
#pragma unroll
            for (int t = 0; t < 4; ++t) {
                float al = av[t];
                acc[0] += al * bflo(ua[t].x); acc[1] += al * bfhi(ua[t].x);
                acc[2] += al * bflo(ua[t].y); acc[3] += al * bfhi(ua[t].y);
                acc[4] += al * bflo(ua[t].z); acc[5] += al * bfhi(ua[t].z);
                acc[6] += al * bflo(ua[t].w); acc[7] += al * bfhi(ua[t].w);
            }
#pragma unroll
            for (int t = 0; t < 4; ++t)
                ua[t] = *(const uint4*)(h + (long)sv[t] * 256 + cbase + 8);
#pragma unroll
            for (int t = 0; t < 4; ++t) {
                float al = av[t];
                acc[8]  += al * bflo(ua[t].x); acc[9]  += al * bfhi(ua[t].x);
                acc[10] += al * bflo(ua[t].y); acc[11] += al * bfhi(ua[t].y);
                acc[12] += al * bflo(ua[t].z); acc[13] += al * bfhi(ua[t].z);
                acc[14] += al * bflo(ua[t].w); acc[15] += al * bfhi(ua[t].w);
            }
        }
        for (; e < cnt; ++e) {   // exact tail, 1 edge
            float al = ((const float*)&alf[w][q][e])[hd];
            const ushort_t* hr = h + (long)sed[w][q][e] * 256 + cbase;
            uint4 u0 = *(const uint4*)hr;
            uint4 u1 = *(const uint4*)(hr + 8);
            acc[0]  += al * bflo(u0.x); acc[1]  += al * bfhi(u0.x);
            acc[2]  += al * bflo(u0.y); acc[3]  += al * bfhi(u0.y);
            acc[4]  += al * bflo(u0.z); acc[5]  += al * bfhi(u0.z);
            acc[6]  += al * bflo(u0.w); acc[7]  += al * bfhi(u0.w);
            acc[8]  += al * bflo(u1.x); acc[9]  += al * bfhi(u1.x);
            acc[10] += al * bflo(u1.y); acc[11] += al * bfhi(u1.y);
            acc[12] += al * bflo(u1.z); acc[13] += al * bfhi(u1.z);
            acc[14] += al * bflo(u1.w); acc[15] += al * bfhi(u1.w);
        }
        if (deg <= 16) break;
    }

    // epilogue: bias + relu into acc (in place), bf16 store, fused BN-stat partials
#pragma unroll
    for (int t = 0; t < 16; ++t) acc[t] = fmaxf(acc[t] + bias[cbase + t], 0.f);
    uint_t ow[8];
#pragma unroll
    for (int t = 0; t < 8; ++t) ow[t] = pkbf(acc[2 * t], acc[2 * t + 1]);
    ushort_t* op = out + (long)n * 256 + cbase;
    *(uint4*)op = make_uint4(ow[0], ow[1], ow[2], ow[3]);
    *(uint4*)(op + 8) = make_uint4(ow[4], ow[5], ow[6], ow[7]);

#pragma unroll
    for (int t = 0; t < 16; ++t) {   // reduce 4 quarters (same cl -> same channels)
        float a = acc[t], sq = a * a;
        a  += __shfl_xor(a, 16, 64);  a  += __shfl_xor(a, 32, 64);
        sq += __shfl_xor(sq, 16, 64); sq += __shfl_xor(sq, 32, 64);
        if (lane < 16) {
            atomicAdd(&ssum[cbase + t], a);
            atomicAdd(&ssq[cbase + t], sq);
        }
    }
    __syncthreads();
    int cp = (blockIdx.x & (NCOPY - 1)) * 512;   // striped copy: ~49 blocks/address
    atomicAdd(&stats[cp + tid], ssum[tid]);
    atomicAdd(&stats[cp + 256 + tid], ssq[tid]);
}

// ---------------- GAT aggregation H=1: fused BN stats (striped) ----------------
__global__ __launch_bounds__(256) void agg1_kernel(const ushort_t* __restrict__ h,
                                                   const float* __restrict__ as_,
                                                   const float* __restrict__ ad_,
                                                   const int* __restrict__ rowptr,
                                                   const int* __restrict__ srcs,
                                                   const float* __restrict__ bias,
                                                   ushort_t* __restrict__ out,
                                                   float* __restrict__ stats) {
    __shared__ float alf1[4][8][9];
    __shared__ int   sed1[4][8][9];
    __shared__ float ssum[64], ssq[64];
    int tid = threadIdx.x;
    int lane = tid & 63, w = tid >> 6;
    int o = lane >> 3, cl = lane & 7;
    int n = blockIdx.x * 32 + w * 8 + o;
    bool valid = n < N_NODES;
    int nc = valid ? n : N_NODES - 1;
    if (tid < 64) { ssum[tid] = 0.f; ssq[tid] = 0.f; }
    __syncthreads();

    int start = rowptr[nc];
    int deg = valid ? rowptr[nc + 1] - start : 0;
    float adn = ad_[nc];

    float mx = -1e30f, dn = 0.f;
    {
        float vst = -1e30f;
        int s0 = 0;
        if (deg > 0) s0 = srcs[start + min(cl, deg - 1)];
        sed1[w][o][cl] = s0;
        if (cl < deg) {
            float v = as_[s0] + adn;
            v = v > 0.f ? v : 0.2f * v;
            vst = v; mx = v; dn = 1.f;
        }
        alf1[w][o][cl] = vst;
        for (int j = cl + 8; j < deg; j += 8) {
            int s = srcs[start + j];
            float v = as_[s] + adn;
            v = v > 0.f ? v : 0.2f * v;
            float mn = fmaxf(mx, v);
            dn = dn * __expf(mx - mn) + __expf(v - mn);
            mx = mn;
        }
    }
    float mloc = mx;
#pragma unroll
    for (int off = 1; off < 8; off <<= 1) mx = fmaxf(mx, __shfl_xor(mx, off, 64));
    dn *= __expf(mloc - mx);
#pragma unroll
    for (int off = 1; off < 8; off <<= 1) dn += __shfl_xor(dn, off, 64);
    float inv = dn > 0.f ? 1.f / dn : 0.f;

    alf1[w][o][cl] = __expf(alf1[w][o][cl] - mx) * inv;

    int c0 = cl * 8;
    float acc[8] = {0.f, 0.f, 0.f, 0.f, 0.f, 0.f, 0.f, 0.f};

    for (int chunk = 0; chunk < deg || chunk == 0; chunk += 8) {
        if (chunk > 0) {
            int j = chunk + cl;
            int s = srcs[start + min(j, deg - 1)];
            sed1[w][o][cl] = s;
            float al = 0.f;
            if (j < deg) {
                float v = as_[s] + adn;
                v = v > 0.f ? v : 0.2f * v;
                al = __expf(v - mx) * inv;
            }
            alf1[w][o][cl] = al;
        }
        int cnt = min(8, deg - chunk);
        if (cnt < 0) cnt = 0;
        int e = 0;
        for (; e + 4 <= cnt; e += 4) {
            float av[4]; int sv[4];
#pragma unroll
            for (int t = 0; t < 4; ++t) {
                av[t] = alf1[w][o][e + t];
                sv[t] = sed1[w][o][e + t];
            }
            uint4 ua[4];
#pragma unroll
            for (int t = 0; t < 4; ++t)
                ua[t] = *(const uint4*)(h + (long)sv[t] * 64 + c0);
#pragma unroll
            for (int t = 0; t < 4; ++t) {
                float al = av[t];
                acc[0] += al * bflo(ua[t].x); acc[1] += al * bfhi(ua[t].x);
                acc[2] += al * bflo(ua[t].y); acc[3] += al * bfhi(ua[t].y);
                acc[4] += al * bflo(ua[t].z); acc[5] += al * bfhi(ua[t].z);
                acc[6] += al * bflo(ua[t].w); acc[7] += al * bfhi(ua[t].w);
            }
        }
        for (; e < cnt; ++e) {
            float al = alf1[w][o][e];
            uint4 u = *(const uint4*)(h + (long)sed1[w][o][e] * 64 + c0);
            acc[0] += al * bflo(u.x); acc[1] += al * bfhi(u.x);
            acc[2] += al * bflo(u.y); acc[3] += al * bfhi(u.y);
            acc[4] += al * bflo(u.z); acc[5] += al * bfhi(u.z);
            acc[6] += al * bflo(u.w); acc[7] += al * bfhi(u.w);
        }
        if (deg <= 8) break;
    }

    float v[8];
#pragma unroll
    for (int t = 0; t < 8; ++t) v[t] = fmaxf(acc[t] + bias[c0 + t], 0.f);
    if (valid) {
        uint_t ow[4];
#pragma unroll
        for (int t = 0; t < 4; ++t) ow[t] = pkbf(v[2 * t], v[2 * t + 1]);
        *(uint4*)(out + (long)n * 64 + c0) = make_uint4(ow[0], ow[1], ow[2], ow[3]);
    }
    float s1[8], s2[8];
#pragma unroll
    for (int t = 0; t < 8; ++t) {
        s1[t] = valid ? v[t] : 0.f;
        s2[t] = valid ? v[t] * v[t] : 0.f;
    }
#pragma unroll
    for (int off = 8; off < 64; off <<= 1)    // reduce 8 octants (same cl -> same channels)
#pragma unroll
        for (int t = 0; t < 8; ++t) {
            s1[t] += __shfl_xor(s1[t], off, 64);
            s2[t] += __shfl_xor(s2[t], off, 64);
        }
    if (lane < 8) {
#pragma unroll
        for (int t = 0; t < 8; ++t) {
            atomicAdd(&ssum[c0 + t], s1[t]);
            atomicAdd(&ssq[c0 + t], s2[t]);
        }
    }
    __syncthreads();
    if (tid < 64) {
        int cp = (blockIdx.x & (NCOPY - 1)) * 512;   // striped copy
        atomicAdd(&stats[cp + tid], ssum[tid]);
        atomicAdd(&stats[cp + 256 + tid], ssq[tid]);
    }
}

// ---------------- pool (BN affine fused, striped-stats reduce) + FC; goff inlined ----------------
__global__ __launch_bounds__(256) void pool_fc_kernel(const ushort_t* __restrict__ h,
                                                      const int* __restrict__ batch,
                                                      const float* __restrict__ stats,
                                                      const float* __restrict__ g3,
                                                      const float* __restrict__ be3,
                                                      const float* __restrict__ fcW,
                                                      const float* __restrict__ fcb,
                                                      float* __restrict__ out) {
    int g = blockIdx.x;
    __shared__ int se[2];
    if (threadIdx.x < 2) {
        int gg = g + threadIdx.x;
        int lo = 0, hi = N_NODES;
        while (lo < hi) {
            int mid = (lo + hi) >> 1;
            if (batch[mid] < gg) lo = mid + 1; else hi = mid;
        }
        se[threadIdx.x] = lo;
    }
    __syncthreads();
    int s = se[0], e = se[1];
    int c = threadIdx.x & 63;
    int ty = threadIdx.x >> 6;
    float sum = 0.f;
    for (int n = s + ty; n < e; n += 4) sum += bflo((uint_t)h[(long)n * 64 + c]);
    __shared__ float red[4][64];
    __shared__ float pv[64];
    red[ty][c] = sum;
    __syncthreads();
    if (ty == 0) {
        float tot = red[0][c] + red[1][c] + red[2][c] + red[3][c];
        float v = tot / fmaxf((float)(e - s), 1.f);
        float s0 = 0.f, s1 = 0.f;
#pragma unroll 8
        for (int j = 0; j < NCOPY; ++j) {
            s0 += stats[j * 512 + c];
            s1 += stats[j * 512 + 256 + c];
        }
        float m = s0 * (1.f / N_NODES);
        float var = fmaxf(s1 * (1.f / N_NODES) - m * m, 0.f);
        pv[c] = (v - m) * rsqrtf(var + EPS_BN) * g3[c] + be3[c];
    }
    __syncthreads();
    if (threadIdx.x < 10) {
        int j = threadIdx.x;
        float acc = fcb[j];
#pragma unroll
        for (int k = 0; k < 64; ++k) acc += pv[k] * fcW[k * 10 + j];
        out[g * 10 + j] = acc;
    }
}

extern "C" void kernel_launch(void* const* d_in, const int* in_sizes, int n_in,
                              void* d_out, int out_size, void* d_ws, size_t ws_size,
                              hipStream_t stream) {
    const float* x      = (const float*)d_in[0];
    const int*   ei     = (const int*)d_in[1];
    const int*   batch  = (const int*)d_in[2];
    const float* W1     = (const float*)d_in[3];
    const float* a_src1 = (const float*)d_in[4];
    const float* a_dst1 = (const float*)d_in[5];
    const float* b1     = (const float*)d_in[6];
    const float* g1     = (const float*)d_in[7];
    const float* be1    = (const float*)d_in[8];
    const float* W2     = (const float*)d_in[9];
    const float* a_src2 = (const float*)d_in[10];
    const float* a_dst2 = (const float*)d_in[11];
    const float* b2     = (const float*)d_in[12];
    const float* g2     = (const float*)d_in[13];
    const float* be2    = (const float*)d_in[14];
    const float* W3     = (const float*)d_in[15];
    const float* a_src3 = (const float*)d_in[16];
    const float* a_dst3 = (const float*)d_in[17];
    const float* b3     = (const float*)d_in[18];
    const float* g3     = (const float*)d_in[19];
    const float* be3    = (const float*)d_in[20];
    const float* fcW    = (const float*)d_in[21];
    const float* fcb    = (const float*)d_in[22];
    float* out = (float*)d_out;

    const size_t N = N_NODES, E = NUM_E;
    const int SST = NCOPY * 512;                        // striped stats size
    ushort_t* hbf    = (ushort_t*)d_ws;                 // [N,256] bf16 GEMM output
    ushort_t* hagg   = hbf + N * 256;                   // [N,256] bf16 agg output (pre-BN)
    ushort_t* xbf    = hagg + N * 256;                  // [N,128] bf16 x
    ushort_t* w1t    = xbf + N * 128;                   // [256][128]
    ushort_t* w2t    = w1t + 256 * 128;                 // [256][256]
    ushort_t* w3t    = w2t + 256 * 256;                 // [64][256]
    ushort_t* w2ts   = w3t + 64 * 256;                  // [256][256] BN-scaled
    ushort_t* w3ts   = w2ts + 256 * 256;                // [64][256]  BN-scaled
    float*    as_    = (float*)(w3ts + 64 * 256 + 128); // [N,4]
    float*    ad_    = as_ + N * 4;                     // [N,4]
    int*      deg    = (int*)(ad_ + N * 4);             // [N]   (zero region start)
    int*      fill   = deg + N;                         // [N]
    float*    statsA = (float*)(fill + N);              // [NCOPY*512]
    float*    statsB = statsA + SST;                    // [NCOPY*512]
    float*    statsC = statsB + SST;                    // [NCOPY*512]
    float*    cvec0  = statsC + SST;                    // [256] zeros (layer-1 cvec)
    int*      rowptr = (int*)(cvec0 + 256);             // [N+1]
    int*      srcs   = rowptr + (N + 1);                // [E]
    int*      bsum   = srcs + E;                        // [256]
    float*    cvec2  = (float*)(bsum + 256);            // [256]
    float*    cvec3  = cvec2 + 256;                     // [64]

    const int NB = (N_NODES + 255) / 256;  // 196
    const int HB = (NUM_E + 255) / 256;    // 3125
    const int SX = N_NODES * 128 / 4;
    const int SW = 128 * 256 + 256 * 256 + 256 * 64;
    const int PB = (SX + SW + 255) / 256;  // 6570

    // ---- setup (merged where independent; R9: grid.sync cooperative fusion = 5-10x slower) ----
    hipMemsetAsync(deg, 0, sizeof(int) * (2 * N + 3 * SST + 256), stream);
    hist_prep_kernel<<<HB + PB, 256, 0, stream>>>(ei, deg, W1, W2, W3, x, w1t, w2t, w3t, xbf);
    scan_local_kernel<<<NB, 256, 0, stream>>>(deg, rowptr, bsum);
    scan_fixup_kernel<<<NB, 256, 0, stream>>>(rowptr, bsum);
    scatter_kernel<<<HB, 256, 0, stream>>>(ei, rowptr, fill, srcs);

    const int GB = (N_NODES + 127) / 128;  // 391
    const int AB = N_NODES / 16;           // 3125 (exact: 50000 % 16 == 0)

    // ---- layer 1: identity BN (cvec0 = zeros, W1 unscaled); stats fused into agg4 ----
    gemm_fused_kernel<128, 256, 128><<<dim3(GB, 2), 256, 0, stream>>>(
        xbf, w1t, hbf, cvec0, a_src1, a_dst1, as_, ad_);
    agg4_kernel<<<AB, 256, 0, stream>>>(hbf, as_, ad_, rowptr, srcs, b1, hagg, statsA);

    // ---- layer 2: fold BN1 into W2 ----
    scale_w_kernel<<<256, 256, 0, stream>>>(statsA, g1, be1, w2t, w2ts, cvec2);
    gemm_fused_kernel<256, 256, 128><<<dim3(GB, 2), 256, 0, stream>>>(
        hagg, w2ts, hbf, cvec2, a_src2, a_dst2, as_, ad_);
    agg4_kernel<<<AB, 256, 0, stream>>>(hbf, as_, ad_, rowptr, srcs, b2, hagg, statsB);

    // ---- layer 3: fold BN2 into W3 ----
    scale_w_kernel<<<64, 256, 0, stream>>>(statsB, g2, be2, w3t, w3ts, cvec3);
    gemm_fused_kernel<256, 64, 64><<<dim3(GB, 1), 256, 0, stream>>>(
        hagg, w3ts, hbf, cvec3, a_src3, a_dst3, as_, ad_);
    agg1_kernel<<<(N_NODES + 31) / 32, 256, 0, stream>>>(hbf, as_, ad_, rowptr, srcs, b3, hagg, statsC);

    // ---- pool + BN3 affine + FC in one (goff inlined, striped-stats reduce) ----
    pool_fc_kernel<<<NUM_GRAPHS, 256, 0, stream>>>(hagg, batch, statsC, g3, be3, fcW, fcb, out);
}

// Round 7
// 499.778 us; speedup vs baseline: 1.2556x; 1.0534x over previous
//
#include <hip/hip_runtime.h>
#include <hip/hip_bf16.h>

#define N_NODES 50000
#define NUM_E   800000
#define EPS_BN  1e-5f
#define NUM_GRAPHS 64
#define NCOPY 64   // striped stats copies (R5/R6: global-atomic serialization fix)

typedef __attribute__((ext_vector_type(8))) short bf16x8;
typedef __attribute__((ext_vector_type(4))) float f32x4;
typedef unsigned short ushort_t;
typedef unsigned int uint_t;

static __device__ __forceinline__ unsigned short f2bf(float f) {
    unsigned int u = __float_as_uint(f);
    u += 0x7fffu + ((u >> 16) & 1u);   // RNE
    return (unsigned short)(u >> 16);
}
static __device__ __forceinline__ uint_t pkbf(float lo, float hi) {
    __hip_bfloat162 t = __float22bfloat162_rn(make_float2(lo, hi));
    return *(uint_t*)&t;
}
static __device__ __forceinline__ float bflo(uint_t u) { return __uint_as_float(u << 16); }
static __device__ __forceinline__ float bfhi(uint_t u) { return __uint_as_float(u & 0xffff0000u); }

// ---------------- hist + prep merged (independent work, block-range split) ----------------
__global__ void hist_prep_kernel(const int* __restrict__ ei, int* __restrict__ deg,
                                 const float* __restrict__ W1, const float* __restrict__ W2,
                                 const float* __restrict__ W3, const float* __restrict__ x,
                                 ushort_t* __restrict__ w1t, ushort_t* __restrict__ w2t,
                                 ushort_t* __restrict__ w3t, ushort_t* __restrict__ xbf) {
    const int HB = (NUM_E + 255) / 256;          // 3125 hist blocks
    const int S1 = 128 * 256, S2 = 256 * 256, S3 = 256 * 64;
    const int SW = S1 + S2 + S3;                 // 81920
    const int SX = N_NODES * 128 / 4;            // 1.6M float4 units
    int b = blockIdx.x;
    if (b < HB) {
        int e = b * 256 + threadIdx.x;
        if (e < NUM_E) atomicAdd(&deg[ei[NUM_E + e]], 1);
        return;
    }
    int i = (b - HB) * 256 + threadIdx.x;
    if (i < SX) {
        float4 v = ((const float4*)x)[i];
        ((uint2*)xbf)[i] = make_uint2(pkbf(v.x, v.y), pkbf(v.z, v.w));
    } else if (i < SX + SW) {
        int j = i - SX;
        if (j < S1) {
            int k = j / 256, n = j % 256;
            w1t[n * 128 + k] = f2bf(W1[j]);
        } else if (j < S1 + S2) {
            int jj = j - S1; int k = jj / 256, n = jj % 256;
            w2t[n * 256 + k] = f2bf(W2[jj]);
        } else {
            int jj = j - S1 - S2; int k = jj / 64, n = jj % 64;
            w3t[n * 256 + k] = f2bf(W3[jj]);
        }
    }
}

__global__ void scan_local_kernel(const int* __restrict__ deg, int* __restrict__ rowptr,
                                  int* __restrict__ bsum) {
    __shared__ int ws[4];
    int b = blockIdx.x, t = threadIdx.x;
    int i = b * 256 + t;
    int lane = t & 63, wv = t >> 6;
    int v = (i < N_NODES) ? deg[i] : 0;
    int incl = v;
#pragma unroll
    for (int off = 1; off < 64; off <<= 1) {
        int u = __shfl_up(incl, off, 64);
        if (lane >= off) incl += u;
    }
    if (lane == 63) ws[wv] = incl;
    __syncthreads();
    if (t == 0) {
        int s = 0;
#pragma unroll
        for (int k = 0; k < 4; ++k) { int x = ws[k]; ws[k] = s; s += x; }
        bsum[b] = s;
    }
    __syncthreads();
    if (i < N_NODES) rowptr[i + 1] = ws[wv] + incl;
}

// merged scan_sums + scan_add: each block redundantly sums its bsum prefix (196 entries, trivial)
__global__ __launch_bounds__(256) void scan_fixup_kernel(int* __restrict__ rowptr,
                                                         const int* __restrict__ bsum) {
    __shared__ int ws[4];
    int b = blockIdx.x, t = threadIdx.x;
    int lane = t & 63, wv = t >> 6;
    int v = (t < b) ? bsum[t] : 0;   // b <= 195 < 256, t < b => valid index
#pragma unroll
    for (int off = 1; off < 64; off <<= 1) v += __shfl_xor(v, off, 64);
    if (lane == 0) ws[wv] = v;
    __syncthreads();
    int pre = ws[0] + ws[1] + ws[2] + ws[3];
    int i = b * 256 + t;
    if (i < N_NODES) rowptr[i + 1] += pre;
    if (b == 0 && t == 0) rowptr[0] = 0;
}

// ---------------- GEMM: BN-affine(A)->bf16 @ Bt^T -> h(bf16) + per-head logits ----------------
// Affine in staging (R4 A/B: cost-neutral vs pure-copy) with NCOPY-striped stats reduce in the
// prologue => deletes the scale_w dispatches. SCAT=true: extra blocks (x >= GBX) run the CSR
// scatter (independent work, saves a launch; ~5-6 us/dispatch chain overhead measured R5).
template<int K, int NFULL, int BN, bool SCAT>
__global__ __launch_bounds__(256) void gemm_fused_kernel(const ushort_t* __restrict__ A,
                                                         const ushort_t* __restrict__ Bt,
                                                         ushort_t* __restrict__ C,
                                                         const float* __restrict__ stats,
                                                         const float* __restrict__ g,
                                                         const float* __restrict__ be,
                                                         const float* __restrict__ a_src,
                                                         const float* __restrict__ a_dst,
                                                         float* __restrict__ as_,
                                                         float* __restrict__ ad_,
                                                         const int* __restrict__ ei,
                                                         const int* __restrict__ rowptr,
                                                         int* __restrict__ fill,
                                                         int* __restrict__ srcs) {
    constexpr int GBX = (N_NODES + 127) / 128;   // 391
    if constexpr (SCAT) {
        if (blockIdx.x >= GBX) {
            int idx = (blockIdx.x - GBX) + 1563 * blockIdx.y;
            int e = idx * 256 + (int)threadIdx.x;
            if (e < NUM_E) {
                int dst = ei[NUM_E + e];
                int pos = rowptr[dst] + atomicAdd(&fill[dst], 1);
                srcs[pos] = ei[e];
            }
            return;
        }
    }
    const int NT = BN / 16;
    const int NG = BN / 64;
    constexpr int LOOP_BYTES = (128 * 40 + BN * 40) * 2;
    constexpr int EPI_BYTES  = 4 * 32 * 64 * 2;
    constexpr int SMEM_BYTES = LOOP_BYTES > EPI_BYTES ? LOOP_BYTES : EPI_BYTES;
    __shared__ __align__(16) unsigned char smem[SMEM_BYTES];
    ushort_t (*As)[40]     = (ushort_t (*)[40])smem;                       // [128][40]
    ushort_t (*Bs)[40]     = (ushort_t (*)[40])(smem + 128 * 40 * 2);      // [BN][40]
    ushort_t (*Cs)[32][64] = (ushort_t (*)[32][64])smem;                   // [4][32][64] (aliases As/Bs)
    __shared__ __align__(16) float aff_a[K], aff_b[K];
    __shared__ float asrc_s[BN], adst_s[BN];
    int tid = threadIdx.x;
    int lane = tid & 63, w = tid >> 6;
    int row0 = blockIdx.x * 128, col0 = blockIdx.y * BN;
    int m_l = lane & 15, q = lane >> 4;

    for (int c = tid; c < K; c += 256) {
        float a = 1.f, b = 0.f;
        if (stats) {
            float s0 = 0.f, s1 = 0.f;
#pragma unroll 8
            for (int j = 0; j < NCOPY; ++j) {    // 128KB striped stats, L2-resident
                s0 += stats[j * 512 + c];
                s1 += stats[j * 512 + 256 + c];
            }
            float m = s0 * (1.f / N_NODES);
            float var = fmaxf(s1 * (1.f / N_NODES) - m * m, 0.f);
            float rs = rsqrtf(var + EPS_BN) * g[c];
            a = rs; b = be[c] - m * rs;
        }
        aff_a[c] = a; aff_b[c] = b;
    }
    if (tid < BN) {
        asrc_s[tid] = a_src[col0 + tid];
        adst_s[tid] = a_dst[col0 + tid];
    }
    __syncthreads();

    f32x4 acc[2][NT];
#pragma unroll
    for (int r = 0; r < 2; ++r)
#pragma unroll
        for (int c = 0; c < NT; ++c) acc[r][c] = (f32x4){0.f, 0.f, 0.f, 0.f};

    int ar = tid >> 1, ako = (tid & 1) * 16;

    for (int k0 = 0; k0 < K; k0 += 32) {
        uint_t ow[8];
        int gr = row0 + ar;
        uint4 u0 = make_uint4(0, 0, 0, 0), u1 = make_uint4(0, 0, 0, 0);
        if (gr < N_NODES) {
            const ushort_t* ap = A + (long)gr * K + k0 + ako;
            u0 = *(const uint4*)ap;
            u1 = *(const uint4*)(ap + 8);
        }
        uint_t uu[8] = {u0.x, u0.y, u0.z, u0.w, u1.x, u1.y, u1.z, u1.w};
#pragma unroll
        for (int t = 0; t < 8; ++t) {
            int k = k0 + ako + t * 2;
            float lo = bflo(uu[t]) * aff_a[k] + aff_b[k];
            float hi = bfhi(uu[t]) * aff_a[k + 1] + aff_b[k + 1];
            ow[t] = pkbf(lo, hi);
        }
        if constexpr (BN == 128) {
            int br = tid >> 1, bko = (tid & 1) * 16;
            const ushort_t* bp = Bt + (long)(col0 + br) * K + k0 + bko;
            uint4 b0 = *(const uint4*)bp;
            uint4 b1 = *(const uint4*)(bp + 8);
            *(uint4*)&As[ar][ako] = make_uint4(ow[0], ow[1], ow[2], ow[3]);
            *(uint4*)&As[ar][ako + 8] = make_uint4(ow[4], ow[5], ow[6], ow[7]);
            *(uint4*)&Bs[br][bko] = b0;
            *(uint4*)&Bs[br][bko + 8] = b1;
        } else {
            int br = tid >> 2, bko = (tid & 3) * 8;
            uint4 bv = *(const uint4*)(Bt + (long)(col0 + br) * K + k0 + bko);
            *(uint4*)&As[ar][ako] = make_uint4(ow[0], ow[1], ow[2], ow[3]);
            *(uint4*)&As[ar][ako + 8] = make_uint4(ow[4], ow[5], ow[6], ow[7]);
            *(uint4*)&Bs[br][bko] = bv;
        }
        __syncthreads();

        bf16x8 af[2];
#pragma unroll
        for (int r = 0; r < 2; ++r)
            af[r] = *(const bf16x8*)&As[w * 32 + r * 16 + m_l][q * 8];
#pragma unroll
        for (int c = 0; c < NT; ++c) {
            bf16x8 bf = *(const bf16x8*)&Bs[c * 16 + m_l][q * 8];
#pragma unroll
            for (int r = 0; r < 2; ++r)
                acc[r][c] = __builtin_amdgcn_mfma_f32_16x16x32_bf16(af[r], bf, acc[r][c], 0, 0, 0);
        }
        __syncthreads();   // after this barrier As/Bs are dead -> Cs may alias
    }

    const int H = NFULL / 64;
#pragma unroll
    for (int gblk = 0; gblk < NG; ++gblk) {
        int hidx = blockIdx.y * NG + gblk;
        int colg = col0 + gblk * 64;
#pragma unroll
        for (int r = 0; r < 2; ++r)
#pragma unroll
            for (int cc = 0; cc < 4; ++cc)
#pragma unroll
                for (int i = 0; i < 4; ++i)
                    Cs[w][r * 16 + q * 4 + i][cc * 16 + m_l] = f2bf(acc[r][gblk * 4 + cc][i]);
        // same-wave LDS RAW: in-order DS pipe, no barrier needed
#pragma unroll
        for (int j = 0; j < 4; ++j) {
            int flat = j * 64 + lane;
            int lr = flat >> 3, chg = flat & 7;
            int gr = row0 + w * 32 + lr;
            uint4 u = *(uint4*)&Cs[w][lr][chg * 8];
            float f0 = bflo(u.x), f1 = bfhi(u.x), f2 = bflo(u.y), f3 = bfhi(u.y);
            float f4 = bflo(u.z), f5 = bfhi(u.z), f6 = bflo(u.w), f7 = bfhi(u.w);
            int cb = gblk * 64 + chg * 8;
            float s1 = f0 * asrc_s[cb] + f1 * asrc_s[cb + 1] + f2 * asrc_s[cb + 2] + f3 * asrc_s[cb + 3]
                     + f4 * asrc_s[cb + 4] + f5 * asrc_s[cb + 5] + f6 * asrc_s[cb + 6] + f7 * asrc_s[cb + 7];
            float s2 = f0 * adst_s[cb] + f1 * adst_s[cb + 1] + f2 * adst_s[cb + 2] + f3 * adst_s[cb + 3]
                     + f4 * adst_s[cb + 4] + f5 * adst_s[cb + 5] + f6 * adst_s[cb + 6] + f7 * adst_s[cb + 7];
#pragma unroll
            for (int o = 1; o < 8; o <<= 1) {
                s1 += __shfl_xor(s1, o, 64);
                s2 += __shfl_xor(s2, o, 64);
            }
            if (gr < N_NODES) {
                *(uint4*)(C + (long)gr * NFULL + colg + chg * 8) = u;
                if ((lane & 7) == 0) {
                    as_[gr * H + hidx] = s1;
                    ad_[gr * H + hidx] = s2;
                }
            }
        }
    }
}

// ---------------- GAT aggregation H=4 (R3 structure: at ~3.3 TB/s gather ceiling, NO stats) ----------------
// R6 post-mortem: fused stats cost +31 us/dispatch (block barrier couples 16 variable-degree
// nodes + atomic tail); separate striped bn_stats is cheaper. Keep this kernel barrier-free.
__global__ __launch_bounds__(256) void agg4_kernel(const ushort_t* __restrict__ h,
                                                   const float* __restrict__ as_,
                                                   const float* __restrict__ ad_,
                                                   const int* __restrict__ rowptr,
                                                   const int* __restrict__ srcs,
                                                   const float* __restrict__ bias,
                                                   ushort_t* __restrict__ out) {
    __shared__ float4 alf[4][4][17];   // [wave][quarter][edge] 4 head alphas (pad 17)
    __shared__ int    sed[4][4][17];   // [wave][quarter][edge] src id
    int tid = threadIdx.x;
    int lane = tid & 63, w = tid >> 6;
    int q = lane >> 4, cl = lane & 15;
    int n = blockIdx.x * 16 + w * 4 + q;   // grid exact: n < N_NODES always

    int start = rowptr[n];
    int deg = rowptr[n + 1] - start;

    float4 adv = *(const float4*)(ad_ + n * 4);
    float ad4[4] = {adv.x, adv.y, adv.z, adv.w};

    float mx[4] = {-1e30f, -1e30f, -1e30f, -1e30f};
    float dn[4] = {0.f, 0.f, 0.f, 0.f};
    {
        float vst[4] = {-1e30f, -1e30f, -1e30f, -1e30f};
        int s0 = 0;
        if (deg > 0) s0 = srcs[start + min(cl, deg - 1)];
        sed[w][q][cl] = s0;
        if (cl < deg) {
            float4 av = *(const float4*)(as_ + s0 * 4);
            float vv[4] = {av.x + ad4[0], av.y + ad4[1], av.z + ad4[2], av.w + ad4[3]};
#pragma unroll
            for (int hh = 0; hh < 4; ++hh) {
                float v = vv[hh] > 0.f ? vv[hh] : 0.2f * vv[hh];
                vst[hh] = v; mx[hh] = v; dn[hh] = 1.f;
            }
        }
        alf[w][q][cl] = make_float4(vst[0], vst[1], vst[2], vst[3]);
        for (int j = cl + 16; j < deg; j += 16) {
            int s = srcs[start + j];
            float4 av = *(const float4*)(as_ + s * 4);
            float vv[4] = {av.x + ad4[0], av.y + ad4[1], av.z + ad4[2], av.w + ad4[3]};
#pragma unroll
            for (int hh = 0; hh < 4; ++hh) {
                float v = vv[hh] > 0.f ? vv[hh] : 0.2f * vv[hh];
                float mn = fmaxf(mx[hh], v);
                dn[hh] = dn[hh] * __expf(mx[hh] - mn) + __expf(v - mn);
                mx[hh] = mn;
            }
        }
    }
    float mloc[4] = {mx[0], mx[1], mx[2], mx[3]};
#pragma unroll
    for (int off = 1; off < 16; off <<= 1)
#pragma unroll
        for (int hh = 0; hh < 4; ++hh) mx[hh] = fmaxf(mx[hh], __shfl_xor(mx[hh], off, 64));
#pragma unroll
    for (int hh = 0; hh < 4; ++hh) dn[hh] *= __expf(mloc[hh] - mx[hh]);
#pragma unroll
    for (int off = 1; off < 16; off <<= 1)
#pragma unroll
        for (int hh = 0; hh < 4; ++hh) dn[hh] += __shfl_xor(dn[hh], off, 64);
    float inv[4];
#pragma unroll
    for (int hh = 0; hh < 4; ++hh) inv[hh] = dn[hh] > 0.f ? 1.f / dn[hh] : 0.f;
    {
        float4 vv = alf[w][q][cl];   // logits -> alphas (OOB lanes: exp(-1e30-mx)=0)
        alf[w][q][cl] = make_float4(__expf(vv.x - mx[0]) * inv[0], __expf(vv.y - mx[1]) * inv[1],
                                    __expf(vv.z - mx[2]) * inv[2], __expf(vv.w - mx[3]) * inv[3]);
    }

    int hd = cl >> 2, cbase = cl * 16;
    float acc[16];
#pragma unroll
    for (int k = 0; k < 16; ++k) acc[k] = 0.f;

    for (int chunk = 0; chunk < deg || chunk == 0; chunk += 16) {
        if (chunk > 0) {
            int j = chunk + cl;
            int s = srcs[start + min(j, deg - 1)];
            sed[w][q][cl] = s;
            float a4[4] = {0.f, 0.f, 0.f, 0.f};
            if (j < deg) {
                float4 av = *(const float4*)(as_ + s * 4);
                float vv[4] = {av.x + ad4[0], av.y + ad4[1], av.z + ad4[2], av.w + ad4[3]};
#pragma unroll
                for (int hh = 0; hh < 4; ++hh) {
                    float v = vv[hh] > 0.f ? vv[hh] : 0.2f * vv[hh];
                    a4[hh] = __expf(v - mx[hh]) * inv[hh];
                }
            }
            alf[w][q][cl] = make_float4(a4[0], a4[1], a4[2], a4[3]);
        }
        int cnt = min(16, deg - chunk);
        if (cnt < 0) cnt = 0;
        int e = 0;
        // 4-edge groups, half-row batches: 4 uint4 in flight, 2 batches per group
        for (; e + 4 <= cnt; e += 4) {
            float av[4]; int sv[4];
#pragma unroll
            for (int t = 0; t < 4; ++t) {
                av[t] = ((const float*)&alf[w][q][e + t])[hd];
                sv[t] = sed[w][q][e + t];
            }
            uint4 ua[4];
#pragma unroll
            for (int t = 0; t < 4; ++t)
                ua[t] = *(const uint4*)(h + (long)sv[t] * 256 + cbase);
#pragma unroll
            for (int t = 0; t < 4; ++t) {
                float al = av[t];
                acc[0] += al * bflo(ua[t].x); acc[1] += al * bfhi(ua[t].x);
                acc[2] += al * bflo(ua[t].y); acc[3] += al * bfhi(ua[t].y);
                acc[4] += al * bflo(ua[t].z); acc[5] += al * bfhi(ua[t].z);
                acc[6] += al * bflo(ua[t].w); acc[7] += al * bfhi(ua[t].w);
            }
#pragma unroll
            for (int t = 0; t < 4; ++t)
                ua[t] = *(const uint4*)(h + (long)sv[t] * 256 + cbase + 8);
#pragma unroll
            for (int t = 0; t < 4; ++t) {
                float al = av[t];
                acc[8]  += al * bflo(ua[t].x); acc[9]  += al * bfhi(ua[t].x);
                acc[10] += al * bflo(ua[t].y); acc[11] += al * bfhi(ua[t].y);
                acc[12] += al * bflo(ua[t].z); acc[13] += al * bfhi(ua[t].z);
                acc[14] += al * bflo(ua[t].w); acc[15] += al * bfhi(ua[t].w);
            }
        }
        for (; e < cnt; ++e) {   // exact tail, 1 edge
            float al = ((const float*)&alf[w][q][e])[hd];
            const ushort_t* hr = h + (long)sed[w][q][e] * 256 + cbase;
            uint4 u0 = *(const uint4*)hr;
            uint4 u1 = *(const uint4*)(hr + 8);
            acc[0]  += al * bflo(u0.x); acc[1]  += al * bfhi(u0.x);
            acc[2]  += al * bflo(u0.y); acc[3]  += al * bfhi(u0.y);
            acc[4]  += al * bflo(u0.z); acc[5]  += al * bfhi(u0.z);
            acc[6]  += al * bflo(u0.w); acc[7]  += al * bfhi(u0.w);
            acc[8]  += al * bflo(u1.x); acc[9]  += al * bfhi(u1.x);
            acc[10] += al * bflo(u1.y); acc[11] += al * bfhi(u1.y);
            acc[12] += al * bflo(u1.z); acc[13] += al * bfhi(u1.z);
            acc[14] += al * bflo(u1.w); acc[15] += al * bfhi(u1.w);
        }
        if (deg <= 16) break;
    }

    // epilogue: bias + relu, bf16 store
    uint_t ow[8];
#pragma unroll
    for (int t = 0; t < 8; ++t) {
        float lo = fmaxf(acc[t * 2] + bias[cbase + t * 2], 0.f);
        float hi = fmaxf(acc[t * 2 + 1] + bias[cbase + t * 2 + 1], 0.f);
        ow[t] = pkbf(lo, hi);
    }
    ushort_t* op = out + (long)n * 256 + cbase;
    *(uint4*)op = make_uint4(ow[0], ow[1], ow[2], ow[3]);
    *(uint4*)(op + 8) = make_uint4(ow[4], ow[5], ow[6], ow[7]);
}

// ---------------- GAT aggregation H=1: fused BN stats (striped) ----------------
__global__ __launch_bounds__(256) void agg1_kernel(const ushort_t* __restrict__ h,
                                                   const float* __restrict__ as_,
                                                   const float* __restrict__ ad_,
                                                   const int* __restrict__ rowptr,
                                                   const int* __restrict__ srcs,
                                                   const float* __restrict__ bias,
                                                   ushort_t* __restrict__ out,
                                                   float* __restrict__ stats) {
    __shared__ float alf1[4][8][9];
    __shared__ int   sed1[4][8][9];
    __shared__ float ssum[64], ssq[64];
    int tid = threadIdx.x;
    int lane = tid & 63, w = tid >> 6;
    int o = lane >> 3, cl = lane & 7;
    int n = blockIdx.x * 32 + w * 8 + o;
    bool valid = n < N_NODES;
    int nc = valid ? n : N_NODES - 1;
    if (tid < 64) { ssum[tid] = 0.f; ssq[tid] = 0.f; }
    __syncthreads();

    int start = rowptr[nc];
    int deg = valid ? rowptr[nc + 1] - start : 0;
    float adn = ad_[nc];

    float mx = -1e30f, dn = 0.f;
    {
        float vst = -1e30f;
        int s0 = 0;
        if (deg > 0) s0 = srcs[start + min(cl, deg - 1)];
        sed1[w][o][cl] = s0;
        if (cl < deg) {
            float v = as_[s0] + adn;
            v = v > 0.f ? v : 0.2f * v;
            vst = v; mx = v; dn = 1.f;
        }
        alf1[w][o][cl] = vst;
        for (int j = cl + 8; j < deg; j += 8) {
            int s = srcs[start + j];
            float v = as_[s] + adn;
            v = v > 0.f ? v : 0.2f * v;
            float mn = fmaxf(mx, v);
            dn = dn * __expf(mx - mn) + __expf(v - mn);
            mx = mn;
        }
    }
    float mloc = mx;
#pragma unroll
    for (int off = 1; off < 8; off <<= 1) mx = fmaxf(mx, __shfl_xor(mx, off, 64));
    dn *= __expf(mloc - mx);
#pragma unroll
    for (int off = 1; off < 8; off <<= 1) dn += __shfl_xor(dn, off, 64);
    float inv = dn > 0.f ? 1.f / dn : 0.f;

    alf1[w][o][cl] = __expf(alf1[w][o][cl] - mx) * inv;

    int c0 = cl * 8;
    float acc[8] = {0.f, 0.f, 0.f, 0.f, 0.f, 0.f, 0.f, 0.f};

    for (int chunk = 0; chunk < deg || chunk == 0; chunk += 8) {
        if (chunk > 0) {
            int j = chunk + cl;
            int s = srcs[start + min(j, deg - 1)];
            sed1[w][o][cl] = s;
            float al = 0.f;
            if (j < deg) {
                float v = as_[s] + adn;
                v = v > 0.f ? v : 0.2f * v;
                al = __expf(v - mx) * inv;
            }
            alf1[w][o][cl] = al;
        }
        int cnt = min(8, deg - chunk);
        if (cnt < 0) cnt = 0;
        int e = 0;
        for (; e + 4 <= cnt; e += 4) {
            float av[4]; int sv[4];
#pragma unroll
            for (int t = 0; t < 4; ++t) {
                av[t] = alf1[w][o][e + t];
                sv[t] = sed1[w][o][e + t];
            }
            uint4 ua[4];
#pragma unroll
            for (int t = 0; t < 4; ++t)
                ua[t] = *(const uint4*)(h + (long)sv[t] * 64 + c0);
#pragma unroll
            for (int t = 0; t < 4; ++t) {
                float al = av[t];
                acc[0] += al * bflo(ua[t].x); acc[1] += al * bfhi(ua[t].x);
                acc[2] += al * bflo(ua[t].y); acc[3] += al * bfhi(ua[t].y);
                acc[4] += al * bflo(ua[t].z); acc[5] += al * bfhi(ua[t].z);
                acc[6] += al * bflo(ua[t].w); acc[7] += al * bfhi(ua[t].w);
            }
        }
        for (; e < cnt; ++e) {
            float al = alf1[w][o][e];
            uint4 u = *(const uint4*)(h + (long)sed1[w][o][e] * 64 + c0);
            acc[0] += al * bflo(u.x); acc[1] += al * bfhi(u.x);
            acc[2] += al * bflo(u.y); acc[3] += al * bfhi(u.y);
            acc[4] += al * bflo(u.z); acc[5] += al * bfhi(u.z);
            acc[6] += al * bflo(u.w); acc[7] += al * bfhi(u.w);
        }
        if (deg <= 8) break;
    }

    float v[8];
#pragma unroll
    for (int t = 0; t < 8; ++t) v[t] = fmaxf(acc[t] + bias[c0 + t], 0.f);
    if (valid) {
        uint_t ow[4];
#pragma unroll
        for (int t = 0; t < 4; ++t) ow[t] = pkbf(v[2 * t], v[2 * t + 1]);
        *(uint4*)(out + (long)n * 64 + c0) = make_uint4(ow[0], ow[1], ow[2], ow[3]);
    }
    float s1[8], s2[8];
#pragma unroll
    for (int t = 0; t < 8; ++t) {
        s1[t] = valid ? v[t] : 0.f;
        s2[t] = valid ? v[t] * v[t] : 0.f;
    }
#pragma unroll
    for (int off = 8; off < 64; off <<= 1)    // reduce 8 octants (same cl -> same channels)
#pragma unroll
        for (int t = 0; t < 8; ++t) {
            s1[t] += __shfl_xor(s1[t], off, 64);
            s2[t] += __shfl_xor(s2[t], off, 64);
        }
    if (lane < 8) {
#pragma unroll
        for (int t = 0; t < 8; ++t) {
            atomicAdd(&ssum[c0 + t], s1[t]);
            atomicAdd(&ssq[c0 + t], s2[t]);
        }
    }
    __syncthreads();
    if (tid < 64) {
        int cp = (blockIdx.x & (NCOPY - 1)) * 512;   // striped copy
        atomicAdd(&stats[cp + tid], ssum[tid]);
        atomicAdd(&stats[cp + 256 + tid], ssq[tid]);
    }
}

// ---------------- BatchNorm stats on bf16, coalesced, striped output ----------------
template<int C>
__global__ __launch_bounds__(256) void bn_stats_bf16(const ushort_t* __restrict__ x,
                                                     float* __restrict__ stats) {
    const int GROUPS = C / 8;
    const int RS = 256 / GROUPS;
    int tid = threadIdx.x;
    int cg_ = tid % GROUPS;
    int rs = tid / GROUPS;
    float s[8], s2[8];
#pragma unroll
    for (int k = 0; k < 8; ++k) { s[k] = 0.f; s2[k] = 0.f; }
    for (int n = blockIdx.x * RS + rs; n < N_NODES; n += gridDim.x * RS) {
        uint4 u = *(const uint4*)(x + (long)n * C + cg_ * 8);
        float f[8] = {bflo(u.x), bfhi(u.x), bflo(u.y), bfhi(u.y),
                      bflo(u.z), bfhi(u.z), bflo(u.w), bfhi(u.w)};
#pragma unroll
        for (int k = 0; k < 8; ++k) { s[k] += f[k]; s2[k] += f[k] * f[k]; }
    }
    __shared__ float red[256][16];
#pragma unroll
    for (int k = 0; k < 8; ++k) { red[tid][k] = s[k]; red[tid][8 + k] = s2[k]; }
    __syncthreads();
    if (tid < C) {
        int g = tid >> 3, k = tid & 7;
        float a = 0.f, b = 0.f;
        for (int r = 0; r < RS; ++r) {
            a += red[g + r * GROUPS][k];
            b += red[g + r * GROUPS][8 + k];
        }
        int cp = (blockIdx.x & (NCOPY - 1)) * 512;   // striped: ~2 blocks/address at 128 blocks
        atomicAdd(&stats[cp + tid], a);
        atomicAdd(&stats[cp + 256 + tid], b);
    }
}

// ---------------- pool (BN affine fused, striped-stats reduce) + FC; goff inlined ----------------
__global__ __launch_bounds__(256) void pool_fc_kernel(const ushort_t* __restrict__ h,
                                                      const int* __restrict__ batch,
                                                      const float* __restrict__ stats,
                                                      const float* __restrict__ g3,
                                                      const float* __restrict__ be3,
                                                      const float* __restrict__ fcW,
                                                      const float* __restrict__ fcb,
                                                      float* __restrict__ out) {
    int g = blockIdx.x;
    __shared__ int se[2];
    if (threadIdx.x < 2) {
        int gg = g + threadIdx.x;
        int lo = 0, hi = N_NODES;
        while (lo < hi) {
            int mid = (lo + hi) >> 1;
            if (batch[mid] < gg) lo = mid + 1; else hi = mid;
        }
        se[threadIdx.x] = lo;
    }
    __syncthreads();
    int s = se[0], e = se[1];
    int c = threadIdx.x & 63;
    int ty = threadIdx.x >> 6;
    float sum = 0.f;
    for (int n = s + ty; n < e; n += 4) sum += bflo((uint_t)h[(long)n * 64 + c]);
    __shared__ float red[4][64];
    __shared__ float pv[64];
    red[ty][c] = sum;
    __syncthreads();
    if (ty == 0) {
        float tot = red[0][c] + red[1][c] + red[2][c] + red[3][c];
        float v = tot / fmaxf((float)(e - s), 1.f);
        float s0 = 0.f, s1 = 0.f;
#pragma unroll 8
        for (int j = 0; j < NCOPY; ++j) {
            s0 += stats[j * 512 + c];
            s1 += stats[j * 512 + 256 + c];
        }
        float m = s0 * (1.f / N_NODES);
        float var = fmaxf(s1 * (1.f / N_NODES) - m * m, 0.f);
        pv[c] = (v - m) * rsqrtf(var + EPS_BN) * g3[c] + be3[c];
    }
    __syncthreads();
    if (threadIdx.x < 10) {
        int j = threadIdx.x;
        float acc = fcb[j];
#pragma unroll
        for (int k = 0; k < 64; ++k) acc += pv[k] * fcW[k * 10 + j];
        out[g * 10 + j] = acc;
    }
}

extern "C" void kernel_launch(void* const* d_in, const int* in_sizes, int n_in,
                              void* d_out, int out_size, void* d_ws, size_t ws_size,
                              hipStream_t stream) {
    const float* x      = (const float*)d_in[0];
    const int*   ei     = (const int*)d_in[1];
    const int*   batch  = (const int*)d_in[2];
    const float* W1     = (const float*)d_in[3];
    const float* a_src1 = (const float*)d_in[4];
    const float* a_dst1 = (const float*)d_in[5];
    const float* b1     = (const float*)d_in[6];
    const float* g1     = (const float*)d_in[7];
    const float* be1    = (const float*)d_in[8];
    const float* W2     = (const float*)d_in[9];
    const float* a_src2 = (const float*)d_in[10];
    const float* a_dst2 = (const float*)d_in[11];
    const float* b2     = (const float*)d_in[12];
    const float* g2     = (const float*)d_in[13];
    const float* be2    = (const float*)d_in[14];
    const float* W3     = (const float*)d_in[15];
    const float* a_src3 = (const float*)d_in[16];
    const float* a_dst3 = (const float*)d_in[17];
    const float* b3     = (const float*)d_in[18];
    const float* g3     = (const float*)d_in[19];
    const float* be3    = (const float*)d_in[20];
    const float* fcW    = (const float*)d_in[21];
    const float* fcb    = (const float*)d_in[22];
    float* out = (float*)d_out;

    const size_t N = N_NODES, E = NUM_E;
    const int SST = NCOPY * 512;                        // striped stats size
    ushort_t* hbf    = (ushort_t*)d_ws;                 // [N,256] bf16 GEMM output
    ushort_t* hagg   = hbf + N * 256;                   // [N,256] bf16 agg output (pre-BN)
    ushort_t* xbf    = hagg + N * 256;                  // [N,128] bf16 x
    ushort_t* w1t    = xbf + N * 128;                   // [256][128]
    ushort_t* w2t    = w1t + 256 * 128;                 // [256][256]
    ushort_t* w3t    = w2t + 256 * 256;                 // [64][256]
    float*    as_    = (float*)(w3t + 64 * 256 + 128);  // [N,4]
    float*    ad_    = as_ + N * 4;                     // [N,4]
    int*      deg    = (int*)(ad_ + N * 4);             // [N]   (zero region start)
    int*      fill   = deg + N;                         // [N]
    float*    statsA = (float*)(fill + N);              // [NCOPY*512]
    float*    statsB = statsA + SST;                    // [NCOPY*512]
    float*    statsC = statsB + SST;                    // [NCOPY*512]
    int*      rowptr = (int*)(statsC + SST);            // [N+1]
    int*      srcs   = rowptr + (N + 1);                // [E]
    int*      bsum   = srcs + E;                        // [256]

    const int NB = (N_NODES + 255) / 256;  // 196
    const int HB = (NUM_E + 255) / 256;    // 3125
    const int SX = N_NODES * 128 / 4;
    const int SW = 128 * 256 + 256 * 256 + 256 * 64;
    const int PB = (SX + SW + 255) / 256;  // 6570

    // ---- setup ----
    hipMemsetAsync(deg, 0, sizeof(int) * (2 * N + 3 * SST), stream);
    hist_prep_kernel<<<HB + PB, 256, 0, stream>>>(ei, deg, W1, W2, W3, x, w1t, w2t, w3t, xbf);
    scan_local_kernel<<<NB, 256, 0, stream>>>(deg, rowptr, bsum);
    scan_fixup_kernel<<<NB, 256, 0, stream>>>(rowptr, bsum);

    const int GB = (N_NODES + 127) / 128;  // 391
    const int AB = N_NODES / 16;           // 3125 (exact: 50000 % 16 == 0)

    // ---- layer 1 (stats=null => identity affine); scatter merged into the gemm1 dispatch ----
    gemm_fused_kernel<128, 256, 128, true><<<dim3(GB + 1563, 2), 256, 0, stream>>>(
        xbf, w1t, hbf, nullptr, nullptr, nullptr, a_src1, a_dst1, as_, ad_,
        ei, rowptr, fill, srcs);
    agg4_kernel<<<AB, 256, 0, stream>>>(hbf, as_, ad_, rowptr, srcs, b1, hagg);
    bn_stats_bf16<256><<<128, 256, 0, stream>>>(hagg, statsA);

    // ---- layer 2 (BN1 affine applied in staging, striped-stats reduce in prologue) ----
    gemm_fused_kernel<256, 256, 128, false><<<dim3(GB, 2), 256, 0, stream>>>(
        hagg, w2t, hbf, statsA, g1, be1, a_src2, a_dst2, as_, ad_,
        nullptr, nullptr, nullptr, nullptr);
    agg4_kernel<<<AB, 256, 0, stream>>>(hbf, as_, ad_, rowptr, srcs, b2, hagg);
    bn_stats_bf16<256><<<128, 256, 0, stream>>>(hagg, statsB);

    // ---- layer 3 ----
    gemm_fused_kernel<256, 64, 64, false><<<dim3(GB, 1), 256, 0, stream>>>(
        hagg, w3t, hbf, statsB, g2, be2, a_src3, a_dst3, as_, ad_,
        nullptr, nullptr, nullptr, nullptr);
    agg1_kernel<<<(N_NODES + 31) / 32, 256, 0, stream>>>(hbf, as_, ad_, rowptr, srcs, b3, hagg, statsC);

    // ---- pool + BN3 affine + FC in one (goff inlined, striped-stats reduce) ----
    pool_fc_kernel<<<NUM_GRAPHS, 256, 0, stream>>>(hagg, batch, statsC, g3, be3, fcW, fcb, out);
}

// Round 8
// 480.167 us; speedup vs baseline: 1.3069x; 1.0408x over previous
//
#include <hip/hip_runtime.h>
#include <hip/hip_bf16.h>

#define N_NODES 50000
#define NUM_E   800000
#define EPS_BN  1e-5f
#define NUM_GRAPHS 64
#define NCOPY 64   // striped stats copies (R5/R6: global-atomic serialization fix)

typedef __attribute__((ext_vector_type(8))) short bf16x8;
typedef __attribute__((ext_vector_type(4))) float f32x4;
typedef unsigned short ushort_t;
typedef unsigned int uint_t;

static __device__ __forceinline__ unsigned short f2bf(float f) {
    unsigned int u = __float_as_uint(f);
    u += 0x7fffu + ((u >> 16) & 1u);   // RNE
    return (unsigned short)(u >> 16);
}
static __device__ __forceinline__ uint_t pkbf(float lo, float hi) {
    __hip_bfloat162 t = __float22bfloat162_rn(make_float2(lo, hi));
    return *(uint_t*)&t;
}
static __device__ __forceinline__ float bflo(uint_t u) { return __uint_as_float(u << 16); }
static __device__ __forceinline__ float bfhi(uint_t u) { return __uint_as_float(u & 0xffff0000u); }

// ---------------- hist + prep merged (independent work, block-range split) ----------------
__global__ void hist_prep_kernel(const int* __restrict__ ei, int* __restrict__ deg,
                                 const float* __restrict__ W1, const float* __restrict__ W2,
                                 const float* __restrict__ W3, const float* __restrict__ x,
                                 ushort_t* __restrict__ w1t, ushort_t* __restrict__ w2t,
                                 ushort_t* __restrict__ w3t, ushort_t* __restrict__ xbf) {
    const int HB = (NUM_E + 255) / 256;          // 3125 hist blocks
    const int S1 = 128 * 256, S2 = 256 * 256, S3 = 256 * 64;
    const int SW = S1 + S2 + S3;                 // 81920
    const int SX = N_NODES * 128 / 4;            // 1.6M float4 units
    int b = blockIdx.x;
    if (b < HB) {
        int e = b * 256 + threadIdx.x;
        if (e < NUM_E) atomicAdd(&deg[ei[NUM_E + e]], 1);
        return;
    }
    int i = (b - HB) * 256 + threadIdx.x;
    if (i < SX) {
        float4 v = ((const float4*)x)[i];
        ((uint2*)xbf)[i] = make_uint2(pkbf(v.x, v.y), pkbf(v.z, v.w));
    } else if (i < SX + SW) {
        int j = i - SX;
        if (j < S1) {
            int k = j / 256, n = j % 256;
            w1t[n * 128 + k] = f2bf(W1[j]);
        } else if (j < S1 + S2) {
            int jj = j - S1; int k = jj / 256, n = jj % 256;
            w2t[n * 256 + k] = f2bf(W2[jj]);
        } else {
            int jj = j - S1 - S2; int k = jj / 64, n = jj % 64;
            w3t[n * 256 + k] = f2bf(W3[jj]);
        }
    }
}

__global__ void scan_local_kernel(const int* __restrict__ deg, int* __restrict__ rowptr,
                                  int* __restrict__ bsum) {
    __shared__ int ws[4];
    int b = blockIdx.x, t = threadIdx.x;
    int i = b * 256 + t;
    int lane = t & 63, wv = t >> 6;
    int v = (i < N_NODES) ? deg[i] : 0;
    int incl = v;
#pragma unroll
    for (int off = 1; off < 64; off <<= 1) {
        int u = __shfl_up(incl, off, 64);
        if (lane >= off) incl += u;
    }
    if (lane == 63) ws[wv] = incl;
    __syncthreads();
    if (t == 0) {
        int s = 0;
#pragma unroll
        for (int k = 0; k < 4; ++k) { int x = ws[k]; ws[k] = s; s += x; }
        bsum[b] = s;
    }
    __syncthreads();
    if (i < N_NODES) rowptr[i + 1] = ws[wv] + incl;
}

// merged scan_sums + scan_add: each block redundantly sums its bsum prefix (196 entries, trivial)
__global__ __launch_bounds__(256) void scan_fixup_kernel(int* __restrict__ rowptr,
                                                         const int* __restrict__ bsum) {
    __shared__ int ws[4];
    int b = blockIdx.x, t = threadIdx.x;
    int lane = t & 63, wv = t >> 6;
    int v = (t < b) ? bsum[t] : 0;   // b <= 195 < 256, t < b => valid index
#pragma unroll
    for (int off = 1; off < 64; off <<= 1) v += __shfl_xor(v, off, 64);
    if (lane == 0) ws[wv] = v;
    __syncthreads();
    int pre = ws[0] + ws[1] + ws[2] + ws[3];
    int i = b * 256 + t;
    if (i < N_NODES) rowptr[i + 1] += pre;
    if (b == 0 && t == 0) rowptr[0] = 0;
}

// ---------------- BN fold into W (striped stats reduce): Wts = a*Wt, cvec = b@W ----------------
// BN(h)@W == h@(diag(a) W) + (b@W): makes GEMM A-staging a PURE COPY (prereq for global_load_lds,
// which cannot apply an affine). Measured cost-neutral in R4.
__global__ __launch_bounds__(256) void scale_w_kernel(const float* __restrict__ stats,
                                                      const float* __restrict__ g,
                                                      const float* __restrict__ be,
                                                      const ushort_t* __restrict__ wt,
                                                      ushort_t* __restrict__ wts,
                                                      float* __restrict__ cvec) {
    int n = blockIdx.x, k = threadIdx.x;
    float s0 = 0.f, s1 = 0.f;
#pragma unroll 8
    for (int j = 0; j < NCOPY; ++j) {          // 128KB striped stats, L2-resident
        s0 += stats[j * 512 + k];
        s1 += stats[j * 512 + 256 + k];
    }
    float m = s0 * (1.f / N_NODES);
    float var = fmaxf(s1 * (1.f / N_NODES) - m * m, 0.f);
    float rs = rsqrtf(var + EPS_BN) * g[k];
    float b = be[k] - m * rs;
    float wv = bflo((uint_t)wt[n * 256 + k]);
    wts[n * 256 + k] = f2bf(rs * wv);
    float p = b * wv;
    __shared__ float ws[4];
    int lane = k & 63, wid = k >> 6;
#pragma unroll
    for (int off = 1; off < 64; off <<= 1) p += __shfl_xor(p, off, 64);
    if (lane == 0) ws[wid] = p;
    __syncthreads();
    if (k == 0) cvec[n] = ws[0] + ws[1] + ws[2] + ws[3];
}

// ---------------- GEMM: A(bf16) @ Bt^T + cvec -> h(bf16) + per-head logits ----------------
// Staging via __builtin_amdgcn_global_load_lds (16B): no VGPR round-trip, ~4 insts/wave/K-step.
// LDS is LINEAR [rows][32] (gload_lds dest = wave-uniform base + lane*16; padding breaks it, m104).
// Known trade: 8-way ds_read bank conflict on fragment reads (m97 precedent: net win).
// A buffers are row-PADDED (+128) because gload_lds has no per-lane predication; garbage rows are
// discarded by the gr<N_NODES store guard (C[m][n] only mixes row-m A values -> no contamination).
// SCAT=true: extra blocks run CSR scatter (saves a launch, ~5-6us measured R5).
template<int K, int NFULL, int BN, bool SCAT>
__global__ __launch_bounds__(256) void gemm_fused_kernel(const ushort_t* __restrict__ A,
                                                         const ushort_t* __restrict__ Bt,
                                                         ushort_t* __restrict__ C,
                                                         const float* __restrict__ cvec,
                                                         const float* __restrict__ a_src,
                                                         const float* __restrict__ a_dst,
                                                         float* __restrict__ as_,
                                                         float* __restrict__ ad_,
                                                         const int* __restrict__ ei,
                                                         const int* __restrict__ rowptr,
                                                         int* __restrict__ fill,
                                                         int* __restrict__ srcs) {
    constexpr int GBX = (N_NODES + 127) / 128;   // 391
    if constexpr (SCAT) {
        if (blockIdx.x >= GBX) {
            int idx = (blockIdx.x - GBX) + 1563 * blockIdx.y;
            int e = idx * 256 + (int)threadIdx.x;
            if (e < NUM_E) {
                int dst = ei[NUM_E + e];
                int pos = rowptr[dst] + atomicAdd(&fill[dst], 1);
                srcs[pos] = ei[e];
            }
            return;
        }
    }
    const int NT = BN / 16;
    const int NG = BN / 64;
    constexpr int LOOP_BYTES = (128 * 32 + BN * 32) * 2;
    constexpr int EPI_BYTES  = 4 * 32 * 64 * 2;
    constexpr int SMEM_BYTES = LOOP_BYTES > EPI_BYTES ? LOOP_BYTES : EPI_BYTES;
    __shared__ __align__(16) unsigned char smem[SMEM_BYTES];
    ushort_t* As = (ushort_t*)smem;                     // [128][32] linear
    ushort_t* Bs = As + 128 * 32;                       // [BN][32] linear
    ushort_t (*Cs)[32][64] = (ushort_t (*)[32][64])smem;  // epilogue alias (post-final-barrier)
    __shared__ float cvec_s[BN];
    __shared__ float asrc_s[BN], adst_s[BN];
    int tid = threadIdx.x;
    int lane = tid & 63, w = tid >> 6;
    int row0 = blockIdx.x * 128, col0 = blockIdx.y * BN;
    int m_l = lane & 15, q = lane >> 4;

    if (tid < BN) {
        cvec_s[tid] = cvec[col0 + tid];
        asrc_s[tid] = a_src[col0 + tid];
        adst_s[tid] = a_dst[col0 + tid];
    }

    f32x4 acc[2][NT];
#pragma unroll
    for (int r = 0; r < 2; ++r)
#pragma unroll
        for (int c = 0; c < NT; ++c) acc[r][c] = (f32x4){0.f, 0.f, 0.f, 0.f};

    int rsub = lane >> 2;          // 0..15: row within 16-row group
    int csub = (lane & 3) * 8;     // 0,8,16,24: elem col offset (16B)

    for (int k0 = 0; k0 < K; k0 += 32) {
        // A: wave w stages rows [w*32, w*32+32): 2 calls x 1KB
        {
            const ushort_t* ag = A + (long)(row0 + w * 32 + rsub) * K + k0 + csub;
            __builtin_amdgcn_global_load_lds(ag, As + (w * 32) * 32, 16, 0, 0);
            __builtin_amdgcn_global_load_lds(ag + 16 * K, As + (w * 32 + 16) * 32, 16, 0, 0);
        }
        if constexpr (BN == 128) {
            const ushort_t* bg = Bt + (long)(col0 + w * 32 + rsub) * K + k0 + csub;
            __builtin_amdgcn_global_load_lds(bg, Bs + (w * 32) * 32, 16, 0, 0);
            __builtin_amdgcn_global_load_lds(bg + 16 * K, Bs + (w * 32 + 16) * 32, 16, 0, 0);
        } else {   // BN == 64: wave w stages rows [w*16, w*16+16)
            const ushort_t* bg = Bt + (long)(col0 + w * 16 + rsub) * K + k0 + csub;
            __builtin_amdgcn_global_load_lds(bg, Bs + (w * 16) * 32, 16, 0, 0);
        }
        __syncthreads();   // compiler drains vmcnt before barrier

        bf16x8 af[2];
#pragma unroll
        for (int r = 0; r < 2; ++r)
            af[r] = *(const bf16x8*)(As + (w * 32 + r * 16 + m_l) * 32 + q * 8);
#pragma unroll
        for (int c = 0; c < NT; ++c) {
            bf16x8 bf = *(const bf16x8*)(Bs + (c * 16 + m_l) * 32 + q * 8);
#pragma unroll
            for (int r = 0; r < 2; ++r)
                acc[r][c] = __builtin_amdgcn_mfma_f32_16x16x32_bf16(af[r], bf, acc[r][c], 0, 0, 0);
        }
        __syncthreads();   // after this barrier As/Bs are dead -> Cs may alias
    }

    const int H = NFULL / 64;
#pragma unroll
    for (int gblk = 0; gblk < NG; ++gblk) {
        int hidx = blockIdx.y * NG + gblk;
        int colg = col0 + gblk * 64;
#pragma unroll
        for (int r = 0; r < 2; ++r)
#pragma unroll
            for (int cc = 0; cc < 4; ++cc)
#pragma unroll
                for (int i = 0; i < 4; ++i)
                    Cs[w][r * 16 + q * 4 + i][cc * 16 + m_l] =
                        f2bf(acc[r][gblk * 4 + cc][i] + cvec_s[gblk * 64 + cc * 16 + m_l]);
        // same-wave LDS RAW: in-order DS pipe, no barrier needed
#pragma unroll
        for (int j = 0; j < 4; ++j) {
            int flat = j * 64 + lane;
            int lr = flat >> 3, chg = flat & 7;
            int gr = row0 + w * 32 + lr;
            uint4 u = *(uint4*)&Cs[w][lr][chg * 8];
            float f0 = bflo(u.x), f1 = bfhi(u.x), f2 = bflo(u.y), f3 = bfhi(u.y);
            float f4 = bflo(u.z), f5 = bfhi(u.z), f6 = bflo(u.w), f7 = bfhi(u.w);
            int cb = gblk * 64 + chg * 8;
            float s1 = f0 * asrc_s[cb] + f1 * asrc_s[cb + 1] + f2 * asrc_s[cb + 2] + f3 * asrc_s[cb + 3]
                     + f4 * asrc_s[cb + 4] + f5 * asrc_s[cb + 5] + f6 * asrc_s[cb + 6] + f7 * asrc_s[cb + 7];
            float s2 = f0 * adst_s[cb] + f1 * adst_s[cb + 1] + f2 * adst_s[cb + 2] + f3 * adst_s[cb + 3]
                     + f4 * adst_s[cb + 4] + f5 * adst_s[cb + 5] + f6 * adst_s[cb + 6] + f7 * adst_s[cb + 7];
#pragma unroll
            for (int o = 1; o < 8; o <<= 1) {
                s1 += __shfl_xor(s1, o, 64);
                s2 += __shfl_xor(s2, o, 64);
            }
            if (gr < N_NODES) {
                *(uint4*)(C + (long)gr * NFULL + colg + chg * 8) = u;
                if ((lane & 7) == 0) {
                    as_[gr * H + hidx] = s1;
                    ad_[gr * H + hidx] = s2;
                }
            }
        }
    }
}

// ---------------- GAT aggregation H=4 (R3 structure: at ~3.3 TB/s gather ceiling, NO stats) ----------------
__global__ __launch_bounds__(256) void agg4_kernel(const ushort_t* __restrict__ h,
                                                   const float* __restrict__ as_,
                                                   const float* __restrict__ ad_,
                                                   const int* __restrict__ rowptr,
                                                   const int* __restrict__ srcs,
                                                   const float* __restrict__ bias,
                                                   ushort_t* __restrict__ out) {
    __shared__ float4 alf[4][4][17];   // [wave][quarter][edge] 4 head alphas (pad 17)
    __shared__ int    sed[4][4][17];   // [wave][quarter][edge] src id
    int tid = threadIdx.x;
    int lane = tid & 63, w = tid >> 6;
    int q = lane >> 4, cl = lane & 15;
    int n = blockIdx.x * 16 + w * 4 + q;   // grid exact: n < N_NODES always

    int start = rowptr[n];
    int deg = rowptr[n + 1] - start;

    float4 adv = *(const float4*)(ad_ + n * 4);
    float ad4[4] = {adv.x, adv.y, adv.z, adv.w};

    float mx[4] = {-1e30f, -1e30f, -1e30f, -1e30f};
    float dn[4] = {0.f, 0.f, 0.f, 0.f};
    {
        float vst[4] = {-1e30f, -1e30f, -1e30f, -1e30f};
        int s0 = 0;
        if (deg > 0) s0 = srcs[start + min(cl, deg - 1)];
        sed[w][q][cl] = s0;
        if (cl < deg) {
            float4 av = *(const float4*)(as_ + s0 * 4);
            float vv[4] = {av.x + ad4[0], av.y + ad4[1], av.z + ad4[2], av.w + ad4[3]};
#pragma unroll
            for (int hh = 0; hh < 4; ++hh) {
                float v = vv[hh] > 0.f ? vv[hh] : 0.2f * vv[hh];
                vst[hh] = v; mx[hh] = v; dn[hh] = 1.f;
            }
        }
        alf[w][q][cl] = make_float4(vst[0], vst[1], vst[2], vst[3]);
        for (int j = cl + 16; j < deg; j += 16) {
            int s = srcs[start + j];
            float4 av = *(const float4*)(as_ + s * 4);
            float vv[4] = {av.x + ad4[0], av.y + ad4[1], av.z + ad4[2], av.w + ad4[3]};
#pragma unroll
            for (int hh = 0; hh < 4; ++hh) {
                float v = vv[hh] > 0.f ? vv[hh] : 0.2f * vv[hh];
                float mn = fmaxf(mx[hh], v);
                dn[hh] = dn[hh] * __expf(mx[hh] - mn) + __expf(v - mn);
                mx[hh] = mn;
            }
        }
    }
    float mloc[4] = {mx[0], mx[1], mx[2], mx[3]};
#pragma unroll
    for (int off = 1; off < 16; off <<= 1)
#pragma unroll
        for (int hh = 0; hh < 4; ++hh) mx[hh] = fmaxf(mx[hh], __shfl_xor(mx[hh], off, 64));
#pragma unroll
    for (int hh = 0; hh < 4; ++hh) dn[hh] *= __expf(mloc[hh] - mx[hh]);
#pragma unroll
    for (int off = 1; off < 16; off <<= 1)
#pragma unroll
        for (int hh = 0; hh < 4; ++hh) dn[hh] += __shfl_xor(dn[hh], off, 64);
    float inv[4];
#pragma unroll
    for (int hh = 0; hh < 4; ++hh) inv[hh] = dn[hh] > 0.f ? 1.f / dn[hh] : 0.f;
    {
        float4 vv = alf[w][q][cl];   // logits -> alphas (OOB lanes: exp(-1e30-mx)=0)
        alf[w][q][cl] = make_float4(__expf(vv.x - mx[0]) * inv[0], __expf(vv.y - mx[1]) * inv[1],
                                    __expf(vv.z - mx[2]) * inv[2], __expf(vv.w - mx[3]) * inv[3]);
    }

    int hd = cl >> 2, cbase = cl * 16;
    float acc[16];
#pragma unroll
    for (int k = 0; k < 16; ++k) acc[k] = 0.f;

    for (int chunk = 0; chunk < deg || chunk == 0; chunk += 16) {
        if (chunk > 0) {
            int j = chunk + cl;
            int s = srcs[start + min(j, deg - 1)];
            sed[w][q][cl] = s;
            float a4[4] = {0.f, 0.f, 0.f, 0.f};
            if (j < deg) {
                float4 av = *(const float4*)(as_ + s * 4);
                float vv[4] = {av.x + ad4[0], av.y + ad4[1], av.z + ad4[2], av.w + ad4[3]};
#pragma unroll
                for (int hh = 0; hh < 4; ++hh) {
                    float v = vv[hh] > 0.f ? vv[hh] : 0.2f * vv[hh];
                    a4[hh] = __expf(v - mx[hh]) * inv[hh];
                }
            }
            alf[w][q][cl] = make_float4(a4[0], a4[1], a4[2], a4[3]);
        }
        int cnt = min(16, deg - chunk);
        if (cnt < 0) cnt = 0;
        int e = 0;
        // 4-edge groups, half-row batches: 4 uint4 in flight, 2 batches per group
        for (; e + 4 <= cnt; e += 4) {
            float av[4]; int sv[4];
#pragma unroll
            for (int t = 0; t < 4; ++t) {
                av[t] = ((const float*)&alf[w][q][e + t])[hd];
                sv[t] = sed[w][q][e + t];
            }
            uint4 ua[4];
#pragma unroll
            for (int t = 0; t < 4; ++t)
                ua[t] = *(const uint4*)(h + (long)sv[t] * 256 + cbase);
#pragma unroll
            for (int t = 0; t < 4; ++t) {
                float al = av[t];
                acc[0] += al * bflo(ua[t].x); acc[1] += al * bfhi(ua[t].x);
                acc[2] += al * bflo(ua[t].y); acc[3] += al * bfhi(ua[t].y);
                acc[4] += al * bflo(ua[t].z); acc[5] += al * bfhi(ua[t].z);
                acc[6] += al * bflo(ua[t].w); acc[7] += al * bfhi(ua[t].w);
            }
#pragma unroll
            for (int t = 0; t < 4; ++t)
                ua[t] = *(const uint4*)(h + (long)sv[t] * 256 + cbase + 8);
#pragma unroll
            for (int t = 0; t < 4; ++t) {
                float al = av[t];
                acc[8]  += al * bflo(ua[t].x); acc[9]  += al * bfhi(ua[t].x);
                acc[10] += al * bflo(ua[t].y); acc[11] += al * bfhi(ua[t].y);
                acc[12] += al * bflo(ua[t].z); acc[13] += al * bfhi(ua[t].z);
                acc[14] += al * bflo(ua[t].w); acc[15] += al * bfhi(ua[t].w);
            }
        }
        for (; e < cnt; ++e) {   // exact tail, 1 edge
            float al = ((const float*)&alf[w][q][e])[hd];
            const ushort_t* hr = h + (long)sed[w][q][e] * 256 + cbase;
            uint4 u0 = *(const uint4*)hr;
            uint4 u1 = *(const uint4*)(hr + 8);
            acc[0]  += al * bflo(u0.x); acc[1]  += al * bfhi(u0.x);
            acc[2]  += al * bflo(u0.y); acc[3]  += al * bfhi(u0.y);
            acc[4]  += al * bflo(u0.z); acc[5]  += al * bfhi(u0.z);
            acc[6]  += al * bflo(u0.w); acc[7]  += al * bfhi(u0.w);
            acc[8]  += al * bflo(u1.x); acc[9]  += al * bfhi(u1.x);
            acc[10] += al * bflo(u1.y); acc[11] += al * bfhi(u1.y);
            acc[12] += al * bflo(u1.z); acc[13] += al * bfhi(u1.z);
            acc[14] += al * bflo(u1.w); acc[15] += al * bfhi(u1.w);
        }
        if (deg <= 16) break;
    }

    // epilogue: bias + relu, bf16 store
    uint_t ow[8];
#pragma unroll
    for (int t = 0; t < 8; ++t) {
        float lo = fmaxf(acc[t * 2] + bias[cbase + t * 2], 0.f);
        float hi = fmaxf(acc[t * 2 + 1] + bias[cbase + t * 2 + 1], 0.f);
        ow[t] = pkbf(lo, hi);
    }
    ushort_t* op = out + (long)n * 256 + cbase;
    *(uint4*)op = make_uint4(ow[0], ow[1], ow[2], ow[3]);
    *(uint4*)(op + 8) = make_uint4(ow[4], ow[5], ow[6], ow[7]);
}

// ---------------- GAT aggregation H=1: fused BN stats (striped) ----------------
__global__ __launch_bounds__(256) void agg1_kernel(const ushort_t* __restrict__ h,
                                                   const float* __restrict__ as_,
                                                   const float* __restrict__ ad_,
                                                   const int* __restrict__ rowptr,
                                                   const int* __restrict__ srcs,
                                                   const float* __restrict__ bias,
                                                   ushort_t* __restrict__ out,
                                                   float* __restrict__ stats) {
    __shared__ float alf1[4][8][9];
    __shared__ int   sed1[4][8][9];
    __shared__ float ssum[64], ssq[64];
    int tid = threadIdx.x;
    int lane = tid & 63, w = tid >> 6;
    int o = lane >> 3, cl = lane & 7;
    int n = blockIdx.x * 32 + w * 8 + o;
    bool valid = n < N_NODES;
    int nc = valid ? n : N_NODES - 1;
    if (tid < 64) { ssum[tid] = 0.f; ssq[tid] = 0.f; }
    __syncthreads();

    int start = rowptr[nc];
    int deg = valid ? rowptr[nc + 1] - start : 0;
    float adn = ad_[nc];

    float mx = -1e30f, dn = 0.f;
    {
        float vst = -1e30f;
        int s0 = 0;
        if (deg > 0) s0 = srcs[start + min(cl, deg - 1)];
        sed1[w][o][cl] = s0;
        if (cl < deg) {
            float v = as_[s0] + adn;
            v = v > 0.f ? v : 0.2f * v;
            vst = v; mx = v; dn = 1.f;
        }
        alf1[w][o][cl] = vst;
        for (int j = cl + 8; j < deg; j += 8) {
            int s = srcs[start + j];
            float v = as_[s] + adn;
            v = v > 0.f ? v : 0.2f * v;
            float mn = fmaxf(mx, v);
            dn = dn * __expf(mx - mn) + __expf(v - mn);
            mx = mn;
        }
    }
    float mloc = mx;
#pragma unroll
    for (int off = 1; off < 8; off <<= 1) mx = fmaxf(mx, __shfl_xor(mx, off, 64));
    dn *= __expf(mloc - mx);
#pragma unroll
    for (int off = 1; off < 8; off <<= 1) dn += __shfl_xor(dn, off, 64);
    float inv = dn > 0.f ? 1.f / dn : 0.f;

    alf1[w][o][cl] = __expf(alf1[w][o][cl] - mx) * inv;

    int c0 = cl * 8;
    float acc[8] = {0.f, 0.f, 0.f, 0.f, 0.f, 0.f, 0.f, 0.f};

    for (int chunk = 0; chunk < deg || chunk == 0; chunk += 8) {
        if (chunk > 0) {
            int j = chunk + cl;
            int s = srcs[start + min(j, deg - 1)];
            sed1[w][o][cl] = s;
            float al = 0.f;
            if (j < deg) {
                float v = as_[s] + adn;
                v = v > 0.f ? v : 0.2f * v;
                al = __expf(v - mx) * inv;
            }
            alf1[w][o][cl] = al;
        }
        int cnt = min(8, deg - chunk);
        if (cnt < 0) cnt = 0;
        int e = 0;
        for (; e + 4 <= cnt; e += 4) {
            float av[4]; int sv[4];
#pragma unroll
            for (int t = 0; t < 4; ++t) {
                av[t] = alf1[w][o][e + t];
                sv[t] = sed1[w][o][e + t];
            }
            uint4 ua[4];
#pragma unroll
            for (int t = 0; t < 4; ++t)
                ua[t] = *(const uint4*)(h + (long)sv[t] * 64 + c0);
#pragma unroll
            for (int t = 0; t < 4; ++t) {
                float al = av[t];
                acc[0] += al * bflo(ua[t].x); acc[1] += al * bfhi(ua[t].x);
                acc[2] += al * bflo(ua[t].y); acc[3] += al * bfhi(ua[t].y);
                acc[4] += al * bflo(ua[t].z); acc[5] += al * bfhi(ua[t].z);
                acc[6] += al * bflo(ua[t].w); acc[7] += al * bfhi(ua[t].w);
            }
        }
        for (; e < cnt; ++e) {
            float al = alf1[w][o][e];
            uint4 u = *(const uint4*)(h + (long)sed1[w][o][e] * 64 + c0);
            acc[0] += al * bflo(u.x); acc[1] += al * bfhi(u.x);
            acc[2] += al * bflo(u.y); acc[3] += al * bfhi(u.y);
            acc[4] += al * bflo(u.z); acc[5] += al * bfhi(u.z);
            acc[6] += al * bflo(u.w); acc[7] += al * bfhi(u.w);
        }
        if (deg <= 8) break;
    }

    float v[8];
#pragma unroll
    for (int t = 0; t < 8; ++t) v[t] = fmaxf(acc[t] + bias[c0 + t], 0.f);
    if (valid) {
        uint_t ow[4];
#pragma unroll
        for (int t = 0; t < 4; ++t) ow[t] = pkbf(v[2 * t], v[2 * t + 1]);
        *(uint4*)(out + (long)n * 64 + c0) = make_uint4(ow[0], ow[1], ow[2], ow[3]);
    }
    float s1[8], s2[8];
#pragma unroll
    for (int t = 0; t < 8; ++t) {
        s1[t] = valid ? v[t] : 0.f;
        s2[t] = valid ? v[t] * v[t] : 0.f;
    }
#pragma unroll
    for (int off = 8; off < 64; off <<= 1)    // reduce 8 octants (same cl -> same channels)
#pragma unroll
        for (int t = 0; t < 8; ++t) {
            s1[t] += __shfl_xor(s1[t], off, 64);
            s2[t] += __shfl_xor(s2[t], off, 64);
        }
    if (lane < 8) {
#pragma unroll
        for (int t = 0; t < 8; ++t) {
            atomicAdd(&ssum[c0 + t], s1[t]);
            atomicAdd(&ssq[c0 + t], s2[t]);
        }
    }
    __syncthreads();
    if (tid < 64) {
        int cp = (blockIdx.x & (NCOPY - 1)) * 512;   // striped copy
        atomicAdd(&stats[cp + tid], ssum[tid]);
        atomicAdd(&stats[cp + 256 + tid], ssq[tid]);
    }
}

// ---------------- BatchNorm stats on bf16, coalesced, striped output ----------------
template<int C>
__global__ __launch_bounds__(256) void bn_stats_bf16(const ushort_t* __restrict__ x,
                                                     float* __restrict__ stats) {
    const int GROUPS = C / 8;
    const int RS = 256 / GROUPS;
    int tid = threadIdx.x;
    int cg_ = tid % GROUPS;
    int rs = tid / GROUPS;
    float s[8], s2[8];
#pragma unroll
    for (int k = 0; k < 8; ++k) { s[k] = 0.f; s2[k] = 0.f; }
    for (int n = blockIdx.x * RS + rs; n < N_NODES; n += gridDim.x * RS) {
        uint4 u = *(const uint4*)(x + (long)n * C + cg_ * 8);
        float f[8] = {bflo(u.x), bfhi(u.x), bflo(u.y), bfhi(u.y),
                      bflo(u.z), bfhi(u.z), bflo(u.w), bfhi(u.w)};
#pragma unroll
        for (int k = 0; k < 8; ++k) { s[k] += f[k]; s2[k] += f[k] * f[k]; }
    }
    __shared__ float red[256][16];
#pragma unroll
    for (int k = 0; k < 8; ++k) { red[tid][k] = s[k]; red[tid][8 + k] = s2[k]; }
    __syncthreads();
    if (tid < C) {
        int g = tid >> 3, k = tid & 7;
        float a = 0.f, b = 0.f;
        for (int r = 0; r < RS; ++r) {
            a += red[g + r * GROUPS][k];
            b += red[g + r * GROUPS][8 + k];
        }
        int cp = (blockIdx.x & (NCOPY - 1)) * 512;   // striped: ~2 blocks/address at 128 blocks
        atomicAdd(&stats[cp + tid], a);
        atomicAdd(&stats[cp + 256 + tid], b);
    }
}

// ---------------- pool (BN affine fused, striped-stats reduce) + FC; goff inlined ----------------
__global__ __launch_bounds__(256) void pool_fc_kernel(const ushort_t* __restrict__ h,
                                                      const int* __restrict__ batch,
                                                      const float* __restrict__ stats,
                                                      const float* __restrict__ g3,
                                                      const float* __restrict__ be3,
                                                      const float* __restrict__ fcW,
                                                      const float* __restrict__ fcb,
                                                      float* __restrict__ out) {
    int g = blockIdx.x;
    __shared__ int se[2];
    if (threadIdx.x < 2) {
        int gg = g + threadIdx.x;
        int lo = 0, hi = N_NODES;
        while (lo < hi) {
            int mid = (lo + hi) >> 1;
            if (batch[mid] < gg) lo = mid + 1; else hi = mid;
        }
        se[threadIdx.x] = lo;
    }
    __syncthreads();
    int s = se[0], e = se[1];
    int c = threadIdx.x & 63;
    int ty = threadIdx.x >> 6;
    float sum = 0.f;
    for (int n = s + ty; n < e; n += 4) sum += bflo((uint_t)h[(long)n * 64 + c]);
    __shared__ float red[4][64];
    __shared__ float pv[64];
    red[ty][c] = sum;
    __syncthreads();
    if (ty == 0) {
        float tot = red[0][c] + red[1][c] + red[2][c] + red[3][c];
        float v = tot / fmaxf((float)(e - s), 1.f);
        float s0 = 0.f, s1 = 0.f;
#pragma unroll 8
        for (int j = 0; j < NCOPY; ++j) {
            s0 += stats[j * 512 + c];
            s1 += stats[j * 512 + 256 + c];
        }
        float m = s0 * (1.f / N_NODES);
        float var = fmaxf(s1 * (1.f / N_NODES) - m * m, 0.f);
        pv[c] = (v - m) * rsqrtf(var + EPS_BN) * g3[c] + be3[c];
    }
    __syncthreads();
    if (threadIdx.x < 10) {
        int j = threadIdx.x;
        float acc = fcb[j];
#pragma unroll
        for (int k = 0; k < 64; ++k) acc += pv[k] * fcW[k * 10 + j];
        out[g * 10 + j] = acc;
    }
}

extern "C" void kernel_launch(void* const* d_in, const int* in_sizes, int n_in,
                              void* d_out, int out_size, void* d_ws, size_t ws_size,
                              hipStream_t stream) {
    const float* x      = (const float*)d_in[0];
    const int*   ei     = (const int*)d_in[1];
    const int*   batch  = (const int*)d_in[2];
    const float* W1     = (const float*)d_in[3];
    const float* a_src1 = (const float*)d_in[4];
    const float* a_dst1 = (const float*)d_in[5];
    const float* b1     = (const float*)d_in[6];
    const float* g1     = (const float*)d_in[7];
    const float* be1    = (const float*)d_in[8];
    const float* W2     = (const float*)d_in[9];
    const float* a_src2 = (const float*)d_in[10];
    const float* a_dst2 = (const float*)d_in[11];
    const float* b2     = (const float*)d_in[12];
    const float* g2     = (const float*)d_in[13];
    const float* be2    = (const float*)d_in[14];
    const float* W3     = (const float*)d_in[15];
    const float* a_src3 = (const float*)d_in[16];
    const float* a_dst3 = (const float*)d_in[17];
    const float* b3     = (const float*)d_in[18];
    const float* g3     = (const float*)d_in[19];
    const float* be3    = (const float*)d_in[20];
    const float* fcW    = (const float*)d_in[21];
    const float* fcb    = (const float*)d_in[22];
    float* out = (float*)d_out;

    const size_t N = N_NODES, E = NUM_E;
    const size_t NPAD = N + 128;                        // gload_lds reads past N (no predication)
    const int SST = NCOPY * 512;                        // striped stats size
    ushort_t* hbf    = (ushort_t*)d_ws;                 // [NPAD,256] bf16 GEMM output
    ushort_t* hagg   = hbf + NPAD * 256;                // [NPAD,256] bf16 agg output (pre-BN)
    ushort_t* xbf    = hagg + NPAD * 256;               // [NPAD,128] bf16 x
    ushort_t* w1t    = xbf + NPAD * 128;                // [256][128]
    ushort_t* w2t    = w1t + 256 * 128;                 // [256][256]
    ushort_t* w3t    = w2t + 256 * 256;                 // [64][256]
    ushort_t* w2ts   = w3t + 64 * 256;                  // [256][256] BN-scaled
    ushort_t* w3ts   = w2ts + 256 * 256;                // [64][256]  BN-scaled
    float*    as_    = (float*)(w3ts + 64 * 256 + 128); // [N,4]
    float*    ad_    = as_ + N * 4;                     // [N,4]
    int*      deg    = (int*)(ad_ + N * 4);             // [N]   (zero region start)
    int*      fill   = deg + N;                         // [N]
    float*    statsA = (float*)(fill + N);              // [NCOPY*512]
    float*    statsB = statsA + SST;                    // [NCOPY*512]
    float*    statsC = statsB + SST;                    // [NCOPY*512]
    float*    cvec0  = statsC + SST;                    // [256] zeros (layer-1 cvec)
    int*      rowptr = (int*)(cvec0 + 256);             // [N+1]
    int*      srcs   = rowptr + (N + 1);                // [E]
    int*      bsum   = srcs + E;                        // [256]
    float*    cvec2  = (float*)(bsum + 256);            // [256]
    float*    cvec3  = cvec2 + 256;                     // [64]

    const int NB = (N_NODES + 255) / 256;  // 196
    const int HB = (NUM_E + 255) / 256;    // 3125
    const int SX = N_NODES * 128 / 4;
    const int SW = 128 * 256 + 256 * 256 + 256 * 64;
    const int PB = (SX + SW + 255) / 256;  // 6570

    // ---- setup ----
    hipMemsetAsync(deg, 0, sizeof(int) * (2 * N + 3 * SST + 256), stream);
    hist_prep_kernel<<<HB + PB, 256, 0, stream>>>(ei, deg, W1, W2, W3, x, w1t, w2t, w3t, xbf);
    scan_local_kernel<<<NB, 256, 0, stream>>>(deg, rowptr, bsum);
    scan_fixup_kernel<<<NB, 256, 0, stream>>>(rowptr, bsum);

    const int GB = (N_NODES + 127) / 128;  // 391
    const int AB = N_NODES / 16;           // 3125 (exact: 50000 % 16 == 0)

    // ---- layer 1 (cvec0 zeros, W1 unscaled); scatter merged into the gemm1 dispatch ----
    gemm_fused_kernel<128, 256, 128, true><<<dim3(GB + 1563, 2), 256, 0, stream>>>(
        xbf, w1t, hbf, cvec0, a_src1, a_dst1, as_, ad_,
        ei, rowptr, fill, srcs);
    agg4_kernel<<<AB, 256, 0, stream>>>(hbf, as_, ad_, rowptr, srcs, b1, hagg);
    bn_stats_bf16<256><<<128, 256, 0, stream>>>(hagg, statsA);

    // ---- layer 2: fold BN1 into W2 (pure-copy staging) ----
    scale_w_kernel<<<256, 256, 0, stream>>>(statsA, g1, be1, w2t, w2ts, cvec2);
    gemm_fused_kernel<256, 256, 128, false><<<dim3(GB, 2), 256, 0, stream>>>(
        hagg, w2ts, hbf, cvec2, a_src2, a_dst2, as_, ad_,
        nullptr, nullptr, nullptr, nullptr);
    agg4_kernel<<<AB, 256, 0, stream>>>(hbf, as_, ad_, rowptr, srcs, b2, hagg);
    bn_stats_bf16<256><<<128, 256, 0, stream>>>(hagg, statsB);

    // ---- layer 3: fold BN2 into W3 ----
    scale_w_kernel<<<64, 256, 0, stream>>>(statsB, g2, be2, w3t, w3ts, cvec3);
    gemm_fused_kernel<256, 64, 64, false><<<dim3(GB, 1), 256, 0, stream>>>(
        hagg, w3ts, hbf, cvec3, a_src3, a_dst3, as_, ad_,
        nullptr, nullptr, nullptr, nullptr);
    agg1_kernel<<<(N_NODES + 31) / 32, 256, 0, stream>>>(hbf, as_, ad_, rowptr, srcs, b3, hagg, statsC);

    // ---- pool + BN3 affine + FC in one (goff inlined, striped-stats reduce) ----
    pool_fc_kernel<<<NUM_GRAPHS, 256, 0, stream>>>(hagg, batch, statsC, g3, be3, fcW, fcb, out);
}

// Round 9
// 475.166 us; speedup vs baseline: 1.3207x; 1.0105x over previous
//
#include <hip/hip_runtime.h>
#include <hip/hip_bf16.h>

#define N_NODES 50000
#define NUM_E   800000
#define EPS_BN  1e-5f
#define NUM_GRAPHS 64
#define NCOPY 64   // striped stats copies (R5/R6: global-atomic serialization fix)

typedef __attribute__((ext_vector_type(8))) short bf16x8;
typedef __attribute__((ext_vector_type(4))) float f32x4;
typedef unsigned short ushort_t;
typedef unsigned int uint_t;

static __device__ __forceinline__ unsigned short f2bf(float f) {
    unsigned int u = __float_as_uint(f);
    u += 0x7fffu + ((u >> 16) & 1u);   // RNE
    return (unsigned short)(u >> 16);
}
static __device__ __forceinline__ uint_t pkbf(float lo, float hi) {
    __hip_bfloat162 t = __float22bfloat162_rn(make_float2(lo, hi));
    return *(uint_t*)&t;
}
static __device__ __forceinline__ float bflo(uint_t u) { return __uint_as_float(u << 16); }
static __device__ __forceinline__ float bfhi(uint_t u) { return __uint_as_float(u & 0xffff0000u); }

// ---------------- hist + prep merged (independent work, block-range split) ----------------
__global__ void hist_prep_kernel(const int* __restrict__ ei, int* __restrict__ deg,
                                 const float* __restrict__ W1, const float* __restrict__ W2,
                                 const float* __restrict__ W3, const float* __restrict__ x,
                                 ushort_t* __restrict__ w1t, ushort_t* __restrict__ w2t,
                                 ushort_t* __restrict__ w3t, ushort_t* __restrict__ xbf) {
    const int HB = (NUM_E + 255) / 256;          // 3125 hist blocks
    const int S1 = 128 * 256, S2 = 256 * 256, S3 = 256 * 64;
    const int SW = S1 + S2 + S3;                 // 81920
    const int SX = N_NODES * 128 / 4;            // 1.6M float4 units
    int b = blockIdx.x;
    if (b < HB) {
        int e = b * 256 + threadIdx.x;
        if (e < NUM_E) atomicAdd(&deg[ei[NUM_E + e]], 1);
        return;
    }
    int i = (b - HB) * 256 + threadIdx.x;
    if (i < SX) {
        float4 v = ((const float4*)x)[i];
        ((uint2*)xbf)[i] = make_uint2(pkbf(v.x, v.y), pkbf(v.z, v.w));
    } else if (i < SX + SW) {
        int j = i - SX;
        if (j < S1) {
            int k = j / 256, n = j % 256;
            w1t[n * 128 + k] = f2bf(W1[j]);
        } else if (j < S1 + S2) {
            int jj = j - S1; int k = jj / 256, n = jj % 256;
            w2t[n * 256 + k] = f2bf(W2[jj]);
        } else {
            int jj = j - S1 - S2; int k = jj / 64, n = jj % 64;
            w3t[n * 256 + k] = f2bf(W3[jj]);
        }
    }
}

__global__ void scan_local_kernel(const int* __restrict__ deg, int* __restrict__ rowptr,
                                  int* __restrict__ bsum) {
    __shared__ int ws[4];
    int b = blockIdx.x, t = threadIdx.x;
    int i = b * 256 + t;
    int lane = t & 63, wv = t >> 6;
    int v = (i < N_NODES) ? deg[i] : 0;
    int incl = v;
#pragma unroll
    for (int off = 1; off < 64; off <<= 1) {
        int u = __shfl_up(incl, off, 64);
        if (lane >= off) incl += u;
    }
    if (lane == 63) ws[wv] = incl;
    __syncthreads();
    if (t == 0) {
        int s = 0;
#pragma unroll
        for (int k = 0; k < 4; ++k) { int x = ws[k]; ws[k] = s; s += x; }
        bsum[b] = s;
    }
    __syncthreads();
    if (i < N_NODES) rowptr[i + 1] = ws[wv] + incl;
}

// merged scan_sums + scan_add: each block redundantly sums its bsum prefix (196 entries, trivial)
__global__ __launch_bounds__(256) void scan_fixup_kernel(int* __restrict__ rowptr,
                                                         const int* __restrict__ bsum) {
    __shared__ int ws[4];
    int b = blockIdx.x, t = threadIdx.x;
    int lane = t & 63, wv = t >> 6;
    int v = (t < b) ? bsum[t] : 0;   // b <= 195 < 256, t < b => valid index
#pragma unroll
    for (int off = 1; off < 64; off <<= 1) v += __shfl_xor(v, off, 64);
    if (lane == 0) ws[wv] = v;
    __syncthreads();
    int pre = ws[0] + ws[1] + ws[2] + ws[3];
    int i = b * 256 + t;
    if (i < N_NODES) rowptr[i + 1] += pre;
    if (b == 0 && t == 0) rowptr[0] = 0;
}

// ---------------- BN fold into W (striped stats reduce): Wts = a*Wt, cvec = b@W ----------------
__global__ __launch_bounds__(256) void scale_w_kernel(const float* __restrict__ stats,
                                                      const float* __restrict__ g,
                                                      const float* __restrict__ be,
                                                      const ushort_t* __restrict__ wt,
                                                      ushort_t* __restrict__ wts,
                                                      float* __restrict__ cvec) {
    int n = blockIdx.x, k = threadIdx.x;
    float s0 = 0.f, s1 = 0.f;
#pragma unroll 8
    for (int j = 0; j < NCOPY; ++j) {          // 128KB striped stats, L2-resident
        s0 += stats[j * 512 + k];
        s1 += stats[j * 512 + 256 + k];
    }
    float m = s0 * (1.f / N_NODES);
    float var = fmaxf(s1 * (1.f / N_NODES) - m * m, 0.f);
    float rs = rsqrtf(var + EPS_BN) * g[k];
    float b = be[k] - m * rs;
    float wv = bflo((uint_t)wt[n * 256 + k]);
    wts[n * 256 + k] = f2bf(rs * wv);
    float p = b * wv;
    __shared__ float ws[4];
    int lane = k & 63, wid = k >> 6;
#pragma unroll
    for (int off = 1; off < 64; off <<= 1) p += __shfl_xor(p, off, 64);
    if (lane == 0) ws[wid] = p;
    __syncthreads();
    if (k == 0) cvec[n] = ws[0] + ws[1] + ws[2] + ws[3];
}

// ---------------- GEMM: A(bf16) @ Bt^T + cvec -> h(bf16) + per-head logits ----------------
// Staging via global_load_lds (16B). LDS linear [row][32]; R9: slot-XOR swizzle (slot ^= row&3)
// applied on BOTH the gload_lds SOURCE address (LDS dest stays linear, m173 pattern) and the
// ds_read fragment address => 8-way bank conflict -> 4-way (rule #21: both sides or neither).
// LDS slot sl of row r holds global slot sl^(r&3); reading slot q^(r&3) returns global slot q.
// A buffers row-PADDED (+128): gload_lds has no per-lane predication; garbage rows discarded by
// the gr<N_NODES store guard. SCAT=true: extra blocks run CSR scatter (saves a launch).
template<int K, int NFULL, int BN, bool SCAT>
__global__ __launch_bounds__(256) void gemm_fused_kernel(const ushort_t* __restrict__ A,
                                                         const ushort_t* __restrict__ Bt,
                                                         ushort_t* __restrict__ C,
                                                         const float* __restrict__ cvec,
                                                         const float* __restrict__ a_src,
                                                         const float* __restrict__ a_dst,
                                                         float* __restrict__ as_,
                                                         float* __restrict__ ad_,
                                                         const int* __restrict__ ei,
                                                         const int* __restrict__ rowptr,
                                                         int* __restrict__ fill,
                                                         int* __restrict__ srcs) {
    constexpr int GBX = (N_NODES + 127) / 128;   // 391
    if constexpr (SCAT) {
        if (blockIdx.x >= GBX) {
            int idx = (blockIdx.x - GBX) + 1563 * blockIdx.y;
            int e = idx * 256 + (int)threadIdx.x;
            if (e < NUM_E) {
                int dst = ei[NUM_E + e];
                int pos = rowptr[dst] + atomicAdd(&fill[dst], 1);
                srcs[pos] = ei[e];
            }
            return;
        }
    }
    const int NT = BN / 16;
    const int NG = BN / 64;
    constexpr int LOOP_BYTES = (128 * 32 + BN * 32) * 2;
    constexpr int EPI_BYTES  = 4 * 32 * 64 * 2;
    constexpr int SMEM_BYTES = LOOP_BYTES > EPI_BYTES ? LOOP_BYTES : EPI_BYTES;
    __shared__ __align__(16) unsigned char smem[SMEM_BYTES];
    ushort_t* As = (ushort_t*)smem;                     // [128][32] linear (slot-swizzled content)
    ushort_t* Bs = As + 128 * 32;                       // [BN][32]
    ushort_t (*Cs)[32][64] = (ushort_t (*)[32][64])smem;  // epilogue alias (post-final-barrier)
    __shared__ float cvec_s[BN];
    __shared__ float asrc_s[BN], adst_s[BN];
    int tid = threadIdx.x;
    int lane = tid & 63, w = tid >> 6;
    int row0 = blockIdx.x * 128, col0 = blockIdx.y * BN;
    int m_l = lane & 15, q = lane >> 4;

    if (tid < BN) {
        cvec_s[tid] = cvec[col0 + tid];
        asrc_s[tid] = a_src[col0 + tid];
        adst_s[tid] = a_dst[col0 + tid];
    }

    f32x4 acc[2][NT];
#pragma unroll
    for (int r = 0; r < 2; ++r)
#pragma unroll
        for (int c = 0; c < NT; ++c) acc[r][c] = (f32x4){0.f, 0.f, 0.f, 0.f};

    int rsub = lane >> 2;                         // 0..15: row within 16-row group
    int ssub = (lane & 3) ^ (rsub & 3);           // swizzled source slot (16B units)
    int csub = ssub * 8;                          // elem col offset
    int fsw = (q ^ (m_l & 3)) * 8;                // swizzled fragment-read col (elems)

    for (int k0 = 0; k0 < K; k0 += 32) {
        // A: wave w stages rows [w*32, w*32+32): 2 calls x 1KB (16 rows each)
        {
            const ushort_t* ag = A + (long)(row0 + w * 32 + rsub) * K + k0 + csub;
            __builtin_amdgcn_global_load_lds(ag, As + (w * 32) * 32, 16, 0, 0);
            __builtin_amdgcn_global_load_lds(ag + 16 * K, As + (w * 32 + 16) * 32, 16, 0, 0);
        }
        if constexpr (BN == 128) {
            const ushort_t* bg = Bt + (long)(col0 + w * 32 + rsub) * K + k0 + csub;
            __builtin_amdgcn_global_load_lds(bg, Bs + (w * 32) * 32, 16, 0, 0);
            __builtin_amdgcn_global_load_lds(bg + 16 * K, Bs + (w * 32 + 16) * 32, 16, 0, 0);
        } else {   // BN == 64: wave w stages rows [w*16, w*16+16)
            const ushort_t* bg = Bt + (long)(col0 + w * 16 + rsub) * K + k0 + csub;
            __builtin_amdgcn_global_load_lds(bg, Bs + (w * 16) * 32, 16, 0, 0);
        }
        __syncthreads();   // compiler drains vmcnt before barrier

        bf16x8 af[2];
#pragma unroll
        for (int r = 0; r < 2; ++r)
            af[r] = *(const bf16x8*)(As + (w * 32 + r * 16 + m_l) * 32 + fsw);
#pragma unroll
        for (int c = 0; c < NT; ++c) {
            bf16x8 bf = *(const bf16x8*)(Bs + (c * 16 + m_l) * 32 + fsw);
#pragma unroll
            for (int r = 0; r < 2; ++r)
                acc[r][c] = __builtin_amdgcn_mfma_f32_16x16x32_bf16(af[r], bf, acc[r][c], 0, 0, 0);
        }
        __syncthreads();   // after this barrier As/Bs are dead -> Cs may alias
    }

    const int H = NFULL / 64;
#pragma unroll
    for (int gblk = 0; gblk < NG; ++gblk) {
        int hidx = blockIdx.y * NG + gblk;
        int colg = col0 + gblk * 64;
#pragma unroll
        for (int r = 0; r < 2; ++r)
#pragma unroll
            for (int cc = 0; cc < 4; ++cc)
#pragma unroll
                for (int i = 0; i < 4; ++i)
                    Cs[w][r * 16 + q * 4 + i][cc * 16 + m_l] =
                        f2bf(acc[r][gblk * 4 + cc][i] + cvec_s[gblk * 64 + cc * 16 + m_l]);
        // same-wave LDS RAW: in-order DS pipe, no barrier needed
#pragma unroll
        for (int j = 0; j < 4; ++j) {
            int flat = j * 64 + lane;
            int lr = flat >> 3, chg = flat & 7;
            int gr = row0 + w * 32 + lr;
            uint4 u = *(uint4*)&Cs[w][lr][chg * 8];
            float f0 = bflo(u.x), f1 = bfhi(u.x), f2 = bflo(u.y), f3 = bfhi(u.y);
            float f4 = bflo(u.z), f5 = bfhi(u.z), f6 = bflo(u.w), f7 = bfhi(u.w);
            int cb = gblk * 64 + chg * 8;
            float s1 = f0 * asrc_s[cb] + f1 * asrc_s[cb + 1] + f2 * asrc_s[cb + 2] + f3 * asrc_s[cb + 3]
                     + f4 * asrc_s[cb + 4] + f5 * asrc_s[cb + 5] + f6 * asrc_s[cb + 6] + f7 * asrc_s[cb + 7];
            float s2 = f0 * adst_s[cb] + f1 * adst_s[cb + 1] + f2 * adst_s[cb + 2] + f3 * adst_s[cb + 3]
                     + f4 * adst_s[cb + 4] + f5 * adst_s[cb + 5] + f6 * adst_s[cb + 6] + f7 * adst_s[cb + 7];
#pragma unroll
            for (int o = 1; o < 8; o <<= 1) {
                s1 += __shfl_xor(s1, o, 64);
                s2 += __shfl_xor(s2, o, 64);
            }
            if (gr < N_NODES) {
                *(uint4*)(C + (long)gr * NFULL + colg + chg * 8) = u;
                if ((lane & 7) == 0) {
                    as_[gr * H + hidx] = s1;
                    ad_[gr * H + hidx] = s2;
                }
            }
        }
    }
}

// ---------------- GAT aggregation H=4 (R3 structure: at ~3.3 TB/s gather ceiling, NO stats) ----------------
__global__ __launch_bounds__(256) void agg4_kernel(const ushort_t* __restrict__ h,
                                                   const float* __restrict__ as_,
                                                   const float* __restrict__ ad_,
                                                   const int* __restrict__ rowptr,
                                                   const int* __restrict__ srcs,
                                                   const float* __restrict__ bias,
                                                   ushort_t* __restrict__ out) {
    __shared__ float4 alf[4][4][17];   // [wave][quarter][edge] 4 head alphas (pad 17)
    __shared__ int    sed[4][4][17];   // [wave][quarter][edge] src id
    int tid = threadIdx.x;
    int lane = tid & 63, w = tid >> 6;
    int q = lane >> 4, cl = lane & 15;
    int n = blockIdx.x * 16 + w * 4 + q;   // grid exact: n < N_NODES always

    int start = rowptr[n];
    int deg = rowptr[n + 1] - start;

    float4 adv = *(const float4*)(ad_ + n * 4);
    float ad4[4] = {adv.x, adv.y, adv.z, adv.w};

    float mx[4] = {-1e30f, -1e30f, -1e30f, -1e30f};
    float dn[4] = {0.f, 0.f, 0.f, 0.f};
    {
        float vst[4] = {-1e30f, -1e30f, -1e30f, -1e30f};
        int s0 = 0;
        if (deg > 0) s0 = srcs[start + min(cl, deg - 1)];
        sed[w][q][cl] = s0;
        if (cl < deg) {
            float4 av = *(const float4*)(as_ + s0 * 4);
            float vv[4] = {av.x + ad4[0], av.y + ad4[1], av.z + ad4[2], av.w + ad4[3]};
#pragma unroll
            for (int hh = 0; hh < 4; ++hh) {
                float v = vv[hh] > 0.f ? vv[hh] : 0.2f * vv[hh];
                vst[hh] = v; mx[hh] = v; dn[hh] = 1.f;
            }
        }
        alf[w][q][cl] = make_float4(vst[0], vst[1], vst[2], vst[3]);
        for (int j = cl + 16; j < deg; j += 16) {
            int s = srcs[start + j];
            float4 av = *(const float4*)(as_ + s * 4);
            float vv[4] = {av.x + ad4[0], av.y + ad4[1], av.z + ad4[2], av.w + ad4[3]};
#pragma unroll
            for (int hh = 0; hh < 4; ++hh) {
                float v = vv[hh] > 0.f ? vv[hh] : 0.2f * vv[hh];
                float mn = fmaxf(mx[hh], v);
                dn[hh] = dn[hh] * __expf(mx[hh] - mn) + __expf(v - mn);
                mx[hh] = mn;
            }
        }
    }
    float mloc[4] = {mx[0], mx[1], mx[2], mx[3]};
#pragma unroll
    for (int off = 1; off < 16; off <<= 1)
#pragma unroll
        for (int hh = 0; hh < 4; ++hh) mx[hh] = fmaxf(mx[hh], __shfl_xor(mx[hh], off, 64));
#pragma unroll
    for (int hh = 0; hh < 4; ++hh) dn[hh] *= __expf(mloc[hh] - mx[hh]);
#pragma unroll
    for (int off = 1; off < 16; off <<= 1)
#pragma unroll
        for (int hh = 0; hh < 4; ++hh) dn[hh] += __shfl_xor(dn[hh], off, 64);
    float inv[4];
#pragma unroll
    for (int hh = 0; hh < 4; ++hh) inv[hh] = dn[hh] > 0.f ? 1.f / dn[hh] : 0.f;
    {
        float4 vv = alf[w][q][cl];   // logits -> alphas (OOB lanes: exp(-1e30-mx)=0)
        alf[w][q][cl] = make_float4(__expf(vv.x - mx[0]) * inv[0], __expf(vv.y - mx[1]) * inv[1],
                                    __expf(vv.z - mx[2]) * inv[2], __expf(vv.w - mx[3]) * inv[3]);
    }

    int hd = cl >> 2, cbase = cl * 16;
    float acc[16];
#pragma unroll
    for (int k = 0; k < 16; ++k) acc[k] = 0.f;

    for (int chunk = 0; chunk < deg || chunk == 0; chunk += 16) {
        if (chunk > 0) {
            int j = chunk + cl;
            int s = srcs[start + min(j, deg - 1)];
            sed[w][q][cl] = s;
            float a4[4] = {0.f, 0.f, 0.f, 0.f};
            if (j < deg) {
                float4 av = *(const float4*)(as_ + s * 4);
                float vv[4] = {av.x + ad4[0], av.y + ad4[1], av.z + ad4[2], av.w + ad4[3]};
#pragma unroll
                for (int hh = 0; hh < 4; ++hh) {
                    float v = vv[hh] > 0.f ? vv[hh] : 0.2f * vv[hh];
                    a4[hh] = __expf(v - mx[hh]) * inv[hh];
                }
            }
            alf[w][q][cl] = make_float4(a4[0], a4[1], a4[2], a4[3]);
        }
        int cnt = min(16, deg - chunk);
        if (cnt < 0) cnt = 0;
        int e = 0;
        // 4-edge groups, half-row batches: 4 uint4 in flight, 2 batches per group
        for (; e + 4 <= cnt; e += 4) {
            float av[4]; int sv[4];
#pragma unroll
            for (int t = 0; t < 4; ++t) {
                av[t] = ((const float*)&alf[w][q][e + t])[hd];
                sv[t] = sed[w][q][e + t];
            }
            uint4 ua[4];
#pragma unroll
            for (int t = 0; t < 4; ++t)
                ua[t] = *(const uint4*)(h + (long)sv[t] * 256 + cbase);
#pragma unroll
            for (int t = 0; t < 4; ++t) {
                float al = av[t];
                acc[0] += al * bflo(ua[t].x); acc[1] += al * bfhi(ua[t].x);
                acc[2] += al * bflo(ua[t].y); acc[3] += al * bfhi(ua[t].y);
                acc[4] += al * bflo(ua[t].z); acc[5] += al * bfhi(ua[t].z);
                acc[6] += al * bflo(ua[t].w); acc[7] += al * bfhi(ua[t].w);
            }
#pragma unroll
            for (int t = 0; t < 4; ++t)
                ua[t] = *(const uint4*)(h + (long)sv[t] * 256 + cbase + 8);
#pragma unroll
            for (int t = 0; t < 4; ++t) {
                float al = av[t];
                acc[8]  += al * bflo(ua[t].x); acc[9]  += al * bfhi(ua[t].x);
                acc[10] += al * bflo(ua[t].y); acc[11] += al * bfhi(ua[t].y);
                acc[12] += al * bflo(ua[t].z); acc[13] += al * bfhi(ua[t].z);
                acc[14] += al * bflo(ua[t].w); acc[15] += al * bfhi(ua[t].w);
            }
        }
        for (; e < cnt; ++e) {   // exact tail, 1 edge
            float al = ((const float*)&alf[w][q][e])[hd];
            const ushort_t* hr = h + (long)sed[w][q][e] * 256 + cbase;
            uint4 u0 = *(const uint4*)hr;
            uint4 u1 = *(const uint4*)(hr + 8);
            acc[0]  += al * bflo(u0.x); acc[1]  += al * bfhi(u0.x);
            acc[2]  += al * bflo(u0.y); acc[3]  += al * bfhi(u0.y);
            acc[4]  += al * bflo(u0.z); acc[5]  += al * bfhi(u0.z);
            acc[6]  += al * bflo(u0.w); acc[7]  += al * bfhi(u0.w);
            acc[8]  += al * bflo(u1.x); acc[9]  += al * bfhi(u1.x);
            acc[10] += al * bflo(u1.y); acc[11] += al * bfhi(u1.y);
            acc[12] += al * bflo(u1.z); acc[13] += al * bfhi(u1.z);
            acc[14] += al * bflo(u1.w); acc[15] += al * bfhi(u1.w);
        }
        if (deg <= 16) break;
    }

    // epilogue: bias + relu, bf16 store
    uint_t ow[8];
#pragma unroll
    for (int t = 0; t < 8; ++t) {
        float lo = fmaxf(acc[t * 2] + bias[cbase + t * 2], 0.f);
        float hi = fmaxf(acc[t * 2 + 1] + bias[cbase + t * 2 + 1], 0.f);
        ow[t] = pkbf(lo, hi);
    }
    ushort_t* op = out + (long)n * 256 + cbase;
    *(uint4*)op = make_uint4(ow[0], ow[1], ow[2], ow[3]);
    *(uint4*)(op + 8) = make_uint4(ow[4], ow[5], ow[6], ow[7]);
}

// ---------------- GAT aggregation H=1: fused BN stats (striped) ----------------
__global__ __launch_bounds__(256) void agg1_kernel(const ushort_t* __restrict__ h,
                                                   const float* __restrict__ as_,
                                                   const float* __restrict__ ad_,
                                                   const int* __restrict__ rowptr,
                                                   const int* __restrict__ srcs,
                                                   const float* __restrict__ bias,
                                                   ushort_t* __restrict__ out,
                                                   float* __restrict__ stats) {
    __shared__ float alf1[4][8][9];
    __shared__ int   sed1[4][8][9];
    __shared__ float ssum[64], ssq[64];
    int tid = threadIdx.x;
    int lane = tid & 63, w = tid >> 6;
    int o = lane >> 3, cl = lane & 7;
    int n = blockIdx.x * 32 + w * 8 + o;
    bool valid = n < N_NODES;
    int nc = valid ? n : N_NODES - 1;
    if (tid < 64) { ssum[tid] = 0.f; ssq[tid] = 0.f; }
    __syncthreads();

    int start = rowptr[nc];
    int deg = valid ? rowptr[nc + 1] - start : 0;
    float adn = ad_[nc];

    float mx = -1e30f, dn = 0.f;
    {
        float vst = -1e30f;
        int s0 = 0;
        if (deg > 0) s0 = srcs[start + min(cl, deg - 1)];
        sed1[w][o][cl] = s0;
        if (cl < deg) {
            float v = as_[s0] + adn;
            v = v > 0.f ? v : 0.2f * v;
            vst = v; mx = v; dn = 1.f;
        }
        alf1[w][o][cl] = vst;
        for (int j = cl + 8; j < deg; j += 8) {
            int s = srcs[start + j];
            float v = as_[s] + adn;
            v = v > 0.f ? v : 0.2f * v;
            float mn = fmaxf(mx, v);
            dn = dn * __expf(mx - mn) + __expf(v - mn);
            mx = mn;
        }
    }
    float mloc = mx;
#pragma unroll
    for (int off = 1; off < 8; off <<= 1) mx = fmaxf(mx, __shfl_xor(mx, off, 64));
    dn *= __expf(mloc - mx);
#pragma unroll
    for (int off = 1; off < 8; off <<= 1) dn += __shfl_xor(dn, off, 64);
    float inv = dn > 0.f ? 1.f / dn : 0.f;

    alf1[w][o][cl] = __expf(alf1[w][o][cl] - mx) * inv;

    int c0 = cl * 8;
    float acc[8] = {0.f, 0.f, 0.f, 0.f, 0.f, 0.f, 0.f, 0.f};

    for (int chunk = 0; chunk < deg || chunk == 0; chunk += 8) {
        if (chunk > 0) {
            int j = chunk + cl;
            int s = srcs[start + min(j, deg - 1)];
            sed1[w][o][cl] = s;
            float al = 0.f;
            if (j < deg) {
                float v = as_[s] + adn;
                v = v > 0.f ? v : 0.2f * v;
                al = __expf(v - mx) * inv;
            }
            alf1[w][o][cl] = al;
        }
        int cnt = min(8, deg - chunk);
        if (cnt < 0) cnt = 0;
        int e = 0;
        for (; e + 4 <= cnt; e += 4) {
            float av[4]; int sv[4];
#pragma unroll
            for (int t = 0; t < 4; ++t) {
                av[t] = alf1[w][o][e + t];
                sv[t] = sed1[w][o][e + t];
            }
            uint4 ua[4];
#pragma unroll
            for (int t = 0; t < 4; ++t)
                ua[t] = *(const uint4*)(h + (long)sv[t] * 64 + c0);
#pragma unroll
            for (int t = 0; t < 4; ++t) {
                float al = av[t];
                acc[0] += al * bflo(ua[t].x); acc[1] += al * bfhi(ua[t].x);
                acc[2] += al * bflo(ua[t].y); acc[3] += al * bfhi(ua[t].y);
                acc[4] += al * bflo(ua[t].z); acc[5] += al * bfhi(ua[t].z);
                acc[6] += al * bflo(ua[t].w); acc[7] += al * bfhi(ua[t].w);
            }
        }
        for (; e < cnt; ++e) {
            float al = alf1[w][o][e];
            uint4 u = *(const uint4*)(h + (long)sed1[w][o][e] * 64 + c0);
            acc[0] += al * bflo(u.x); acc[1] += al * bfhi(u.x);
            acc[2] += al * bflo(u.y); acc[3] += al * bfhi(u.y);
            acc[4] += al * bflo(u.z); acc[5] += al * bfhi(u.z);
            acc[6] += al * bflo(u.w); acc[7] += al * bfhi(u.w);
        }
        if (deg <= 8) break;
    }

    float v[8];
#pragma unroll
    for (int t = 0; t < 8; ++t) v[t] = fmaxf(acc[t] + bias[c0 + t], 0.f);
    if (valid) {
        uint_t ow[4];
#pragma unroll
        for (int t = 0; t < 4; ++t) ow[t] = pkbf(v[2 * t], v[2 * t + 1]);
        *(uint4*)(out + (long)n * 64 + c0) = make_uint4(ow[0], ow[1], ow[2], ow[3]);
    }
    float s1[8], s2[8];
#pragma unroll
    for (int t = 0; t < 8; ++t) {
        s1[t] = valid ? v[t] : 0.f;
        s2[t] = valid ? v[t] * v[t] : 0.f;
    }
#pragma unroll
    for (int off = 8; off < 64; off <<= 1)    // reduce 8 octants (same cl -> same channels)
#pragma unroll
        for (int t = 0; t < 8; ++t) {
            s1[t] += __shfl_xor(s1[t], off, 64);
            s2[t] += __shfl_xor(s2[t], off, 64);
        }
    if (lane < 8) {
#pragma unroll
        for (int t = 0; t < 8; ++t) {
            atomicAdd(&ssum[c0 + t], s1[t]);
            atomicAdd(&ssq[c0 + t], s2[t]);
        }
    }
    __syncthreads();
    if (tid < 64) {
        int cp = (blockIdx.x & (NCOPY - 1)) * 512;   // striped copy
        atomicAdd(&stats[cp + tid], ssum[tid]);
        atomicAdd(&stats[cp + 256 + tid], ssq[tid]);
    }
}

// ---------------- BatchNorm stats on bf16, coalesced, striped output ----------------
template<int C>
__global__ __launch_bounds__(256) void bn_stats_bf16(const ushort_t* __restrict__ x,
                                                     float* __restrict__ stats) {
    const int GROUPS = C / 8;
    const int RS = 256 / GROUPS;
    int tid = threadIdx.x;
    int cg_ = tid % GROUPS;
    int rs = tid / GROUPS;
    float s[8], s2[8];
#pragma unroll
    for (int k = 0; k < 8; ++k) { s[k] = 0.f; s2[k] = 0.f; }
    for (int n = blockIdx.x * RS + rs; n < N_NODES; n += gridDim.x * RS) {
        uint4 u = *(const uint4*)(x + (long)n * C + cg_ * 8);
        float f[8] = {bflo(u.x), bfhi(u.x), bflo(u.y), bfhi(u.y),
                      bflo(u.z), bfhi(u.z), bflo(u.w), bfhi(u.w)};
#pragma unroll
        for (int k = 0; k < 8; ++k) { s[k] += f[k]; s2[k] += f[k] * f[k]; }
    }
    __shared__ float red[256][16];
#pragma unroll
    for (int k = 0; k < 8; ++k) { red[tid][k] = s[k]; red[tid][8 + k] = s2[k]; }
    __syncthreads();
    if (tid < C) {
        int g = tid >> 3, k = tid & 7;
        float a = 0.f, b = 0.f;
        for (int r = 0; r < RS; ++r) {
            a += red[g + r * GROUPS][k];
            b += red[g + r * GROUPS][8 + k];
        }
        int cp = (blockIdx.x & (NCOPY - 1)) * 512;   // striped: ~4 blocks/address at 256 blocks
        atomicAdd(&stats[cp + tid], a);
        atomicAdd(&stats[cp + 256 + tid], b);
    }
}

// ---------------- pool (BN affine fused, striped-stats reduce) + FC; goff inlined ----------------
__global__ __launch_bounds__(256) void pool_fc_kernel(const ushort_t* __restrict__ h,
                                                      const int* __restrict__ batch,
                                                      const float* __restrict__ stats,
                                                      const float* __restrict__ g3,
                                                      const float* __restrict__ be3,
                                                      const float* __restrict__ fcW,
                                                      const float* __restrict__ fcb,
                                                      float* __restrict__ out) {
    int g = blockIdx.x;
    __shared__ int se[2];
    if (threadIdx.x < 2) {
        int gg = g + threadIdx.x;
        int lo = 0, hi = N_NODES;
        while (lo < hi) {
            int mid = (lo + hi) >> 1;
            if (batch[mid] < gg) lo = mid + 1; else hi = mid;
        }
        se[threadIdx.x] = lo;
    }
    __syncthreads();
    int s = se[0], e = se[1];
    int c = threadIdx.x & 63;
    int ty = threadIdx.x >> 6;
    float sum = 0.f;
    for (int n = s + ty; n < e; n += 4) sum += bflo((uint_t)h[(long)n * 64 + c]);
    __shared__ float red[4][64];
    __shared__ float pv[64];
    red[ty][c] = sum;
    __syncthreads();
    if (ty == 0) {
        float tot = red[0][c] + red[1][c] + red[2][c] + red[3][c];
        float v = tot / fmaxf((float)(e - s), 1.f);
        float s0 = 0.f, s1 = 0.f;
#pragma unroll 8
        for (int j = 0; j < NCOPY; ++j) {
            s0 += stats[j * 512 + c];
            s1 += stats[j * 512 + 256 + c];
        }
        float m = s0 * (1.f / N_NODES);
        float var = fmaxf(s1 * (1.f / N_NODES) - m * m, 0.f);
        pv[c] = (v - m) * rsqrtf(var + EPS_BN) * g3[c] + be3[c];
    }
    __syncthreads();
    if (threadIdx.x < 10) {
        int j = threadIdx.x;
        float acc = fcb[j];
#pragma unroll
        for (int k = 0; k < 64; ++k) acc += pv[k] * fcW[k * 10 + j];
        out[g * 10 + j] = acc;
    }
}

extern "C" void kernel_launch(void* const* d_in, const int* in_sizes, int n_in,
                              void* d_out, int out_size, void* d_ws, size_t ws_size,
                              hipStream_t stream) {
    const float* x      = (const float*)d_in[0];
    const int*   ei     = (const int*)d_in[1];
    const int*   batch  = (const int*)d_in[2];
    const float* W1     = (const float*)d_in[3];
    const float* a_src1 = (const float*)d_in[4];
    const float* a_dst1 = (const float*)d_in[5];
    const float* b1     = (const float*)d_in[6];
    const float* g1     = (const float*)d_in[7];
    const float* be1    = (const float*)d_in[8];
    const float* W2     = (const float*)d_in[9];
    const float* a_src2 = (const float*)d_in[10];
    const float* a_dst2 = (const float*)d_in[11];
    const float* b2     = (const float*)d_in[12];
    const float* g2     = (const float*)d_in[13];
    const float* be2    = (const float*)d_in[14];
    const float* W3     = (const float*)d_in[15];
    const float* a_src3 = (const float*)d_in[16];
    const float* a_dst3 = (const float*)d_in[17];
    const float* b3     = (const float*)d_in[18];
    const float* g3     = (const float*)d_in[19];
    const float* be3    = (const float*)d_in[20];
    const float* fcW    = (const float*)d_in[21];
    const float* fcb    = (const float*)d_in[22];
    float* out = (float*)d_out;

    const size_t N = N_NODES, E = NUM_E;
    const size_t NPAD = N + 128;                        // gload_lds reads past N (no predication)
    const int SST = NCOPY * 512;                        // striped stats size
    ushort_t* hbf    = (ushort_t*)d_ws;                 // [NPAD,256] bf16 GEMM output
    ushort_t* hagg   = hbf + NPAD * 256;                // [NPAD,256] bf16 agg output (pre-BN)
    ushort_t* xbf    = hagg + NPAD * 256;               // [NPAD,128] bf16 x
    ushort_t* w1t    = xbf + NPAD * 128;                // [256][128]
    ushort_t* w2t    = w1t + 256 * 128;                 // [256][256]
    ushort_t* w3t    = w2t + 256 * 256;                 // [64][256]
    ushort_t* w2ts   = w3t + 64 * 256;                  // [256][256] BN-scaled
    ushort_t* w3ts   = w2ts + 256 * 256;                // [64][256]  BN-scaled
    float*    as_    = (float*)(w3ts + 64 * 256 + 128); // [N,4]
    float*    ad_    = as_ + N * 4;                     // [N,4]
    int*      deg    = (int*)(ad_ + N * 4);             // [N]   (zero region start)
    int*      fill   = deg + N;                         // [N]
    float*    statsA = (float*)(fill + N);              // [NCOPY*512]
    float*    statsB = statsA + SST;                    // [NCOPY*512]
    float*    statsC = statsB + SST;                    // [NCOPY*512]
    float*    cvec0  = statsC + SST;                    // [256] zeros (layer-1 cvec)
    int*      rowptr = (int*)(cvec0 + 256);             // [N+1]
    int*      srcs   = rowptr + (N + 1);                // [E]
    int*      bsum   = srcs + E;                        // [256]
    float*    cvec2  = (float*)(bsum + 256);            // [256]
    float*    cvec3  = cvec2 + 256;                     // [64]

    const int NB = (N_NODES + 255) / 256;  // 196
    const int HB = (NUM_E + 255) / 256;    // 3125
    const int SX = N_NODES * 128 / 4;
    const int SW = 128 * 256 + 256 * 256 + 256 * 64;
    const int PB = (SX + SW + 255) / 256;  // 6570

    // ---- setup ----
    hipMemsetAsync(deg, 0, sizeof(int) * (2 * N + 3 * SST + 256), stream);
    hist_prep_kernel<<<HB + PB, 256, 0, stream>>>(ei, deg, W1, W2, W3, x, w1t, w2t, w3t, xbf);
    scan_local_kernel<<<NB, 256, 0, stream>>>(deg, rowptr, bsum);
    scan_fixup_kernel<<<NB, 256, 0, stream>>>(rowptr, bsum);

    const int GB = (N_NODES + 127) / 128;  // 391
    const int AB = N_NODES / 16;           // 3125 (exact: 50000 % 16 == 0)

    // ---- layer 1 (cvec0 zeros, W1 unscaled); scatter merged into the gemm1 dispatch ----
    gemm_fused_kernel<128, 256, 128, true><<<dim3(GB + 1563, 2), 256, 0, stream>>>(
        xbf, w1t, hbf, cvec0, a_src1, a_dst1, as_, ad_,
        ei, rowptr, fill, srcs);
    agg4_kernel<<<AB, 256, 0, stream>>>(hbf, as_, ad_, rowptr, srcs, b1, hagg);
    bn_stats_bf16<256><<<256, 256, 0, stream>>>(hagg, statsA);

    // ---- layer 2: fold BN1 into W2 (pure-copy staging) ----
    scale_w_kernel<<<256, 256, 0, stream>>>(statsA, g1, be1, w2t, w2ts, cvec2);
    gemm_fused_kernel<256, 256, 128, false><<<dim3(GB, 2), 256, 0, stream>>>(
        hagg, w2ts, hbf, cvec2, a_src2, a_dst2, as_, ad_,
        nullptr, nullptr, nullptr, nullptr);
    agg4_kernel<<<AB, 256, 0, stream>>>(hbf, as_, ad_, rowptr, srcs, b2, hagg);
    bn_stats_bf16<256><<<256, 256, 0, stream>>>(hagg, statsB);

    // ---- layer 3: fold BN2 into W3 ----
    scale_w_kernel<<<64, 256, 0, stream>>>(statsB, g2, be2, w3t, w3ts, cvec3);
    gemm_fused_kernel<256, 64, 64, false><<<dim3(GB, 1), 256, 0, stream>>>(
        hagg, w3ts, hbf, cvec3, a_src3, a_dst3, as_, ad_,
        nullptr, nullptr, nullptr, nullptr);
    agg1_kernel<<<(N_NODES + 31) / 32, 256, 0, stream>>>(hbf, as_, ad_, rowptr, srcs, b3, hagg, statsC);

    // ---- pool + BN3 affine + FC in one (goff inlined, striped-stats reduce) ----
    pool_fc_kernel<<<NUM_GRAPHS, 256, 0, stream>>>(hagg, batch, statsC, g3, be3, fcW, fcb, out);
}

// Round 10
// 473.176 us; speedup vs baseline: 1.3262x; 1.0042x over previous
//
#include <hip/hip_runtime.h>
#include <hip/hip_bf16.h>

#define N_NODES 50000
#define NUM_E   800000
#define EPS_BN  1e-5f
#define NUM_GRAPHS 64
#define NCOPY 64   // striped stats copies (R5/R6: global-atomic serialization fix)

typedef __attribute__((ext_vector_type(8))) short bf16x8;
typedef __attribute__((ext_vector_type(4))) float f32x4;
typedef unsigned short ushort_t;
typedef unsigned int uint_t;

static __device__ __forceinline__ unsigned short f2bf(float f) {
    unsigned int u = __float_as_uint(f);
    u += 0x7fffu + ((u >> 16) & 1u);   // RNE
    return (unsigned short)(u >> 16);
}
static __device__ __forceinline__ uint_t pkbf(float lo, float hi) {
    __hip_bfloat162 t = __float22bfloat162_rn(make_float2(lo, hi));
    return *(uint_t*)&t;
}
static __device__ __forceinline__ float bflo(uint_t u) { return __uint_as_float(u << 16); }
static __device__ __forceinline__ float bfhi(uint_t u) { return __uint_as_float(u & 0xffff0000u); }

// ---------------- hist + prep merged (independent work, block-range split) ----------------
__global__ void hist_prep_kernel(const int* __restrict__ ei, int* __restrict__ deg,
                                 const float* __restrict__ W1, const float* __restrict__ W2,
                                 const float* __restrict__ W3, const float* __restrict__ x,
                                 ushort_t* __restrict__ w1t, ushort_t* __restrict__ w2t,
                                 ushort_t* __restrict__ w3t, ushort_t* __restrict__ xbf) {
    const int HB = (NUM_E + 255) / 256;          // 3125 hist blocks
    const int S1 = 128 * 256, S2 = 256 * 256, S3 = 256 * 64;
    const int SW = S1 + S2 + S3;                 // 81920
    const int SX = N_NODES * 128 / 4;            // 1.6M float4 units
    int b = blockIdx.x;
    if (b < HB) {
        int e = b * 256 + threadIdx.x;
        if (e < NUM_E) atomicAdd(&deg[ei[NUM_E + e]], 1);
        return;
    }
    int i = (b - HB) * 256 + threadIdx.x;
    if (i < SX) {
        float4 v = ((const float4*)x)[i];
        ((uint2*)xbf)[i] = make_uint2(pkbf(v.x, v.y), pkbf(v.z, v.w));
    } else if (i < SX + SW) {
        int j = i - SX;
        if (j < S1) {
            int k = j / 256, n = j % 256;
            w1t[n * 128 + k] = f2bf(W1[j]);
        } else if (j < S1 + S2) {
            int jj = j - S1; int k = jj / 256, n = jj % 256;
            w2t[n * 256 + k] = f2bf(W2[jj]);
        } else {
            int jj = j - S1 - S2; int k = jj / 64, n = jj % 64;
            w3t[n * 256 + k] = f2bf(W3[jj]);
        }
    }
}

__global__ void scan_local_kernel(const int* __restrict__ deg, int* __restrict__ rowptr,
                                  int* __restrict__ bsum) {
    __shared__ int ws[4];
    int b = blockIdx.x, t = threadIdx.x;
    int i = b * 256 + t;
    int lane = t & 63, wv = t >> 6;
    int v = (i < N_NODES) ? deg[i] : 0;
    int incl = v;
#pragma unroll
    for (int off = 1; off < 64; off <<= 1) {
        int u = __shfl_up(incl, off, 64);
        if (lane >= off) incl += u;
    }
    if (lane == 63) ws[wv] = incl;
    __syncthreads();
    if (t == 0) {
        int s = 0;
#pragma unroll
        for (int k = 0; k < 4; ++k) { int x = ws[k]; ws[k] = s; s += x; }
        bsum[b] = s;
    }
    __syncthreads();
    if (i < N_NODES) rowptr[i + 1] = ws[wv] + incl;
}

// merged scan_sums + scan_add: each block redundantly sums its bsum prefix (196 entries, trivial)
__global__ __launch_bounds__(256) void scan_fixup_kernel(int* __restrict__ rowptr,
                                                         const int* __restrict__ bsum) {
    __shared__ int ws[4];
    int b = blockIdx.x, t = threadIdx.x;
    int lane = t & 63, wv = t >> 6;
    int v = (t < b) ? bsum[t] : 0;   // b <= 195 < 256, t < b => valid index
#pragma unroll
    for (int off = 1; off < 64; off <<= 1) v += __shfl_xor(v, off, 64);
    if (lane == 0) ws[wv] = v;
    __syncthreads();
    int pre = ws[0] + ws[1] + ws[2] + ws[3];
    int i = b * 256 + t;
    if (i < N_NODES) rowptr[i + 1] += pre;
    if (b == 0 && t == 0) rowptr[0] = 0;
}

// ---------------- BN fold into W (striped stats reduce): Wts = a*Wt, cvec = b@W ----------------
__global__ __launch_bounds__(256) void scale_w_kernel(const float* __restrict__ stats,
                                                      const float* __restrict__ g,
                                                      const float* __restrict__ be,
                                                      const ushort_t* __restrict__ wt,
                                                      ushort_t* __restrict__ wts,
                                                      float* __restrict__ cvec) {
    int n = blockIdx.x, k = threadIdx.x;
    float s0 = 0.f, s1 = 0.f;
#pragma unroll 8
    for (int j = 0; j < NCOPY; ++j) {          // 128KB striped stats, L2-resident
        s0 += stats[j * 512 + k];
        s1 += stats[j * 512 + 256 + k];
    }
    float m = s0 * (1.f / N_NODES);
    float var = fmaxf(s1 * (1.f / N_NODES) - m * m, 0.f);
    float rs = rsqrtf(var + EPS_BN) * g[k];
    float b = be[k] - m * rs;
    float wv = bflo((uint_t)wt[n * 256 + k]);
    wts[n * 256 + k] = f2bf(rs * wv);
    float p = b * wv;
    __shared__ float ws[4];
    int lane = k & 63, wid = k >> 6;
#pragma unroll
    for (int off = 1; off < 64; off <<= 1) p += __shfl_xor(p, off, 64);
    if (lane == 0) ws[wid] = p;
    __syncthreads();
    if (k == 0) cvec[n] = ws[0] + ws[1] + ws[2] + ws[3];
}

// ---------------- GEMM: A(bf16) @ Bt^T + cvec -> h(bf16) + per-head logits ----------------
// R10: DOUBLE-BUFFERED global_load_lds staging (T3-minimal 2-phase): stage tile t+1 before
// computing tile t -> ONE barrier per K-step (was 2) and load latency hidden under MFMA.
// The compiler's vmcnt(0)-drain at the barrier now waits on loads that have been in flight
// across the whole compute phase. Slot-XOR swizzle from R9 retained (both sides, rule #21).
// A buffers row-PADDED (+128): gload_lds has no per-lane predication; garbage rows discarded by
// the gr<N_NODES store guard. SCAT=true: extra blocks run CSR scatter (saves a launch).
template<int K, int NFULL, int BN, bool SCAT>
__global__ __launch_bounds__(256) void gemm_fused_kernel(const ushort_t* __restrict__ A,
                                                         const ushort_t* __restrict__ Bt,
                                                         ushort_t* __restrict__ C,
                                                         const float* __restrict__ cvec,
                                                         const float* __restrict__ a_src,
                                                         const float* __restrict__ a_dst,
                                                         float* __restrict__ as_,
                                                         float* __restrict__ ad_,
                                                         const int* __restrict__ ei,
                                                         const int* __restrict__ rowptr,
                                                         int* __restrict__ fill,
                                                         int* __restrict__ srcs) {
    constexpr int GBX = (N_NODES + 127) / 128;   // 391
    if constexpr (SCAT) {
        if (blockIdx.x >= GBX) {
            int idx = (blockIdx.x - GBX) + 1563 * blockIdx.y;
            int e = idx * 256 + (int)threadIdx.x;
            if (e < NUM_E) {
                int dst = ei[NUM_E + e];
                int pos = rowptr[dst] + atomicAdd(&fill[dst], 1);
                srcs[pos] = ei[e];
            }
            return;
        }
    }
    const int NT = BN / 16;
    const int NG = BN / 64;
    constexpr int ABYTES = 128 * 32 * 2;                 // 8KB per A buffer
    constexpr int BBYTES = BN * 32 * 2;                  // 8KB (BN=128) / 4KB (BN=64)
    constexpr int LOOP_BYTES = 2 * (ABYTES + BBYTES);    // double-buffered
    constexpr int EPI_BYTES  = 4 * 32 * 64 * 2;          // 16KB
    constexpr int SMEM_BYTES = LOOP_BYTES > EPI_BYTES ? LOOP_BYTES : EPI_BYTES;
    __shared__ __align__(16) unsigned char smem[SMEM_BYTES];
    ushort_t* As0 = (ushort_t*)smem;                     // [128][32]
    ushort_t* Bs0 = As0 + 128 * 32;                      // [BN][32]
    ushort_t* As1 = Bs0 + BN * 32;
    ushort_t* Bs1 = As1 + 128 * 32;
    ushort_t (*Cs)[32][64] = (ushort_t (*)[32][64])smem; // epilogue alias (post-final-barrier)
    __shared__ float cvec_s[BN];
    __shared__ float asrc_s[BN], adst_s[BN];
    int tid = threadIdx.x;
    int lane = tid & 63, w = tid >> 6;
    int row0 = blockIdx.x * 128, col0 = blockIdx.y * BN;
    int m_l = lane & 15, q = lane >> 4;

    if (tid < BN) {
        cvec_s[tid] = cvec[col0 + tid];
        asrc_s[tid] = a_src[col0 + tid];
        adst_s[tid] = a_dst[col0 + tid];
    }

    f32x4 acc[2][NT];
#pragma unroll
    for (int r = 0; r < 2; ++r)
#pragma unroll
        for (int c = 0; c < NT; ++c) acc[r][c] = (f32x4){0.f, 0.f, 0.f, 0.f};

    int rsub = lane >> 2;                         // 0..15: row within 16-row group
    int ssub = (lane & 3) ^ (rsub & 3);           // swizzled source slot (16B units)
    int csub = ssub * 8;                          // elem col offset
    int fsw = (q ^ (m_l & 3)) * 8;                // swizzled fragment-read col (elems)

#define STAGE(Abuf, Bbuf, K0)                                                        \
    {                                                                                \
        const ushort_t* ag = A + (long)(row0 + w * 32 + rsub) * K + (K0) + csub;     \
        __builtin_amdgcn_global_load_lds(ag, (Abuf) + (w * 32) * 32, 16, 0, 0);      \
        __builtin_amdgcn_global_load_lds(ag + 16 * K, (Abuf) + (w * 32 + 16) * 32, 16, 0, 0); \
        if constexpr (BN == 128) {                                                   \
            const ushort_t* bg = Bt + (long)(col0 + w * 32 + rsub) * K + (K0) + csub;\
            __builtin_amdgcn_global_load_lds(bg, (Bbuf) + (w * 32) * 32, 16, 0, 0);  \
            __builtin_amdgcn_global_load_lds(bg + 16 * K, (Bbuf) + (w * 32 + 16) * 32, 16, 0, 0); \
        } else {                                                                     \
            const ushort_t* bg = Bt + (long)(col0 + w * 16 + rsub) * K + (K0) + csub;\
            __builtin_amdgcn_global_load_lds(bg, (Bbuf) + (w * 16) * 32, 16, 0, 0);  \
        }                                                                            \
    }
#define COMPUTE(Abuf, Bbuf)                                                          \
    {                                                                                \
        bf16x8 af[2];                                                                \
        _Pragma("unroll")                                                            \
        for (int r = 0; r < 2; ++r)                                                  \
            af[r] = *(const bf16x8*)((Abuf) + (w * 32 + r * 16 + m_l) * 32 + fsw);   \
        _Pragma("unroll")                                                            \
        for (int c = 0; c < NT; ++c) {                                               \
            bf16x8 bf = *(const bf16x8*)((Bbuf) + (c * 16 + m_l) * 32 + fsw);        \
            _Pragma("unroll")                                                        \
            for (int r = 0; r < 2; ++r)                                              \
                acc[r][c] = __builtin_amdgcn_mfma_f32_16x16x32_bf16(af[r], bf, acc[r][c], 0, 0, 0); \
        }                                                                            \
    }

    STAGE(As0, Bs0, 0);
    __syncthreads();   // tile 0 resident (drain covers cvec_s/asrc_s/adst_s visibility too)
    // K % 64 == 0 for all instantiations (128, 256)
    for (int k0 = 0; k0 < K; k0 += 64) {
        if (k0 + 32 < K) STAGE(As1, Bs1, k0 + 32);   // prefetch t+1, in flight during compute
        COMPUTE(As0, Bs0);
        __syncthreads();                              // drains t+1 loads; all waves done with buf0
        if (k0 + 32 < K) {
            if (k0 + 64 < K) STAGE(As0, Bs0, k0 + 64);
            COMPUTE(As1, Bs1);
            __syncthreads();
        }
    }
#undef STAGE
#undef COMPUTE

    const int H = NFULL / 64;
#pragma unroll
    for (int gblk = 0; gblk < NG; ++gblk) {
        int hidx = blockIdx.y * NG + gblk;
        int colg = col0 + gblk * 64;
#pragma unroll
        for (int r = 0; r < 2; ++r)
#pragma unroll
            for (int cc = 0; cc < 4; ++cc)
#pragma unroll
                for (int i = 0; i < 4; ++i)
                    Cs[w][r * 16 + q * 4 + i][cc * 16 + m_l] =
                        f2bf(acc[r][gblk * 4 + cc][i] + cvec_s[gblk * 64 + cc * 16 + m_l]);
        // same-wave LDS RAW: in-order DS pipe, no barrier needed
#pragma unroll
        for (int j = 0; j < 4; ++j) {
            int flat = j * 64 + lane;
            int lr = flat >> 3, chg = flat & 7;
            int gr = row0 + w * 32 + lr;
            uint4 u = *(uint4*)&Cs[w][lr][chg * 8];
            float f0 = bflo(u.x), f1 = bfhi(u.x), f2 = bflo(u.y), f3 = bfhi(u.y);
            float f4 = bflo(u.z), f5 = bfhi(u.z), f6 = bflo(u.w), f7 = bfhi(u.w);
            int cb = gblk * 64 + chg * 8;
            float s1 = f0 * asrc_s[cb] + f1 * asrc_s[cb + 1] + f2 * asrc_s[cb + 2] + f3 * asrc_s[cb + 3]
                     + f4 * asrc_s[cb + 4] + f5 * asrc_s[cb + 5] + f6 * asrc_s[cb + 6] + f7 * asrc_s[cb + 7];
            float s2 = f0 * adst_s[cb] + f1 * adst_s[cb + 1] + f2 * adst_s[cb + 2] + f3 * adst_s[cb + 3]
                     + f4 * adst_s[cb + 4] + f5 * adst_s[cb + 5] + f6 * adst_s[cb + 6] + f7 * adst_s[cb + 7];
#pragma unroll
            for (int o = 1; o < 8; o <<= 1) {
                s1 += __shfl_xor(s1, o, 64);
                s2 += __shfl_xor(s2, o, 64);
            }
            if (gr < N_NODES) {
                *(uint4*)(C + (long)gr * NFULL + colg + chg * 8) = u;
                if ((lane & 7) == 0) {
                    as_[gr * H + hidx] = s1;
                    ad_[gr * H + hidx] = s2;
                }
            }
        }
    }
}

// ---------------- GAT aggregation H=4 (R3 structure: at ~3.3 TB/s gather ceiling, NO stats) ----------------
__global__ __launch_bounds__(256) void agg4_kernel(const ushort_t* __restrict__ h,
                                                   const float* __restrict__ as_,
                                                   const float* __restrict__ ad_,
                                                   const int* __restrict__ rowptr,
                                                   const int* __restrict__ srcs,
                                                   const float* __restrict__ bias,
                                                   ushort_t* __restrict__ out) {
    __shared__ float4 alf[4][4][17];   // [wave][quarter][edge] 4 head alphas (pad 17)
    __shared__ int    sed[4][4][17];   // [wave][quarter][edge] src id
    int tid = threadIdx.x;
    int lane = tid & 63, w = tid >> 6;
    int q = lane >> 4, cl = lane & 15;
    int n = blockIdx.x * 16 + w * 4 + q;   // grid exact: n < N_NODES always

    int start = rowptr[n];
    int deg = rowptr[n + 1] - start;

    float4 adv = *(const float4*)(ad_ + n * 4);
    float ad4[4] = {adv.x, adv.y, adv.z, adv.w};

    float mx[4] = {-1e30f, -1e30f, -1e30f, -1e30f};
    float dn[4] = {0.f, 0.f, 0.f, 0.f};
    {
        float vst[4] = {-1e30f, -1e30f, -1e30f, -1e30f};
        int s0 = 0;
        if (deg > 0) s0 = srcs[start + min(cl, deg - 1)];
        sed[w][q][cl] = s0;
        if (cl < deg) {
            float4 av = *(const float4*)(as_ + s0 * 4);
            float vv[4] = {av.x + ad4[0], av.y + ad4[1], av.z + ad4[2], av.w + ad4[3]};
#pragma unroll
            for (int hh = 0; hh < 4; ++hh) {
                float v = vv[hh] > 0.f ? vv[hh] : 0.2f * vv[hh];
                vst[hh] = v; mx[hh] = v; dn[hh] = 1.f;
            }
        }
        alf[w][q][cl] = make_float4(vst[0], vst[1], vst[2], vst[3]);
        for (int j = cl + 16; j < deg; j += 16) {
            int s = srcs[start + j];
            float4 av = *(const float4*)(as_ + s * 4);
            float vv[4] = {av.x + ad4[0], av.y + ad4[1], av.z + ad4[2], av.w + ad4[3]};
#pragma unroll
            for (int hh = 0; hh < 4; ++hh) {
                float v = vv[hh] > 0.f ? vv[hh] : 0.2f * vv[hh];
                float mn = fmaxf(mx[hh], v);
                dn[hh] = dn[hh] * __expf(mx[hh] - mn) + __expf(v - mn);
                mx[hh] = mn;
            }
        }
    }
    float mloc[4] = {mx[0], mx[1], mx[2], mx[3]};
#pragma unroll
    for (int off = 1; off < 16; off <<= 1)
#pragma unroll
        for (int hh = 0; hh < 4; ++hh) mx[hh] = fmaxf(mx[hh], __shfl_xor(mx[hh], off, 64));
#pragma unroll
    for (int hh = 0; hh < 4; ++hh) dn[hh] *= __expf(mloc[hh] - mx[hh]);
#pragma unroll
    for (int off = 1; off < 16; off <<= 1)
#pragma unroll
        for (int hh = 0; hh < 4; ++hh) dn[hh] += __shfl_xor(dn[hh], off, 64);
    float inv[4];
#pragma unroll
    for (int hh = 0; hh < 4; ++hh) inv[hh] = dn[hh] > 0.f ? 1.f / dn[hh] : 0.f;
    {
        float4 vv = alf[w][q][cl];   // logits -> alphas (OOB lanes: exp(-1e30-mx)=0)
        alf[w][q][cl] = make_float4(__expf(vv.x - mx[0]) * inv[0], __expf(vv.y - mx[1]) * inv[1],
                                    __expf(vv.z - mx[2]) * inv[2], __expf(vv.w - mx[3]) * inv[3]);
    }

    int hd = cl >> 2, cbase = cl * 16;
    float acc[16];
#pragma unroll
    for (int k = 0; k < 16; ++k) acc[k] = 0.f;

    for (int chunk = 0; chunk < deg || chunk == 0; chunk += 16) {
        if (chunk > 0) {
            int j = chunk + cl;
            int s = srcs[start + min(j, deg - 1)];
            sed[w][q][cl] = s;
            float a4[4] = {0.f, 0.f, 0.f, 0.f};
            if (j < deg) {
                float4 av = *(const float4*)(as_ + s * 4);
                float vv[4] = {av.x + ad4[0], av.y + ad4[1], av.z + ad4[2], av.w + ad4[3]};
#pragma unroll
                for (int hh = 0; hh < 4; ++hh) {
                    float v = vv[hh] > 0.f ? vv[hh] : 0.2f * vv[hh];
                    a4[hh] = __expf(v - mx[hh]) * inv[hh];
                }
            }
            alf[w][q][cl] = make_float4(a4[0], a4[1], a4[2], a4[3]);
        }
        int cnt = min(16, deg - chunk);
        if (cnt < 0) cnt = 0;
        int e = 0;
        // 4-edge groups, half-row batches: 4 uint4 in flight, 2 batches per group
        for (; e + 4 <= cnt; e += 4) {
            float av[4]; int sv[4];
#pragma unroll
            for (int t = 0; t < 4; ++t) {
                av[t] = ((const float*)&alf[w][q][e + t])[hd];
                sv[t] = sed[w][q][e + t];
            }
            uint4 ua[4];
#pragma unroll
            for (int t = 0; t < 4; ++t)
                ua[t] = *(const uint4*)(h + (long)sv[t] * 256 + cbase);
#pragma unroll
            for (int t = 0; t < 4; ++t) {
                float al = av[t];
                acc[0] += al * bflo(ua[t].x); acc[1] += al * bfhi(ua[t].x);
                acc[2] += al * bflo(ua[t].y); acc[3] += al * bfhi(ua[t].y);
                acc[4] += al * bflo(ua[t].z); acc[5] += al * bfhi(ua[t].z);
                acc[6] += al * bflo(ua[t].w); acc[7] += al * bfhi(ua[t].w);
            }
#pragma unroll
            for (int t = 0; t < 4; ++t)
                ua[t] = *(const uint4*)(h + (long)sv[t] * 256 + cbase + 8);
#pragma unroll
            for (int t = 0; t < 4; ++t) {
                float al = av[t];
                acc[8]  += al * bflo(ua[t].x); acc[9]  += al * bfhi(ua[t].x);
                acc[10] += al * bflo(ua[t].y); acc[11] += al * bfhi(ua[t].y);
                acc[12] += al * bflo(ua[t].z); acc[13] += al * bfhi(ua[t].z);
                acc[14] += al * bflo(ua[t].w); acc[15] += al * bfhi(ua[t].w);
            }
        }
        for (; e < cnt; ++e) {   // exact tail, 1 edge
            float al = ((const float*)&alf[w][q][e])[hd];
            const ushort_t* hr = h + (long)sed[w][q][e] * 256 + cbase;
            uint4 u0 = *(const uint4*)hr;
            uint4 u1 = *(const uint4*)(hr + 8);
            acc[0]  += al * bflo(u0.x); acc[1]  += al * bfhi(u0.x);
            acc[2]  += al * bflo(u0.y); acc[3]  += al * bfhi(u0.y);
            acc[4]  += al * bflo(u0.z); acc[5]  += al * bfhi(u0.z);
            acc[6]  += al * bflo(u0.w); acc[7]  += al * bfhi(u0.w);
            acc[8]  += al * bflo(u1.x); acc[9]  += al * bfhi(u1.x);
            acc[10] += al * bflo(u1.y); acc[11] += al * bfhi(u1.y);
            acc[12] += al * bflo(u1.z); acc[13] += al * bfhi(u1.z);
            acc[14] += al * bflo(u1.w); acc[15] += al * bfhi(u1.w);
        }
        if (deg <= 16) break;
    }

    // epilogue: bias + relu, bf16 store
    uint_t ow[8];
#pragma unroll
    for (int t = 0; t < 8; ++t) {
        float lo = fmaxf(acc[t * 2] + bias[cbase + t * 2], 0.f);
        float hi = fmaxf(acc[t * 2 + 1] + bias[cbase + t * 2 + 1], 0.f);
        ow[t] = pkbf(lo, hi);
    }
    ushort_t* op = out + (long)n * 256 + cbase;
    *(uint4*)op = make_uint4(ow[0], ow[1], ow[2], ow[3]);
    *(uint4*)(op + 8) = make_uint4(ow[4], ow[5], ow[6], ow[7]);
}

// ---------------- GAT aggregation H=1: fused BN stats (striped) ----------------
__global__ __launch_bounds__(256) void agg1_kernel(const ushort_t* __restrict__ h,
                                                   const float* __restrict__ as_,
                                                   const float* __restrict__ ad_,
                                                   const int* __restrict__ rowptr,
                                                   const int* __restrict__ srcs,
                                                   const float* __restrict__ bias,
                                                   ushort_t* __restrict__ out,
                                                   float* __restrict__ stats) {
    __shared__ float alf1[4][8][9];
    __shared__ int   sed1[4][8][9];
    __shared__ float ssum[64], ssq[64];
    int tid = threadIdx.x;
    int lane = tid & 63, w = tid >> 6;
    int o = lane >> 3, cl = lane & 7;
    int n = blockIdx.x * 32 + w * 8 + o;
    bool valid = n < N_NODES;
    int nc = valid ? n : N_NODES - 1;
    if (tid < 64) { ssum[tid] = 0.f; ssq[tid] = 0.f; }
    __syncthreads();

    int start = rowptr[nc];
    int deg = valid ? rowptr[nc + 1] - start : 0;
    float adn = ad_[nc];

    float mx = -1e30f, dn = 0.f;
    {
        float vst = -1e30f;
        int s0 = 0;
        if (deg > 0) s0 = srcs[start + min(cl, deg - 1)];
        sed1[w][o][cl] = s0;
        if (cl < deg) {
            float v = as_[s0] + adn;
            v = v > 0.f ? v : 0.2f * v;
            vst = v; mx = v; dn = 1.f;
        }
        alf1[w][o][cl] = vst;
        for (int j = cl + 8; j < deg; j += 8) {
            int s = srcs[start + j];
            float v = as_[s] + adn;
            v = v > 0.f ? v : 0.2f * v;
            float mn = fmaxf(mx, v);
            dn = dn * __expf(mx - mn) + __expf(v - mn);
            mx = mn;
        }
    }
    float mloc = mx;
#pragma unroll
    for (int off = 1; off < 8; off <<= 1) mx = fmaxf(mx, __shfl_xor(mx, off, 64));
    dn *= __expf(mloc - mx);
#pragma unroll
    for (int off = 1; off < 8; off <<= 1) dn += __shfl_xor(dn, off, 64);
    float inv = dn > 0.f ? 1.f / dn : 0.f;

    alf1[w][o][cl] = __expf(alf1[w][o][cl] - mx) * inv;

    int c0 = cl * 8;
    float acc[8] = {0.f, 0.f, 0.f, 0.f, 0.f, 0.f, 0.f, 0.f};

    for (int chunk = 0; chunk < deg || chunk == 0; chunk += 8) {
        if (chunk > 0) {
            int j = chunk + cl;
            int s = srcs[start + min(j, deg - 1)];
            sed1[w][o][cl] = s;
            float al = 0.f;
            if (j < deg) {
                float v = as_[s] + adn;
                v = v > 0.f ? v : 0.2f * v;
                al = __expf(v - mx) * inv;
            }
            alf1[w][o][cl] = al;
        }
        int cnt = min(8, deg - chunk);
        if (cnt < 0) cnt = 0;
        int e = 0;
        for (; e + 4 <= cnt; e += 4) {
            float av[4]; int sv[4];
#pragma unroll
            for (int t = 0; t < 4; ++t) {
                av[t] = alf1[w][o][e + t];
                sv[t] = sed1[w][o][e + t];
            }
            uint4 ua[4];
#pragma unroll
            for (int t = 0; t < 4; ++t)
                ua[t] = *(const uint4*)(h + (long)sv[t] * 64 + c0);
#pragma unroll
            for (int t = 0; t < 4; ++t) {
                float al = av[t];
                acc[0] += al * bflo(ua[t].x); acc[1] += al * bfhi(ua[t].x);
                acc[2] += al * bflo(ua[t].y); acc[3] += al * bfhi(ua[t].y);
                acc[4] += al * bflo(ua[t].z); acc[5] += al * bfhi(ua[t].z);
                acc[6] += al * bflo(ua[t].w); acc[7] += al * bfhi(ua[t].w);
            }
        }
        for (; e < cnt; ++e) {
            float al = alf1[w][o][e];
            uint4 u = *(const uint4*)(h + (long)sed1[w][o][e] * 64 + c0);
            acc[0] += al * bflo(u.x); acc[1] += al * bfhi(u.x);
            acc[2] += al * bflo(u.y); acc[3] += al * bfhi(u.y);
            acc[4] += al * bflo(u.z); acc[5] += al * bfhi(u.z);
            acc[6] += al * bflo(u.w); acc[7] += al * bfhi(u.w);
        }
        if (deg <= 8) break;
    }

    float v[8];
#pragma unroll
    for (int t = 0; t < 8; ++t) v[t] = fmaxf(acc[t] + bias[c0 + t], 0.f);
    if (valid) {
        uint_t ow[4];
#pragma unroll
        for (int t = 0; t < 4; ++t) ow[t] = pkbf(v[2 * t], v[2 * t + 1]);
        *(uint4*)(out + (long)n * 64 + c0) = make_uint4(ow[0], ow[1], ow[2], ow[3]);
    }
    float s1[8], s2[8];
#pragma unroll
    for (int t = 0; t < 8; ++t) {
        s1[t] = valid ? v[t] : 0.f;
        s2[t] = valid ? v[t] * v[t] : 0.f;
    }
#pragma unroll
    for (int off = 8; off < 64; off <<= 1)    // reduce 8 octants (same cl -> same channels)
#pragma unroll
        for (int t = 0; t < 8; ++t) {
            s1[t] += __shfl_xor(s1[t], off, 64);
            s2[t] += __shfl_xor(s2[t], off, 64);
        }
    if (lane < 8) {
#pragma unroll
        for (int t = 0; t < 8; ++t) {
            atomicAdd(&ssum[c0 + t], s1[t]);
            atomicAdd(&ssq[c0 + t], s2[t]);
        }
    }
    __syncthreads();
    if (tid < 64) {
        int cp = (blockIdx.x & (NCOPY - 1)) * 512;   // striped copy
        atomicAdd(&stats[cp + tid], ssum[tid]);
        atomicAdd(&stats[cp + 256 + tid], ssq[tid]);
    }
}

// ---------------- BatchNorm stats on bf16, coalesced, striped output ----------------
template<int C>
__global__ __launch_bounds__(256) void bn_stats_bf16(const ushort_t* __restrict__ x,
                                                     float* __restrict__ stats) {
    const int GROUPS = C / 8;
    const int RS = 256 / GROUPS;
    int tid = threadIdx.x;
    int cg_ = tid % GROUPS;
    int rs = tid / GROUPS;
    float s[8], s2[8];
#pragma unroll
    for (int k = 0; k < 8; ++k) { s[k] = 0.f; s2[k] = 0.f; }
    for (int n = blockIdx.x * RS + rs; n < N_NODES; n += gridDim.x * RS) {
        uint4 u = *(const uint4*)(x + (long)n * C + cg_ * 8);
        float f[8] = {bflo(u.x), bfhi(u.x), bflo(u.y), bfhi(u.y),
                      bflo(u.z), bfhi(u.z), bflo(u.w), bfhi(u.w)};
#pragma unroll
        for (int k = 0; k < 8; ++k) { s[k] += f[k]; s2[k] += f[k] * f[k]; }
    }
    __shared__ float red[256][16];
#pragma unroll
    for (int k = 0; k < 8; ++k) { red[tid][k] = s[k]; red[tid][8 + k] = s2[k]; }
    __syncthreads();
    if (tid < C) {
        int g = tid >> 3, k = tid & 7;
        float a = 0.f, b = 0.f;
        for (int r = 0; r < RS; ++r) {
            a += red[g + r * GROUPS][k];
            b += red[g + r * GROUPS][8 + k];
        }
        int cp = (blockIdx.x & (NCOPY - 1)) * 512;   // striped: ~4 blocks/address at 256 blocks
        atomicAdd(&stats[cp + tid], a);
        atomicAdd(&stats[cp + 256 + tid], b);
    }
}

// ---------------- pool (BN affine fused, striped-stats reduce) + FC; goff inlined ----------------
__global__ __launch_bounds__(256) void pool_fc_kernel(const ushort_t* __restrict__ h,
                                                      const int* __restrict__ batch,
                                                      const float* __restrict__ stats,
                                                      const float* __restrict__ g3,
                                                      const float* __restrict__ be3,
                                                      const float* __restrict__ fcW,
                                                      const float* __restrict__ fcb,
                                                      float* __restrict__ out) {
    int g = blockIdx.x;
    __shared__ int se[2];
    if (threadIdx.x < 2) {
        int gg = g + threadIdx.x;
        int lo = 0, hi = N_NODES;
        while (lo < hi) {
            int mid = (lo + hi) >> 1;
            if (batch[mid] < gg) lo = mid + 1; else hi = mid;
        }
        se[threadIdx.x] = lo;
    }
    __syncthreads();
    int s = se[0], e = se[1];
    int c = threadIdx.x & 63;
    int ty = threadIdx.x >> 6;
    float sum = 0.f;
    for (int n = s + ty; n < e; n += 4) sum += bflo((uint_t)h[(long)n * 64 + c]);
    __shared__ float red[4][64];
    __shared__ float pv[64];
    red[ty][c] = sum;
    __syncthreads();
    if (ty == 0) {
        float tot = red[0][c] + red[1][c] + red[2][c] + red[3][c];
        float v = tot / fmaxf((float)(e - s), 1.f);
        float s0 = 0.f, s1 = 0.f;
#pragma unroll 8
        for (int j = 0; j < NCOPY; ++j) {
            s0 += stats[j * 512 + c];
            s1 += stats[j * 512 + 256 + c];
        }
        float m = s0 * (1.f / N_NODES);
        float var = fmaxf(s1 * (1.f / N_NODES) - m * m, 0.f);
        pv[c] = (v - m) * rsqrtf(var + EPS_BN) * g3[c] + be3[c];
    }
    __syncthreads();
    if (threadIdx.x < 10) {
        int j = threadIdx.x;
        float acc = fcb[j];
#pragma unroll
        for (int k = 0; k < 64; ++k) acc += pv[k] * fcW[k * 10 + j];
        out[g * 10 + j] = acc;
    }
}

extern "C" void kernel_launch(void* const* d_in, const int* in_sizes, int n_in,
                              void* d_out, int out_size, void* d_ws, size_t ws_size,
                              hipStream_t stream) {
    const float* x      = (const float*)d_in[0];
    const int*   ei     = (const int*)d_in[1];
    const int*   batch  = (const int*)d_in[2];
    const float* W1     = (const float*)d_in[3];
    const float* a_src1 = (const float*)d_in[4];
    const float* a_dst1 = (const float*)d_in[5];
    const float* b1     = (const float*)d_in[6];
    const float* g1     = (const float*)d_in[7];
    const float* be1    = (const float*)d_in[8];
    const float* W2     = (const float*)d_in[9];
    const float* a_src2 = (const float*)d_in[10];
    const float* a_dst2 = (const float*)d_in[11];
    const float* b2     = (const float*)d_in[12];
    const float* g2     = (const float*)d_in[13];
    const float* be2    = (const float*)d_in[14];
    const float* W3     = (const float*)d_in[15];
    const float* a_src3 = (const float*)d_in[16];
    const float* a_dst3 = (const float*)d_in[17];
    const float* b3     = (const float*)d_in[18];
    const float* g3     = (const float*)d_in[19];
    const float* be3    = (const float*)d_in[20];
    const float* fcW    = (const float*)d_in[21];
    const float* fcb    = (const float*)d_in[22];
    float* out = (float*)d_out;

    const size_t N = N_NODES, E = NUM_E;
    const size_t NPAD = N + 128;                        // gload_lds reads past N (no predication)
    const int SST = NCOPY * 512;                        // striped stats size
    ushort_t* hbf    = (ushort_t*)d_ws;                 // [NPAD,256] bf16 GEMM output
    ushort_t* hagg   = hbf + NPAD * 256;                // [NPAD,256] bf16 agg output (pre-BN)
    ushort_t* xbf    = hagg + NPAD * 256;               // [NPAD,128] bf16 x
    ushort_t* w1t    = xbf + NPAD * 128;                // [256][128]
    ushort_t* w2t    = w1t + 256 * 128;                 // [256][256]
    ushort_t* w3t    = w2t + 256 * 256;                 // [64][256]
    ushort_t* w2ts   = w3t + 64 * 256;                  // [256][256] BN-scaled
    ushort_t* w3ts   = w2ts + 256 * 256;                // [64][256]  BN-scaled
    float*    as_    = (float*)(w3ts + 64 * 256 + 128); // [N,4]
    float*    ad_    = as_ + N * 4;                     // [N,4]
    int*      deg    = (int*)(ad_ + N * 4);             // [N]   (zero region start)
    int*      fill   = deg + N;                         // [N]
    float*    statsA = (float*)(fill + N);              // [NCOPY*512]
    float*    statsB = statsA + SST;                    // [NCOPY*512]
    float*    statsC = statsB + SST;                    // [NCOPY*512]
    float*    cvec0  = statsC + SST;                    // [256] zeros (layer-1 cvec)
    int*      rowptr = (int*)(cvec0 + 256);             // [N+1]
    int*      srcs   = rowptr + (N + 1);                // [E]
    int*      bsum   = srcs + E;                        // [256]
    float*    cvec2  = (float*)(bsum + 256);            // [256]
    float*    cvec3  = cvec2 + 256;                     // [64]

    const int NB = (N_NODES + 255) / 256;  // 196
    const int HB = (NUM_E + 255) / 256;    // 3125
    const int SX = N_NODES * 128 / 4;
    const int SW = 128 * 256 + 256 * 256 + 256 * 64;
    const int PB = (SX + SW + 255) / 256;  // 6570

    // ---- setup ----
    hipMemsetAsync(deg, 0, sizeof(int) * (2 * N + 3 * SST + 256), stream);
    hist_prep_kernel<<<HB + PB, 256, 0, stream>>>(ei, deg, W1, W2, W3, x, w1t, w2t, w3t, xbf);
    scan_local_kernel<<<NB, 256, 0, stream>>>(deg, rowptr, bsum);
    scan_fixup_kernel<<<NB, 256, 0, stream>>>(rowptr, bsum);

    const int GB = (N_NODES + 127) / 128;  // 391
    const int AB = N_NODES / 16;           // 3125 (exact: 50000 % 16 == 0)

    // ---- layer 1 (cvec0 zeros, W1 unscaled); scatter merged into the gemm1 dispatch ----
    gemm_fused_kernel<128, 256, 128, true><<<dim3(GB + 1563, 2), 256, 0, stream>>>(
        xbf, w1t, hbf, cvec0, a_src1, a_dst1, as_, ad_,
        ei, rowptr, fill, srcs);
    agg4_kernel<<<AB, 256, 0, stream>>>(hbf, as_, ad_, rowptr, srcs, b1, hagg);
    bn_stats_bf16<256><<<256, 256, 0, stream>>>(hagg, statsA);

    // ---- layer 2: fold BN1 into W2 (pure-copy staging) ----
    scale_w_kernel<<<256, 256, 0, stream>>>(statsA, g1, be1, w2t, w2ts, cvec2);
    gemm_fused_kernel<256, 256, 128, false><<<dim3(GB, 2), 256, 0, stream>>>(
        hagg, w2ts, hbf, cvec2, a_src2, a_dst2, as_, ad_,
        nullptr, nullptr, nullptr, nullptr);
    agg4_kernel<<<AB, 256, 0, stream>>>(hbf, as_, ad_, rowptr, srcs, b2, hagg);
    bn_stats_bf16<256><<<256, 256, 0, stream>>>(hagg, statsB);

    // ---- layer 3: fold BN2 into W3 ----
    scale_w_kernel<<<64, 256, 0, stream>>>(statsB, g2, be2, w3t, w3ts, cvec3);
    gemm_fused_kernel<256, 64, 64, false><<<dim3(GB, 1), 256, 0, stream>>>(
        hagg, w3ts, hbf, cvec3, a_src3, a_dst3, as_, ad_,
        nullptr, nullptr, nullptr, nullptr);
    agg1_kernel<<<(N_NODES + 31) / 32, 256, 0, stream>>>(hbf, as_, ad_, rowptr, srcs, b3, hagg, statsC);

    // ---- pool + BN3 affine + FC in one (goff inlined, striped-stats reduce) ----
    pool_fc_kernel<<<NUM_GRAPHS, 256, 0, stream>>>(hagg, batch, statsC, g3, be3, fcW, fcb, out);
}